// Round 17
// baseline (1698.036 us; speedup 1.0000x reference)
//
#include <hip/hip_runtime.h>
#include <hip/hip_bf16.h>
#include <math.h>

typedef __hip_bfloat16 bf16;
typedef __attribute__((ext_vector_type(8))) short s16x8;
typedef __attribute__((ext_vector_type(4))) float f32x4;

constexpr int Bn  = 4;
constexpr int Cn  = 512;
constexpr int Hn  = 128;
constexpr int Wn  = 128;
constexpr int Nn  = Hn * Wn;   // 16384
constexpr int CQn = 64;
constexpr int CIn = 256;

__device__ __forceinline__ float bf2f(bf16 v){ return __bfloat162float(v); }
__device__ __forceinline__ bf16  f2bf(float v){ return __float2bfloat16(v); }

// async global->LDS, 16B per lane; LDS dest must be wave-uniform base (HW adds lane*16)
__device__ __forceinline__ void gload_lds16(const void* g, void* l){
  __builtin_amdgcn_global_load_lds(
      (const __attribute__((address_space(1))) unsigned int*)g,
      (__attribute__((address_space(3))) unsigned int*)l,
      16, 0, 0);
}

// ============================ stage 0 ============================

// logits[b][n] = sum_c wqr[c]*x[b][c][n]  (identical order to old k_dotc)
// pxb[b][blk][c] = sum_{n in 256-tile} x[b][c][n]  (wave-tree partials)
__global__ __launch_bounds__(256) void k_pass1(const float* __restrict__ x,
                                               const float* __restrict__ wqr,
                                               float* __restrict__ logits,
                                               float* __restrict__ pxb){
  __shared__ float xbw[4][Cn];   // 8KB
  int blk = blockIdx.x, b = blockIdx.y;   // blk over Nn/256 = 64
  int t = threadIdx.x, wid = t >> 6;
  int n = blk * 256 + t;
  const float* xp = x + (size_t)b * Cn * Nn + n;
  float acc = 0.f;
  #pragma unroll 4
  for (int c = 0; c < Cn; ++c){
    float xv = xp[(size_t)c * Nn];
    acc += wqr[c] * xv;
    float s = xv;
    s += __shfl_xor(s, 1);
    s += __shfl_xor(s, 2);
    s += __shfl_xor(s, 4);
    s += __shfl_xor(s, 8);
    s += __shfl_xor(s, 16);
    s += __shfl_xor(s, 32);
    if ((t & 63) == 0) xbw[wid][c] = s;
  }
  logits[b * Nn + n] = acc;
  __syncthreads();
  for (int c = t; c < Cn; c += 256)
    pxb[((size_t)b * 64 + blk) * Cn + c] = xbw[0][c] + xbw[1][c] + xbw[2][c] + xbw[3][c];
}

// xbar[b][c] = scale * sum_blk pxb[b][blk][c]
__global__ __launch_bounds__(256) void k_red1(const float* __restrict__ pxb,
                                              float* __restrict__ xbar,
                                              float scale){
  int i = blockIdx.x * 256 + threadIdx.x;   // over Bn*Cn
  int b = i >> 9, c = i & 511;
  float s = 0.f;
  #pragma unroll 8
  for (int k = 0; k < 64; ++k) s += pxb[((size_t)b * 64 + k) * Cn + c];
  xbar[i] = s * scale;
}

// ctxlog[b][n] = sum_c u[b][c]*x ; pwg[b][blk][c] = sum_n x*exp(logits[n]-m)
__global__ __launch_bounds__(256) void k_pass2(const float* __restrict__ x,
                                               const float* __restrict__ u,
                                               const float* __restrict__ logits,
                                               const float* __restrict__ stats,
                                               float* __restrict__ ctxlog,
                                               float* __restrict__ pwg){
  __shared__ float xbw[4][Cn];
  int blk = blockIdx.x, b = blockIdx.y;
  int t = threadIdx.x, wid = t >> 6;
  int n = blk * 256 + t;
  float m = stats[b * 2];
  float we = expf(logits[b * Nn + n] - m);
  const float* xp = x + (size_t)b * Cn * Nn + n;
  const float* up = u + b * Cn;
  float acc = 0.f;
  #pragma unroll 4
  for (int c = 0; c < Cn; ++c){
    float xv = xp[(size_t)c * Nn];
    acc += up[c] * xv;
    float s = xv * we;
    s += __shfl_xor(s, 1);
    s += __shfl_xor(s, 2);
    s += __shfl_xor(s, 4);
    s += __shfl_xor(s, 8);
    s += __shfl_xor(s, 16);
    s += __shfl_xor(s, 32);
    if ((t & 63) == 0) xbw[wid][c] = s;
  }
  ctxlog[b * Nn + n] = acc;
  __syncthreads();
  for (int c = t; c < Cn; c += 256)
    pwg[((size_t)b * 64 + blk) * Cn + c] = xbw[0][c] + xbw[1][c] + xbw[2][c] + xbw[3][c];
}

// wgt[b][c] = (sum_blk pwg) / den
__global__ __launch_bounds__(256) void k_red2(const float* __restrict__ pwg,
                                              const float* __restrict__ stats,
                                              float* __restrict__ wgt){
  int i = blockIdx.x * 256 + threadIdx.x;
  int b = i >> 9, c = i & 511;
  float s = 0.f;
  #pragma unroll 8
  for (int k = 0; k < 64; ++k) s += pwg[((size_t)b * 64 + k) * Cn + c];
  wgt[i] = s / stats[b * 2 + 1];
}

__global__ __launch_bounds__(256) void k_rowdot(const float* __restrict__ W,
                                                const float* __restrict__ vec,
                                                float* __restrict__ out){
  __shared__ float vs[Cn];
  int b = blockIdx.x, t = threadIdx.x;
  for (int j = t; j < Cn; j += 256) vs[j] = vec[b * Cn + j];
  __syncthreads();
  const float4* wp = (const float4*)(W + (size_t)t * Cn);
  float a = 0.f;
  #pragma unroll 4
  for (int j = 0; j < Cn / 4; ++j){
    float4 w4 = wp[j];
    a += w4.x * vs[4*j] + w4.y * vs[4*j+1] + w4.z * vs[4*j+2] + w4.w * vs[4*j+3];
  }
  out[b * CIn + t] = a;
}

__global__ __launch_bounds__(256) void k_coldot(const float* __restrict__ W,
                                                const float* __restrict__ vec,
                                                float* __restrict__ out){
  __shared__ float vs[CIn];
  int b = blockIdx.y, t = threadIdx.x;
  int c = blockIdx.x * 256 + t;
  if (t < CIn) vs[t] = vec[b * CIn + t];
  __syncthreads();
  float a = 0.f;
  #pragma unroll 8
  for (int j = 0; j < CIn; ++j) a += W[(size_t)j * Cn + c] * vs[j];
  out[b * Cn + c] = a;
}

__global__ __launch_bounds__(256) void k_mch2(const float* __restrict__ w_up,
                                              const float* __restrict__ b_up,
                                              const float* __restrict__ ctx,
                                              float* __restrict__ mch){
  __shared__ float cs[CIn];
  int b = blockIdx.y, t = threadIdx.x;
  int o = blockIdx.x * 256 + t;
  if (t < CIn) cs[t] = ctx[b * CIn + t];
  __syncthreads();
  const float4* wp = (const float4*)(w_up + (size_t)o * CIn);
  float a = b_up[o];
  #pragma unroll 4
  for (int j = 0; j < CIn / 4; ++j){
    float4 w4 = wp[j];
    a += w4.x * cs[4*j] + w4.y * cs[4*j+1] + w4.z * cs[4*j+2] + w4.w * cs[4*j+3];
  }
  mch[b * Cn + o] = 1.f / (1.f + expf(-a));
}

__global__ __launch_bounds__(1024) void k_stats(const float* __restrict__ vv,
                                                float* __restrict__ stats){
  int b = blockIdx.x;
  const float* pp = vv + (size_t)b * Nn;
  int t = threadIdx.x;
  float m = -3.4e38f;
  for (int n = t; n < Nn; n += 1024) m = fmaxf(m, pp[n]);
  for (int o = 32; o > 0; o >>= 1) m = fmaxf(m, __shfl_down(m, o));
  __shared__ float red[16];
  int wid = t >> 6, lid = t & 63;
  if (lid == 0) red[wid] = m;
  __syncthreads();
  if (t == 0){
    float q = red[0];
    for (int i = 1; i < 16; i++) q = fmaxf(q, red[i]);
    red[0] = q;
  }
  __syncthreads();
  m = red[0];
  __syncthreads();
  float s = 0.f;
  for (int n = t; n < Nn; n += 1024) s += expf(pp[n] - m);
  for (int o = 32; o > 0; o >>= 1) s += __shfl_down(s, o);
  if (lid == 0) red[wid] = s;
  __syncthreads();
  if (t == 0){
    float q = 0.f;
    for (int i = 0; i < 16; i++) q += red[i];
    stats[b * 2]     = m;
    stats[b * 2 + 1] = q;
  }
}

__global__ __launch_bounds__(256) void k_msp(const float* __restrict__ lg,
                                             const float* __restrict__ stats,
                                             float* __restrict__ msp){
  int t = blockIdx.x * 256 + threadIdx.x;
  int b = t >> 14;
  float v = expf(lg[t] - stats[b * 2]) / stats[b * 2 + 1];
  msp[t] = 1.f / (1.f + expf(-v));
}

// Single x pass: cc = x*mch -> cc_hi/lo; cs = x*msp -> cs_hi/lo (all transposed [b][n][c])
__global__ __launch_bounds__(256) void k_applyT3(const float* __restrict__ x,
                                                 const float* __restrict__ mch,
                                                 const float* __restrict__ msp,
                                                 bf16* __restrict__ cc_hi,
                                                 bf16* __restrict__ cc_lo,
                                                 bf16* __restrict__ cs_hi,
                                                 bf16* __restrict__ cs_lo){
  __shared__ bf16 tch[32][33], tcl[32][33], tsh[32][33], tsl[32][33];
  int nt = blockIdx.x, ct = blockIdx.y, b = blockIdx.z;
  int n0 = nt * 32, c0 = ct * 32;
  int t = threadIdx.x;
  #pragma unroll
  for (int kk = 0; kk < 4; ++kk){
    int idx = t + kk * 256;
    int cl = idx >> 5, nl = idx & 31;
    float xv = x[((size_t)(b * Cn + c0 + cl)) * Nn + n0 + nl];
    float ccv = xv * mch[b * Cn + c0 + cl];
    float csv = xv * msp[b * Nn + n0 + nl];
    bf16 h1 = f2bf(ccv);
    tch[cl][nl] = h1;
    tcl[cl][nl] = f2bf(ccv - bf2f(h1));
    bf16 h2 = f2bf(csv);
    tsh[cl][nl] = h2;
    tsl[cl][nl] = f2bf(csv - bf2f(h2));
  }
  __syncthreads();
  #pragma unroll
  for (int kk = 0; kk < 4; ++kk){
    int idx = t + kk * 256;
    int nl = idx >> 5, cl = idx & 31;
    size_t o = ((size_t)(b * Nn + n0 + nl)) * Cn + c0 + cl;
    cc_hi[o] = tch[cl][nl];
    cc_lo[o] = tcl[cl][nl];
    cs_hi[o] = tsh[cl][nl];
    cs_lo[o] = tsl[cl][nl];
  }
}

// ============================ conversions ============================

__global__ __launch_bounds__(256) void k_cvt_w(const float* __restrict__ in,
                                               bf16* __restrict__ out, int n){
  int t = blockIdx.x * 256 + threadIdx.x;
  if (t < n) out[t] = f2bf(in[t]);
}

__global__ __launch_bounds__(256) void k_prep_wqk(const float* __restrict__ wq,
                                                  const float* __restrict__ wk,
                                                  const float* __restrict__ bq,
                                                  const float* __restrict__ bk,
                                                  bf16* __restrict__ wqk_hi,
                                                  bf16* __restrict__ wqk_lo,
                                                  float* __restrict__ bqk){
  int t = blockIdx.x * 256 + threadIdx.x;   // over 128*512
  int o = t >> 9, c = t & 511;
  float v = (o < 64) ? wq[(size_t)o * Cn + c] : wk[(size_t)(o - 64) * Cn + c];
  bf16 h = f2bf(v);
  wqk_hi[t] = h;
  wqk_lo[t] = f2bf(v - bf2f(h));
  if (t < 128) bqk[t] = (t < 64) ? bq[t] : bk[t - 64];
}

__global__ __launch_bounds__(256) void k_cvt_T(const float* __restrict__ in,
                                               bf16* __restrict__ out_hi,
                                               bf16* __restrict__ out_lo){
  __shared__ bf16 th_[32][33];
  __shared__ bf16 tl_[32][33];
  int nt = blockIdx.x, ct = blockIdx.y, b = blockIdx.z;
  int n0 = nt * 32, c0 = ct * 32;
  int t = threadIdx.x;
  #pragma unroll
  for (int kk = 0; kk < 4; ++kk){
    int idx = t + kk * 256;
    int cl = idx >> 5, nl = idx & 31;
    float v = in[((size_t)(b * Cn + c0 + cl)) * Nn + n0 + nl];
    bf16 h = f2bf(v);
    th_[cl][nl] = h;
    tl_[cl][nl] = f2bf(v - bf2f(h));
  }
  __syncthreads();
  #pragma unroll
  for (int kk = 0; kk < 4; ++kk){
    int idx = t + kk * 256;
    int nl = idx >> 5, cl = idx & 31;
    size_t o = ((size_t)(b * Nn + n0 + nl)) * Cn + c0 + cl;
    out_hi[o] = th_[cl][nl];
    out_lo[o] = tl_[cl][nl];
  }
}

// ============================ MFMA GEMMs ============================

// V = Wv @ X. 128x128 tile, BK=64. XCD-chunked 1D grid of 2048.
__global__ __launch_bounds__(256) void k_v_mfma(const bf16* __restrict__ xT,
                                                const bf16* __restrict__ wvb,
                                                const float* __restrict__ bv,
                                                bf16* __restrict__ v){
  __shared__ short As[128 * 64];
  __shared__ short Bs[128 * 64];
  __shared__ float bvs[128];
  int lin = blockIdx.x;
  int swz = (lin & 7) * 256 + (lin >> 3);
  int cb = (swz & 3) * 128;
  int nb = ((swz >> 2) & 127) * 128;
  int b  = swz >> 9;
  int t = threadIdx.x, lane = t & 63, wid = t >> 6;
  int wm = wid >> 1, wn = wid & 1;
  int l15 = lane & 15, l4 = lane >> 4;
  if (t < 128) bvs[t] = bv[cb + t];
  f32x4 acc[4][4];
  #pragma unroll
  for (int i = 0; i < 4; i++)
    #pragma unroll
    for (int j = 0; j < 4; j++) acc[i][j] = (f32x4){0.f, 0.f, 0.f, 0.f};

  const bf16* wp = wvb + (size_t)cb * Cn;
  const bf16* xp = xT + ((size_t)b * Nn + nb) * Cn;
  int r8 = lane >> 3;
  int kc = (lane & 7) * 8;
  for (int kt = 0; kt < 8; ++kt){
    int k0 = kt * 64;
    #pragma unroll
    for (int j = 0; j < 4; ++j){
      int inst = wid * 4 + j;
      int row = inst * 8 + r8;
      gload_lds16(wp + (size_t)row * Cn + k0 + kc, (char*)As + inst * 1024);
      gload_lds16(xp + (size_t)row * Cn + k0 + kc, (char*)Bs + inst * 1024);
    }
    __syncthreads();
    #pragma unroll
    for (int kk = 0; kk < 64; kk += 32){
      s16x8 a[4], bb[4];
      #pragma unroll
      for (int mi = 0; mi < 4; mi++)
        a[mi] = *(const s16x8*)&As[(wm * 64 + mi * 16 + l15) * 64 + kk + l4 * 8];
      #pragma unroll
      for (int ni = 0; ni < 4; ni++)
        bb[ni] = *(const s16x8*)&Bs[(wn * 64 + ni * 16 + l15) * 64 + kk + l4 * 8];
      #pragma unroll
      for (int mi = 0; mi < 4; mi++)
        #pragma unroll
        for (int ni = 0; ni < 4; ni++)
          acc[mi][ni] = __builtin_amdgcn_mfma_f32_16x16x32_bf16(a[mi], bb[ni], acc[mi][ni], 0, 0, 0);
    }
    __syncthreads();
  }
  #pragma unroll
  for (int mi = 0; mi < 4; mi++){
    #pragma unroll
    for (int r = 0; r < 4; r++){
      int cl = wm * 64 + mi * 16 + l4 * 4 + r;
      int c  = cb + cl;
      float bias = bvs[cl];
      #pragma unroll
      for (int ni = 0; ni < 4; ni++){
        int n = nb + wn * 64 + ni * 16 + l15;
        v[((size_t)(b * Cn + c)) * Nn + n] = f2bf(acc[mi][ni][r] + bias);
      }
    }
  }
}

// Q,K = [Wq;Wk] @ X, split-precision bf16 (3 MFMA terms).
// Writes qhw/khw ([b][w][h][c]) DIRECTLY via LDS transpose epilogue (no std q/k).
__global__ __launch_bounds__(256) void k_qk_mfma(const bf16* __restrict__ xT_hi,
                                                 const bf16* __restrict__ xT_lo,
                                                 const bf16* __restrict__ wqk_hi,
                                                 const bf16* __restrict__ wqk_lo,
                                                 const float* __restrict__ bqk,
                                                 bf16* __restrict__ qhw,
                                                 bf16* __restrict__ khw){
  __shared__ char smem[65536];
  short* Ah = (short*)smem;
  short* Al = Ah + 8192;
  short* Bh = Al + 8192;
  short* Bl = Bh + 8192;
  char*  Os = smem;                 // reused after final K-loop barrier (32KB)
  __shared__ float bs[128];
  int h = blockIdx.x, b = blockIdx.y;      // block covers n = h*128 + w, w=0..127
  int nb = h * 128;
  int t = threadIdx.x, lane = t & 63, wid = t >> 6;
  int wm = wid >> 1, wn = wid & 1;
  int l15 = lane & 15, l4 = lane >> 4;
  if (t < 128) bs[t] = bqk[t];
  f32x4 acc[4][4];
  #pragma unroll
  for (int i = 0; i < 4; i++)
    #pragma unroll
    for (int j = 0; j < 4; j++) acc[i][j] = (f32x4){0.f, 0.f, 0.f, 0.f};

  const bf16* xh = xT_hi + ((size_t)b * Nn + nb) * Cn;
  const bf16* xl = xT_lo + ((size_t)b * Nn + nb) * Cn;
  int r8 = lane >> 3;
  int kc = (lane & 7) * 8;
  for (int kt = 0; kt < 8; ++kt){
    int k0 = kt * 64;
    #pragma unroll
    for (int j = 0; j < 4; ++j){
      int inst = wid * 4 + j;
      int row = inst * 8 + r8;
      size_t off = (size_t)row * Cn + k0 + kc;
      gload_lds16(wqk_hi + off, (char*)Ah + inst * 1024);
      gload_lds16(wqk_lo + off, (char*)Al + inst * 1024);
      gload_lds16(xh + off,     (char*)Bh + inst * 1024);
      gload_lds16(xl + off,     (char*)Bl + inst * 1024);
    }
    __syncthreads();
    #pragma unroll
    for (int kk = 0; kk < 64; kk += 32){
      s16x8 ah[4], al[4], bh[4], bl[4];
      #pragma unroll
      for (int mi = 0; mi < 4; mi++){
        int idx = (wm * 64 + mi * 16 + l15) * 64 + kk + l4 * 8;
        ah[mi] = *(const s16x8*)&Ah[idx];
        al[mi] = *(const s16x8*)&Al[idx];
      }
      #pragma unroll
      for (int ni = 0; ni < 4; ni++){
        int idx = (wn * 64 + ni * 16 + l15) * 64 + kk + l4 * 8;
        bh[ni] = *(const s16x8*)&Bh[idx];
        bl[ni] = *(const s16x8*)&Bl[idx];
      }
      #pragma unroll
      for (int mi = 0; mi < 4; mi++)
        #pragma unroll
        for (int ni = 0; ni < 4; ni++){
          acc[mi][ni] = __builtin_amdgcn_mfma_f32_16x16x32_bf16(ah[mi], bh[ni], acc[mi][ni], 0, 0, 0);
          acc[mi][ni] = __builtin_amdgcn_mfma_f32_16x16x32_bf16(ah[mi], bl[ni], acc[mi][ni], 0, 0, 0);
          acc[mi][ni] = __builtin_amdgcn_mfma_f32_16x16x32_bf16(al[mi], bh[ni], acc[mi][ni], 0, 0, 0);
        }
    }
    __syncthreads();
  }
  // epilogue: Os[n][o] bf16 (256B rows, XOR-swizzled), then 128B row stores
  #pragma unroll
  for (int mi = 0; mi < 4; mi++){
    #pragma unroll
    for (int r = 0; r < 4; r++){
      int o = wm * 64 + mi * 16 + l4 * 4 + r;
      float bias = bs[o];
      #pragma unroll
      for (int ni = 0; ni < 4; ni++){
        int n = wn * 64 + ni * 16 + l15;
        bf16 bv = f2bf(acc[mi][ni][r] + bias);
        int byte = (n * 256 + o * 2) ^ ((n & 7) << 4);
        *(unsigned short*)(Os + byte) = *(unsigned short*)&bv;
      }
    }
  }
  __syncthreads();
  #pragma unroll
  for (int i = 0; i < 8; ++i){
    int s = t + i * 256;            // 0..2047: row = s>>3 (w + 128*qk), seg = s&7
    int row = s >> 3, seg = s & 7;
    int w = row & 127, qk = row >> 7;
    int o0 = qk * 64 + seg * 8;
    int byte = (w * 256 + o0 * 2) ^ ((w & 7) << 4);
    s16x8 d = *(const s16x8*)(Os + byte);
    bf16* dst = (qk == 0 ? qhw : khw) + (((size_t)b * Wn + w) * Hn + h) * CQn + seg * 8;
    *(s16x8*)dst = d;
  }
}

// ============================ fused attention ============================

// per (b,w): MFMA e_h from qhw/khw ([b][w][h][c]), diag, stats, p->LDS, PV MFMA.
// ohX layout [b][c][w][h] (unnormalized; alpha in fuse).
__global__ __launch_bounds__(256) void k_att_h(const bf16* __restrict__ qhw,
                                               const bf16* __restrict__ khw,
                                               const bf16* __restrict__ vT,
                                               float* __restrict__ mh,
                                               float* __restrict__ sh,
                                               bf16* __restrict__ ohX){
  __shared__ char smem[65536];
  char* attb = smem;                 // p tile 32KB
  char* vbb  = smem + 32768;         // V tile 32KB (e-phase: first 2KB = stats)
  float* redm = (float*)(smem + 32768);        // [2][128]
  float* reds = redm + 256;                    // [2][128]
  int w = blockIdx.x, b = blockIdx.y;
  int t = threadIdx.x, lane = t & 63, wid = t >> 6;
  int wm = wid >> 1, wn = wid & 1;
  int l15 = lane & 15, l4 = lane >> 4;

  const bf16* qp = qhw + ((size_t)(b * Wn + w)) * (Hn * CQn);
  const bf16* kp = khw + ((size_t)(b * Wn + w)) * (Hn * CQn);
  f32x4 acc[4][4];
  #pragma unroll
  for (int i = 0; i < 4; i++)
    #pragma unroll
    for (int j = 0; j < 4; j++) acc[i][j] = (f32x4){0.f, 0.f, 0.f, 0.f};
  #pragma unroll
  for (int kk = 0; kk < 64; kk += 32){
    s16x8 a[4], bb[4];
    #pragma unroll
    for (int mi = 0; mi < 4; mi++)
      a[mi] = *(const s16x8*)(qp + (size_t)(wm * 64 + mi * 16 + l15) * CQn + kk + l4 * 8);
    #pragma unroll
    for (int ni = 0; ni < 4; ni++)
      bb[ni] = *(const s16x8*)(kp + (size_t)(wn * 64 + ni * 16 + l15) * CQn + kk + l4 * 8);
    #pragma unroll
    for (int mi = 0; mi < 4; mi++)
      #pragma unroll
      for (int ni = 0; ni < 4; ni++)
        acc[mi][ni] = __builtin_amdgcn_mfma_f32_16x16x32_bf16(a[mi], bb[ni], acc[mi][ni], 0, 0, 0);
  }
  // diag mask: h==g
  if (wm == wn){
    #pragma unroll
    for (int mi = 0; mi < 4; mi++)
      #pragma unroll
      for (int r = 0; r < 4; r++)
        if (l15 == l4 * 4 + r) acc[mi][mi][r] = -1e30f;
  }
  float rm[4][4];
  #pragma unroll
  for (int mi = 0; mi < 4; mi++)
    #pragma unroll
    for (int r = 0; r < 4; r++){
      float m = fmaxf(fmaxf(acc[mi][0][r], acc[mi][1][r]),
                      fmaxf(acc[mi][2][r], acc[mi][3][r]));
      m = fmaxf(m, __shfl_xor(m, 1));
      m = fmaxf(m, __shfl_xor(m, 2));
      m = fmaxf(m, __shfl_xor(m, 4));
      m = fmaxf(m, __shfl_xor(m, 8));
      rm[mi][r] = m;
    }
  if (l15 == 0){
    #pragma unroll
    for (int mi = 0; mi < 4; mi++)
      #pragma unroll
      for (int r = 0; r < 4; r++)
        redm[wn * 128 + wm * 64 + mi * 16 + l4 * 4 + r] = rm[mi][r];
  }
  __syncthreads();
  float rs[4][4];
  #pragma unroll
  for (int mi = 0; mi < 4; mi++)
    #pragma unroll
    for (int r = 0; r < 4; r++){
      int h = wm * 64 + mi * 16 + l4 * 4 + r;
      float m = fmaxf(redm[h], redm[128 + h]);
      rm[mi][r] = m;
      float s = 0.f;
      #pragma unroll
      for (int ni = 0; ni < 4; ni++){
        acc[mi][ni][r] = expf(acc[mi][ni][r] - m);
        s += acc[mi][ni][r];
      }
      s += __shfl_xor(s, 1);
      s += __shfl_xor(s, 2);
      s += __shfl_xor(s, 4);
      s += __shfl_xor(s, 8);
      rs[mi][r] = s;
    }
  if (l15 == 0){
    #pragma unroll
    for (int mi = 0; mi < 4; mi++)
      #pragma unroll
      for (int r = 0; r < 4; r++)
        reds[wn * 128 + wm * 64 + mi * 16 + l4 * 4 + r] = rs[mi][r];
  }
  __syncthreads();
  #pragma unroll
  for (int mi = 0; mi < 4; mi++)
    #pragma unroll
    for (int r = 0; r < 4; r++){
      int h = wm * 64 + mi * 16 + l4 * 4 + r;
      if (wn == 0 && l15 == 0){
        mh[(size_t)(b * Wn + w) * Hn + h] = rm[mi][r];
        sh[(size_t)(b * Wn + w) * Hn + h] = reds[h] + reds[128 + h];
      }
      #pragma unroll
      for (int ni = 0; ni < 4; ni++){
        int g = wn * 64 + ni * 16 + l15;
        bf16 bv = f2bf(acc[mi][ni][r]);
        int byte = (h * 256 + g * 2) ^ ((h & 7) << 4);
        *(unsigned short*)(attb + byte) = *(unsigned short*)&bv;
      }
    }
  __syncthreads();
  // PV MFMA over 4 c-tiles
  for (int cb = 0; cb < Cn; cb += 128){
    const bf16* vp = vT + ((size_t)(b * Wn + w) * Cn + cb) * Hn;
    for (int s = t; s < 2048; s += 256){
      int row = s >> 4, seg = s & 15;
      s16x8 d = *(const s16x8*)(vp + (size_t)row * Hn + seg * 8);
      int byte = (row * 256 + seg * 16) ^ ((row & 7) << 4);
      *(s16x8*)(vbb + byte) = d;
    }
    __syncthreads();
    f32x4 acc2[4][4];
    #pragma unroll
    for (int i = 0; i < 4; i++)
      #pragma unroll
      for (int j = 0; j < 4; j++) acc2[i][j] = (f32x4){0.f, 0.f, 0.f, 0.f};
    #pragma unroll
    for (int kk = 0; kk < 128; kk += 32){
      s16x8 a[4], bb[4];
      #pragma unroll
      for (int mi = 0; mi < 4; mi++){
        int row = wm * 64 + mi * 16 + l15;
        int byte = (row * 256 + (kk + l4 * 8) * 2) ^ ((row & 7) << 4);
        a[mi] = *(const s16x8*)(vbb + byte);
      }
      #pragma unroll
      for (int ni = 0; ni < 4; ni++){
        int row = wn * 64 + ni * 16 + l15;
        int byte = (row * 256 + (kk + l4 * 8) * 2) ^ ((row & 7) << 4);
        bb[ni] = *(const s16x8*)(attb + byte);
      }
      #pragma unroll
      for (int mi = 0; mi < 4; mi++)
        #pragma unroll
        for (int ni = 0; ni < 4; ni++)
          acc2[mi][ni] = __builtin_amdgcn_mfma_f32_16x16x32_bf16(a[mi], bb[ni], acc2[mi][ni], 0, 0, 0);
    }
    bf16* op = ohX + ((size_t)(b * Cn + cb)) * Nn + (size_t)w * Hn;
    #pragma unroll
    for (int mi = 0; mi < 4; mi++)
      #pragma unroll
      for (int r = 0; r < 4; r++){
        int cl = wm * 64 + mi * 16 + l4 * 4 + r;
        #pragma unroll
        for (int ni = 0; ni < 4; ni++){
          int h = wn * 64 + ni * 16 + l15;
          op[(size_t)cl * Nn + h] = f2bf(acc2[mi][ni][r]);
        }
      }
    __syncthreads();
  }
}

// per (b,h): MFMA e_w from qhw/khw (strided rows), stats, p->LDS, PV MFMA.
__global__ __launch_bounds__(256) void k_att_w(const bf16* __restrict__ qhw,
                                               const bf16* __restrict__ khw,
                                               const bf16* __restrict__ v,
                                               float* __restrict__ mw,
                                               float* __restrict__ sw,
                                               bf16* __restrict__ ow){
  __shared__ char smem[65536];
  char* attb = smem;
  char* vbb  = smem + 32768;
  float* redm = (float*)(smem + 32768);
  float* reds = redm + 256;
  int h = blockIdx.x, b = blockIdx.y;
  int t = threadIdx.x, lane = t & 63, wid = t >> 6;
  int wm = wid >> 1, wn = wid & 1;
  int l15 = lane & 15, l4 = lane >> 4;

  const bf16* qp = qhw + (size_t)b * Wn * Hn * CQn + (size_t)h * CQn;
  const bf16* kp = khw + (size_t)b * Wn * Hn * CQn + (size_t)h * CQn;
  f32x4 acc[4][4];
  #pragma unroll
  for (int i = 0; i < 4; i++)
    #pragma unroll
    for (int j = 0; j < 4; j++) acc[i][j] = (f32x4){0.f, 0.f, 0.f, 0.f};
  #pragma unroll
  for (int kk = 0; kk < 64; kk += 32){
    s16x8 a[4], bb[4];
    #pragma unroll
    for (int mi = 0; mi < 4; mi++)
      a[mi] = *(const s16x8*)(qp + (size_t)(wm * 64 + mi * 16 + l15) * (Hn * CQn) + kk + l4 * 8);
    #pragma unroll
    for (int ni = 0; ni < 4; ni++)
      bb[ni] = *(const s16x8*)(kp + (size_t)(wn * 64 + ni * 16 + l15) * (Hn * CQn) + kk + l4 * 8);
    #pragma unroll
    for (int mi = 0; mi < 4; mi++)
      #pragma unroll
      for (int ni = 0; ni < 4; ni++)
        acc[mi][ni] = __builtin_amdgcn_mfma_f32_16x16x32_bf16(a[mi], bb[ni], acc[mi][ni], 0, 0, 0);
  }
  float rm[4][4];
  #pragma unroll
  for (int mi = 0; mi < 4; mi++)
    #pragma unroll
    for (int r = 0; r < 4; r++){
      float m = fmaxf(fmaxf(acc[mi][0][r], acc[mi][1][r]),
                      fmaxf(acc[mi][2][r], acc[mi][3][r]));
      m = fmaxf(m, __shfl_xor(m, 1));
      m = fmaxf(m, __shfl_xor(m, 2));
      m = fmaxf(m, __shfl_xor(m, 4));
      m = fmaxf(m, __shfl_xor(m, 8));
      rm[mi][r] = m;
    }
  if (l15 == 0){
    #pragma unroll
    for (int mi = 0; mi < 4; mi++)
      #pragma unroll
      for (int r = 0; r < 4; r++)
        redm[wn * 128 + wm * 64 + mi * 16 + l4 * 4 + r] = rm[mi][r];
  }
  __syncthreads();
  float rs[4][4];
  #pragma unroll
  for (int mi = 0; mi < 4; mi++)
    #pragma unroll
    for (int r = 0; r < 4; r++){
      int wr = wm * 64 + mi * 16 + l4 * 4 + r;
      float m = fmaxf(redm[wr], redm[128 + wr]);
      rm[mi][r] = m;
      float s = 0.f;
      #pragma unroll
      for (int ni = 0; ni < 4; ni++){
        acc[mi][ni][r] = expf(acc[mi][ni][r] - m);
        s += acc[mi][ni][r];
      }
      s += __shfl_xor(s, 1);
      s += __shfl_xor(s, 2);
      s += __shfl_xor(s, 4);
      s += __shfl_xor(s, 8);
      rs[mi][r] = s;
    }
  if (l15 == 0){
    #pragma unroll
    for (int mi = 0; mi < 4; mi++)
      #pragma unroll
      for (int r = 0; r < 4; r++)
        reds[wn * 128 + wm * 64 + mi * 16 + l4 * 4 + r] = rs[mi][r];
  }
  __syncthreads();
  #pragma unroll
  for (int mi = 0; mi < 4; mi++)
    #pragma unroll
    for (int r = 0; r < 4; r++){
      int wr = wm * 64 + mi * 16 + l4 * 4 + r;
      if (wn == 0 && l15 == 0){
        mw[(size_t)(b * Hn + h) * Wn + wr] = rm[mi][r];
        sw[(size_t)(b * Hn + h) * Wn + wr] = reds[wr] + reds[128 + wr];
      }
      #pragma unroll
      for (int ni = 0; ni < 4; ni++){
        int g = wn * 64 + ni * 16 + l15;
        bf16 bv = f2bf(acc[mi][ni][r]);
        int byte = (wr * 256 + g * 2) ^ ((wr & 7) << 4);
        *(unsigned short*)(attb + byte) = *(unsigned short*)&bv;
      }
    }
  __syncthreads();
  for (int cb = 0; cb < Cn; cb += 128){
    const bf16* vp = v + (size_t)(b * Cn + cb) * Nn + (size_t)h * Wn;
    for (int s = t; s < 2048; s += 256){
      int row = s >> 4, seg = s & 15;
      s16x8 d = *(const s16x8*)(vp + (size_t)row * Nn + seg * 8);
      int byte = (row * 256 + seg * 16) ^ ((row & 7) << 4);
      *(s16x8*)(vbb + byte) = d;
    }
    __syncthreads();
    f32x4 acc2[4][4];
    #pragma unroll
    for (int i = 0; i < 4; i++)
      #pragma unroll
      for (int j = 0; j < 4; j++) acc2[i][j] = (f32x4){0.f, 0.f, 0.f, 0.f};
    #pragma unroll
    for (int kk = 0; kk < 128; kk += 32){
      s16x8 a[4], bb[4];
      #pragma unroll
      for (int mi = 0; mi < 4; mi++){
        int row = wm * 64 + mi * 16 + l15;
        int byte = (row * 256 + (kk + l4 * 8) * 2) ^ ((row & 7) << 4);
        a[mi] = *(const s16x8*)(vbb + byte);
      }
      #pragma unroll
      for (int ni = 0; ni < 4; ni++){
        int row = wn * 64 + ni * 16 + l15;
        int byte = (row * 256 + (kk + l4 * 8) * 2) ^ ((row & 7) << 4);
        bb[ni] = *(const s16x8*)(attb + byte);
      }
      #pragma unroll
      for (int mi = 0; mi < 4; mi++)
        #pragma unroll
        for (int ni = 0; ni < 4; ni++)
          acc2[mi][ni] = __builtin_amdgcn_mfma_f32_16x16x32_bf16(a[mi], bb[ni], acc2[mi][ni], 0, 0, 0);
    }
    bf16* op = ow + (size_t)(b * Cn + cb) * Nn + (size_t)h * Wn;
    #pragma unroll
    for (int mi = 0; mi < 4; mi++)
      #pragma unroll
      for (int r = 0; r < 4; r++){
        int cl = wm * 64 + mi * 16 + l4 * 4 + r;
        #pragma unroll
        for (int ni = 0; ni < 4; ni++){
          int wr = wn * 64 + ni * 16 + l15;
          op[(size_t)cl * Nn + wr] = f2bf(acc2[mi][ni][r]);
        }
      }
    __syncthreads();
  }
}

// merge stats -> alphas, both in [b,h,w] layout for fuse
__global__ __launch_bounds__(256) void k_alpha(const float* __restrict__ mh,
                                               const float* __restrict__ sh,
                                               const float* __restrict__ mw,
                                               const float* __restrict__ sw,
                                               float* __restrict__ ahT,
                                               float* __restrict__ aw){
  int t = blockIdx.x * 256 + threadIdx.x;   // (b*Hn+h)*Wn + w
  int b = t >> 14;
  int hw = t & (Nn - 1);
  int h = hw >> 7, w = hw & 127;
  size_t ih = (size_t)(b * Wn + w) * Hn + h;
  size_t iw = t;
  float mhv = mh[ih], mwv = mw[iw];
  float M = fmaxf(mhv, mwv);
  float eh_ = expf(mhv - M), ew_ = expf(mwv - M);
  float inv = 1.f / (sh[ih] * eh_ + sw[iw] * ew_);
  ahT[t] = eh_ * inv;
  aw[t]  = ew_ * inv;
}

// ============================ remaining CA kernels ============================

__global__ __launch_bounds__(256) void k_trans(const bf16* __restrict__ in,
                                               bf16* __restrict__ out,
                                               int CH){
  __shared__ bf16 tile[32][33];
  int tl = blockIdx.x, c = blockIdx.y, b = blockIdx.z;
  int th = tl >> 2, tw = tl & 3;
  int h0 = th * 32, w0 = tw * 32;
  int t = threadIdx.x;
  const bf16* ip = in + ((size_t)(b * CH + c)) * Nn;
  #pragma unroll
  for (int kk = 0; kk < 4; ++kk){
    int idx = t + kk * 256;
    int hl = idx >> 5, wl = idx & 31;
    tile[hl][wl] = ip[(h0 + hl) * Wn + w0 + wl];
  }
  __syncthreads();
  #pragma unroll
  for (int kk = 0; kk < 4; ++kk){
    int idx = t + kk * 256;
    int wl = idx >> 5, hl = idx & 31;
    out[((size_t)(b * Wn + w0 + wl) * CH + c) * Hn + h0 + hl] = tile[hl][wl];
  }
}

// out = gamma*(ah*ohX^T + aw*ow) + resid  [single attention set]
__global__ __launch_bounds__(256) void k_fuse2(const float* __restrict__ in,
                                               const bf16* __restrict__ ohX,
                                               const bf16* __restrict__ ow,
                                               const float* __restrict__ ahT,
                                               const float* __restrict__ aw,
                                               const float* __restrict__ gamma,
                                               float* __restrict__ out){
  __shared__ unsigned short tileT[64][138];
  int c = blockIdx.x, half = blockIdx.y, b = blockIdx.z;
  int t = threadIdx.x;
  float g = gamma[0];
  int h0 = half * 64;
  const bf16* ohp = ohX + ((size_t)(b * Cn + c)) * Nn;   // [w][h] rows
  #pragma unroll
  for (int i = 0; i < 4; ++i){
    int s = t + i * 256;            // 0..1023: w = s>>3, seg = s&7 (h-chunk)
    int w = s >> 3, seg = s & 7;
    s16x8 d = *(const s16x8*)(ohp + (size_t)w * Hn + h0 + seg * 8);
    #pragma unroll
    for (int j = 0; j < 8; ++j)
      tileT[seg * 8 + j][w] = (unsigned short)d[j];
  }
  __syncthreads();
  size_t base = ((size_t)(b * Cn + c)) * Nn;
  #pragma unroll
  for (int i = 0; i < 8; ++i){
    int o = t + i * 256;            // 0..2047
    int hl = o >> 5, w4 = (o & 31) * 4;
    int h = h0 + hl;
    size_t idx = base + (size_t)h * Wn + w4;
    size_t aidx = (size_t)b * Nn + (size_t)h * Wn + w4;
    ushort4 owv = *(const ushort4*)((const unsigned short*)ow + idx);
    float4 ah4 = *(const float4*)(ahT + aidx);
    float4 aw4 = *(const float4*)(aw + aidx);
    float4 inv = in ? *(const float4*)(in + idx) : (float4){0.f,0.f,0.f,0.f};
    float r[4];
    #pragma unroll
    for (int j = 0; j < 4; ++j){
      unsigned short uh = tileT[hl][w4 + j];
      unsigned short uo = ((const unsigned short*)&owv)[j];
      float ohv = bf2f(*(bf16*)&uh);
      float owf = bf2f(*(bf16*)&uo);
      float ahv = ((const float*)&ah4)[j];
      float awv = ((const float*)&aw4)[j];
      r[j] = g * (ahv * ohv + awv * owf) + ((const float*)&inv)[j];
    }
    float4 o4 = { r[0], r[1], r[2], r[3] };
    *(float4*)(out + idx) = o4;
  }
}

// s = gamma*(a1h*oh1^T + a1w*ow1) + gamma*(a2h*oh2^T + a2w*ow2) + x*(mch+msp)
__global__ __launch_bounds__(256) void k_fuse3(const float* __restrict__ x,
                                               const float* __restrict__ mch,
                                               const float* __restrict__ msp,
                                               const bf16* __restrict__ oh1,
                                               const bf16* __restrict__ ow1,
                                               const float* __restrict__ a1h,
                                               const float* __restrict__ a1w,
                                               const bf16* __restrict__ oh2,
                                               const bf16* __restrict__ ow2,
                                               const float* __restrict__ a2h,
                                               const float* __restrict__ a2w,
                                               const float* __restrict__ gamma,
                                               float* __restrict__ out){
  __shared__ unsigned short t1[64][138];
  __shared__ unsigned short t2[64][138];
  int c = blockIdx.x, half = blockIdx.y, b = blockIdx.z;
  int t = threadIdx.x;
  float g = gamma[0];
  float mc = mch[b * Cn + c];
  int h0 = half * 64;
  const bf16* p1 = oh1 + ((size_t)(b * Cn + c)) * Nn;
  const bf16* p2 = oh2 + ((size_t)(b * Cn + c)) * Nn;
  #pragma unroll
  for (int i = 0; i < 4; ++i){
    int s = t + i * 256;
    int w = s >> 3, seg = s & 7;
    s16x8 d1 = *(const s16x8*)(p1 + (size_t)w * Hn + h0 + seg * 8);
    s16x8 d2 = *(const s16x8*)(p2 + (size_t)w * Hn + h0 + seg * 8);
    #pragma unroll
    for (int j = 0; j < 8; ++j){
      t1[seg * 8 + j][w] = (unsigned short)d1[j];
      t2[seg * 8 + j][w] = (unsigned short)d2[j];
    }
  }
  __syncthreads();
  size_t base = ((size_t)(b * Cn + c)) * Nn;
  #pragma unroll
  for (int i = 0; i < 8; ++i){
    int o = t + i * 256;
    int hl = o >> 5, w4 = (o & 31) * 4;
    int h = h0 + hl;
    size_t idx = base + (size_t)h * Wn + w4;
    size_t aidx = (size_t)b * Nn + (size_t)h * Wn + w4;
    ushort4 o1v = *(const ushort4*)((const unsigned short*)ow1 + idx);
    ushort4 o2v = *(const ushort4*)((const unsigned short*)ow2 + idx);
    float4 a1h4 = *(const float4*)(a1h + aidx);
    float4 a1w4 = *(const float4*)(a1w + aidx);
    float4 a2h4 = *(const float4*)(a2h + aidx);
    float4 a2w4 = *(const float4*)(a2w + aidx);
    float4 xv4  = *(const float4*)(x + idx);
    float4 mn4  = *(const float4*)(msp + aidx);
    float r[4];
    #pragma unroll
    for (int j = 0; j < 4; ++j){
      unsigned short u1 = t1[hl][w4 + j];
      unsigned short u2 = t2[hl][w4 + j];
      unsigned short w1 = ((const unsigned short*)&o1v)[j];
      unsigned short w2 = ((const unsigned short*)&o2v)[j];
      float oh1v = bf2f(*(bf16*)&u1), ow1v = bf2f(*(bf16*)&w1);
      float oh2v = bf2f(*(bf16*)&u2), ow2v = bf2f(*(bf16*)&w2);
      float term1 = g * (((const float*)&a1h4)[j] * oh1v + ((const float*)&a1w4)[j] * ow1v);
      float term2 = g * (((const float*)&a2h4)[j] * oh2v + ((const float*)&a2w4)[j] * ow2v);
      float resid = ((const float*)&xv4)[j] * (mc + ((const float*)&mn4)[j]);
      r[j] = term2 + resid + term1;
    }
    float4 o4 = { r[0], r[1], r[2], r[3] };
    *(float4*)(out + idx) = o4;
  }
}

// ============================ host ============================

static void run_att(const bf16* xT_hi, const bf16* xT_lo,
                    const bf16* wqk_hi, const bf16* wqk_lo, const float* bqk,
                    const bf16* wvb, const float* bv,
                    bf16* qhw, bf16* khw, bf16* v, bf16* vT,
                    float* mh, float* sh, float* mw, float* sw,
                    float* ahT, float* aw, bf16* tmp, hipStream_t stream){
  bf16* ohX = tmp;
  bf16* ow  = tmp + (size_t)Bn * Cn * Nn;
  k_qk_mfma<<<dim3(Nn / 128, Bn), 256, 0, stream>>>(xT_hi, xT_lo, wqk_hi, wqk_lo, bqk,
                                                    qhw, khw);
  k_v_mfma<<<2048, 256, 0, stream>>>(xT_hi, wvb, bv, v);
  k_trans<<<dim3(16, Cn, Bn), 256, 0, stream>>>(v, vT, Cn);
  k_att_h<<<dim3(Wn, Bn), 256, 0, stream>>>(qhw, khw, vT, mh, sh, ohX);
  k_att_w<<<dim3(Hn, Bn), 256, 0, stream>>>(qhw, khw, v, mw, sw, ow);
  k_alpha<<<Bn * Nn / 256, 256, 0, stream>>>(mh, sh, mw, sw, ahT, aw);
}

extern "C" void kernel_launch(void* const* d_in, const int* in_sizes, int n_in,
                              void* d_out, int out_size, void* d_ws, size_t ws_size,
                              hipStream_t stream){
  (void)in_sizes; (void)n_in; (void)out_size; (void)ws_size;
  const float* x         = (const float*)d_in[0];
  const float* w_q_right = (const float*)d_in[1];
  const float* w_v_right = (const float*)d_in[2];
  const float* w_up      = (const float*)d_in[3];
  const float* b_up      = (const float*)d_in[4];
  const float* w_q_left  = (const float*)d_in[5];
  const float* w_v_left  = (const float*)d_in[6];
  const float* wq        = (const float*)d_in[7];
  const float* bq        = (const float*)d_in[8];
  const float* wk        = (const float*)d_in[9];
  const float* bk        = (const float*)d_in[10];
  const float* wv        = (const float*)d_in[11];
  const float* bv        = (const float*)d_in[12];
  const float* gamma     = (const float*)d_in[13];

  const size_t SZ_MAP = (size_t)Bn * Cn * Nn;     // 33.5M elements
  char* p = (char*)d_ws;
  float* buf0   = (float*)p; p += SZ_MAP * 4;     // CA2 tmp (oh2/ow2), CA3 tmp
  float* buf1   = (float*)p; p += SZ_MAP * 4;     // cs_hi/lo during CA1-2; then s
  bf16*  vbuf   = (bf16*)p;  p += SZ_MAP * 2;
  bf16*  vT     = (bf16*)p;  p += SZ_MAP * 2;
  bf16*  qhw    = (bf16*)p;  p += (size_t)Bn * CQn * Nn * 2;
  bf16*  khw    = (bf16*)p;  p += (size_t)Bn * CQn * Nn * 2;
  float* ebuf   = (float*)p; p += (size_t)SZ_MAP * 2;         // xT_hi arena (67MB)
  float* logits = (float*)p; p += (size_t)Bn * Nn * 4;
  float* ctxlog = (float*)p; p += (size_t)Bn * Nn * 4;
  float* msp    = (float*)p; p += (size_t)Bn * Nn * 4;
  float* xbar   = (float*)p; p += Bn * Cn * 4;
  float* wgt    = (float*)p; p += Bn * Cn * 4;
  float* u      = (float*)p; p += Bn * Cn * 4;
  float* mch    = (float*)p; p += Bn * Cn * 4;
  float* avg    = (float*)p; p += Bn * CIn * 4;
  float* ctx    = (float*)p; p += Bn * CIn * 4;
  float* stats_sp = (float*)p; p += 64;
  float* stats_ch = (float*)p; p += 64;
  bf16*  wvb    = (bf16*)p;  p += (size_t)Cn * Cn * 2;
  bf16*  wqk_hi = (bf16*)p;  p += (size_t)128 * Cn * 2;
  bf16*  wqk_lo = (bf16*)p;  p += (size_t)128 * Cn * 2;
  float* bqk    = (float*)p; p += 128 * 4;
  float* mh     = (float*)p; p += (size_t)Bn * Nn * 4;
  float* sh     = (float*)p; p += (size_t)Bn * Nn * 4;
  float* mw     = (float*)p; p += (size_t)Bn * Nn * 4;
  float* sw     = (float*)p; p += (size_t)Bn * Nn * 4;
  float* ah1    = (float*)p; p += (size_t)Bn * Nn * 4;
  float* aw1    = (float*)p; p += (size_t)Bn * Nn * 4;
  float* ah2    = (float*)p; p += (size_t)Bn * Nn * 4;
  float* aw2    = (float*)p; p += (size_t)Bn * Nn * 4;
  float* pxb    = (float*)p; p += (size_t)Bn * 64 * Cn * 4;   // 512KB partials

  bf16*  cc_hi  = (bf16*)ebuf;               // dead after CA1's v_mfma
  bf16*  cc_lo  = (bf16*)d_out;              // dead after CA1's qk_mfma
  bf16*  cs_hi  = (bf16*)buf1;               // dead after CA2's v_mfma
  bf16*  cs_lo  = (bf16*)buf1 + SZ_MAP;      // dead after CA2's qk_mfma
  bf16*  xT_hi3 = (bf16*)ebuf;               // CA3 set
  bf16*  xT_lo3 = (bf16*)d_out;              // d_out free after fuse3 consumed oh1/ow1

  // ---- weight prep (once) ----
  k_cvt_w<<<(Cn * Cn + 255) / 256, 256, 0, stream>>>(wv, wvb, Cn * Cn);
  k_prep_wqk<<<(128 * Cn) / 256, 256, 0, stream>>>(wq, wk, bq, bk, wqk_hi, wqk_lo, bqk);

  // ---- stage 0: gating masks (fused dual-purpose x passes) ----
  k_pass1<<<dim3(Nn / 256, Bn), 256, 0, stream>>>(x, w_q_right, logits, pxb);
  k_red1<<<Bn * Cn / 256, 256, 0, stream>>>(pxb, xbar, 1.f / Nn);
  k_rowdot<<<Bn, 256, 0, stream>>>(w_q_left, xbar, avg);
  k_coldot<<<dim3(Cn / 256, Bn), 256, 0, stream>>>(w_v_left, avg, u);
  k_stats<<<Bn, 1024, 0, stream>>>(logits, stats_sp);
  k_pass2<<<dim3(Nn / 256, Bn), 256, 0, stream>>>(x, u, logits, stats_sp, ctxlog, pxb);
  k_stats<<<Bn, 1024, 0, stream>>>(ctxlog, stats_ch);
  k_red2<<<Bn * Cn / 256, 256, 0, stream>>>(pxb, stats_sp, wgt);
  k_rowdot<<<Bn, 256, 0, stream>>>(w_v_right, wgt, ctx);
  k_mch2<<<dim3(Cn / 256, Bn), 256, 0, stream>>>(w_up, b_up, ctx, mch);
  k_msp<<<Bn * Nn / 256, 256, 0, stream>>>(ctxlog, stats_ch, msp);

  // single x pass: both cc and cs transposed hi/lo sets
  k_applyT3<<<dim3(Nn / 32, Cn / 32, Bn), 256, 0, stream>>>(x, mch, msp,
                                                            cc_hi, cc_lo, cs_hi, cs_lo);

  // ---- CA1 attention only: oh1/ow1 -> d_out, alphas -> ah1/aw1 (no fuse) ----
  run_att(cc_hi, cc_lo, wqk_hi, wqk_lo, bqk, wvb, bv,
          qhw, khw, vbuf, vT, mh, sh, mw, sw, ah1, aw1, (bf16*)d_out, stream);
  // ---- CA2 attention: oh2/ow2 -> buf0, alphas -> ah2/aw2 ----
  run_att(cs_hi, cs_lo, wqk_hi, wqk_lo, bqk, wvb, bv,
          qhw, khw, vbuf, vT, mh, sh, mw, sw, ah2, aw2, (bf16*)buf0, stream);
  // ---- combined fuse: s = g*att1 + g*att2 + x*(mch+msp) -> buf1 ----
  k_fuse3<<<dim3(Cn, 2, Bn), 256, 0, stream>>>(x, mch, msp,
                                               (const bf16*)d_out,
                                               (const bf16*)d_out + SZ_MAP, ah1, aw1,
                                               (const bf16*)buf0,
                                               (const bf16*)buf0 + SZ_MAP, ah2, aw2,
                                               gamma, buf1);
  // ---- CA3: in = s = buf1; tmp = buf0; out = d_out ----
  k_cvt_T<<<dim3(Nn / 32, Cn / 32, Bn), 256, 0, stream>>>(buf1, xT_hi3, xT_lo3);
  run_att(xT_hi3, xT_lo3, wqk_hi, wqk_lo, bqk, wvb, bv,
          qhw, khw, vbuf, vT, mh, sh, mw, sw, ah1, aw1, (bf16*)buf0, stream);
  k_fuse2<<<dim3(Cn, 2, Bn), 256, 0, stream>>>(buf1, (const bf16*)buf0,
                                               (const bf16*)buf0 + SZ_MAP, ah1, aw1,
                                               gamma, (float*)d_out);
}

// Round 18
// 1274.501 us; speedup vs baseline: 1.3323x; 1.3323x over previous
//
#include <hip/hip_runtime.h>
#include <hip/hip_bf16.h>
#include <math.h>

typedef __hip_bfloat16 bf16;
typedef __attribute__((ext_vector_type(8))) short s16x8;
typedef __attribute__((ext_vector_type(4))) float f32x4;

constexpr int Bn  = 4;
constexpr int Cn  = 512;
constexpr int Hn  = 128;
constexpr int Wn  = 128;
constexpr int Nn  = Hn * Wn;   // 16384
constexpr int CQn = 64;
constexpr int CIn = 256;

__device__ __forceinline__ float bf2f(bf16 v){ return __bfloat162float(v); }
__device__ __forceinline__ bf16  f2bf(float v){ return __float2bfloat16(v); }

// async global->LDS, 16B per lane; LDS dest must be wave-uniform base (HW adds lane*16)
__device__ __forceinline__ void gload_lds16(const void* g, void* l){
  __builtin_amdgcn_global_load_lds(
      (const __attribute__((address_space(1))) unsigned int*)g,
      (__attribute__((address_space(3))) unsigned int*)l,
      16, 0, 0);
}

// ============================ stage 0 ============================

__global__ __launch_bounds__(256) void k_dotc(const float* __restrict__ x,
                                              const float* __restrict__ w,
                                              int wstride,
                                              float* __restrict__ out){
  int t = blockIdx.x * 256 + threadIdx.x;      // over B*Nn
  int b = t >> 14;
  const float* wp = w + (size_t)b * wstride;
  const float* xp = x + (size_t)b * Cn * Nn + (t & (Nn - 1));
  float acc = 0.f;
  #pragma unroll 8
  for (int c = 0; c < Cn; ++c) acc += wp[c] * xp[(size_t)c * Nn];
  out[t] = acc;
}

__global__ __launch_bounds__(256) void k_rowmean(const float* __restrict__ x,
                                                 float* __restrict__ out,
                                                 float scale){
  int bc = blockIdx.x;
  const float* xp = x + (size_t)bc * Nn;
  float acc = 0.f;
  for (int n = threadIdx.x; n < Nn; n += 256) acc += xp[n];
  for (int o = 32; o > 0; o >>= 1) acc += __shfl_down(acc, o);
  __shared__ float red[4];
  if ((threadIdx.x & 63) == 0) red[threadIdx.x >> 6] = acc;
  __syncthreads();
  if (threadIdx.x == 0) out[bc] = (red[0] + red[1] + red[2] + red[3]) * scale;
}

__global__ __launch_bounds__(256) void k_rowdot(const float* __restrict__ W,
                                                const float* __restrict__ vec,
                                                float* __restrict__ out){
  __shared__ float vs[Cn];
  int b = blockIdx.x, t = threadIdx.x;
  for (int j = t; j < Cn; j += 256) vs[j] = vec[b * Cn + j];
  __syncthreads();
  const float4* wp = (const float4*)(W + (size_t)t * Cn);
  float a = 0.f;
  #pragma unroll 4
  for (int j = 0; j < Cn / 4; ++j){
    float4 w4 = wp[j];
    a += w4.x * vs[4*j] + w4.y * vs[4*j+1] + w4.z * vs[4*j+2] + w4.w * vs[4*j+3];
  }
  out[b * CIn + t] = a;
}

__global__ __launch_bounds__(256) void k_coldot(const float* __restrict__ W,
                                                const float* __restrict__ vec,
                                                float* __restrict__ out){
  __shared__ float vs[CIn];
  int b = blockIdx.y, t = threadIdx.x;
  int c = blockIdx.x * 256 + t;
  if (t < CIn) vs[t] = vec[b * CIn + t];
  __syncthreads();
  float a = 0.f;
  #pragma unroll 8
  for (int j = 0; j < CIn; ++j) a += W[(size_t)j * Cn + c] * vs[j];
  out[b * Cn + c] = a;
}

__global__ __launch_bounds__(256) void k_mch2(const float* __restrict__ w_up,
                                              const float* __restrict__ b_up,
                                              const float* __restrict__ ctx,
                                              float* __restrict__ mch){
  __shared__ float cs[CIn];
  int b = blockIdx.y, t = threadIdx.x;
  int o = blockIdx.x * 256 + t;
  if (t < CIn) cs[t] = ctx[b * CIn + t];
  __syncthreads();
  const float4* wp = (const float4*)(w_up + (size_t)o * CIn);
  float a = b_up[o];
  #pragma unroll 4
  for (int j = 0; j < CIn / 4; ++j){
    float4 w4 = wp[j];
    a += w4.x * cs[4*j] + w4.y * cs[4*j+1] + w4.z * cs[4*j+2] + w4.w * cs[4*j+3];
  }
  mch[b * Cn + o] = 1.f / (1.f + expf(-a));
}

__global__ __launch_bounds__(1024) void k_stats(const float* __restrict__ vv,
                                                float* __restrict__ stats){
  int b = blockIdx.x;
  const float* pp = vv + (size_t)b * Nn;
  int t = threadIdx.x;
  float m = -3.4e38f;
  for (int n = t; n < Nn; n += 1024) m = fmaxf(m, pp[n]);
  for (int o = 32; o > 0; o >>= 1) m = fmaxf(m, __shfl_down(m, o));
  __shared__ float red[16];
  int wid = t >> 6, lid = t & 63;
  if (lid == 0) red[wid] = m;
  __syncthreads();
  if (t == 0){
    float q = red[0];
    for (int i = 1; i < 16; i++) q = fmaxf(q, red[i]);
    red[0] = q;
  }
  __syncthreads();
  m = red[0];
  __syncthreads();
  float s = 0.f;
  for (int n = t; n < Nn; n += 1024) s += expf(pp[n] - m);
  for (int o = 32; o > 0; o >>= 1) s += __shfl_down(s, o);
  if (lid == 0) red[wid] = s;
  __syncthreads();
  if (t == 0){
    float q = 0.f;
    for (int i = 0; i < 16; i++) q += red[i];
    stats[b * 2]     = m;
    stats[b * 2 + 1] = q;
  }
}

__global__ __launch_bounds__(256) void k_weighted(const float* __restrict__ x,
                                                  const float* __restrict__ logits,
                                                  const float* __restrict__ stats,
                                                  float* __restrict__ out){
  int bc = blockIdx.x;
  int b = bc >> 9;
  const float* xp = x + (size_t)bc * Nn;
  const float* lp = logits + (size_t)b * Nn;
  float m = stats[b * 2], den = stats[b * 2 + 1];
  float acc = 0.f;
  for (int n = threadIdx.x; n < Nn; n += 256) acc += xp[n] * expf(lp[n] - m);
  for (int o = 32; o > 0; o >>= 1) acc += __shfl_down(acc, o);
  __shared__ float red[4];
  if ((threadIdx.x & 63) == 0) red[threadIdx.x >> 6] = acc;
  __syncthreads();
  if (threadIdx.x == 0) out[bc] = (red[0] + red[1] + red[2] + red[3]) / den;
}

__global__ __launch_bounds__(256) void k_msp(const float* __restrict__ lg,
                                             const float* __restrict__ stats,
                                             float* __restrict__ msp){
  int t = blockIdx.x * 256 + threadIdx.x;
  int b = t >> 14;
  float v = expf(lg[t] - stats[b * 2]) / stats[b * 2 + 1];
  msp[t] = 1.f / (1.f + expf(-v));
}

// Single x pass: cc = x*mch -> cc_hi/lo; cs = x*msp -> cs_hi/lo (all transposed [b][n][c])
__global__ __launch_bounds__(256) void k_applyT3(const float* __restrict__ x,
                                                 const float* __restrict__ mch,
                                                 const float* __restrict__ msp,
                                                 bf16* __restrict__ cc_hi,
                                                 bf16* __restrict__ cc_lo,
                                                 bf16* __restrict__ cs_hi,
                                                 bf16* __restrict__ cs_lo){
  __shared__ bf16 tch[32][33], tcl[32][33], tsh[32][33], tsl[32][33];
  int nt = blockIdx.x, ct = blockIdx.y, b = blockIdx.z;
  int n0 = nt * 32, c0 = ct * 32;
  int t = threadIdx.x;
  #pragma unroll
  for (int kk = 0; kk < 4; ++kk){
    int idx = t + kk * 256;
    int cl = idx >> 5, nl = idx & 31;
    float xv = x[((size_t)(b * Cn + c0 + cl)) * Nn + n0 + nl];
    float ccv = xv * mch[b * Cn + c0 + cl];
    float csv = xv * msp[b * Nn + n0 + nl];
    bf16 h1 = f2bf(ccv);
    tch[cl][nl] = h1;
    tcl[cl][nl] = f2bf(ccv - bf2f(h1));
    bf16 h2 = f2bf(csv);
    tsh[cl][nl] = h2;
    tsl[cl][nl] = f2bf(csv - bf2f(h2));
  }
  __syncthreads();
  #pragma unroll
  for (int kk = 0; kk < 4; ++kk){
    int idx = t + kk * 256;
    int nl = idx >> 5, cl = idx & 31;
    size_t o = ((size_t)(b * Nn + n0 + nl)) * Cn + c0 + cl;
    cc_hi[o] = tch[cl][nl];
    cc_lo[o] = tcl[cl][nl];
    cs_hi[o] = tsh[cl][nl];
    cs_lo[o] = tsl[cl][nl];
  }
}

// ============================ conversions ============================

__global__ __launch_bounds__(256) void k_cvt_w(const float* __restrict__ in,
                                               bf16* __restrict__ out, int n){
  int t = blockIdx.x * 256 + threadIdx.x;
  if (t < n) out[t] = f2bf(in[t]);
}

__global__ __launch_bounds__(256) void k_prep_wqk(const float* __restrict__ wq,
                                                  const float* __restrict__ wk,
                                                  const float* __restrict__ bq,
                                                  const float* __restrict__ bk,
                                                  bf16* __restrict__ wqk_hi,
                                                  bf16* __restrict__ wqk_lo,
                                                  float* __restrict__ bqk){
  int t = blockIdx.x * 256 + threadIdx.x;   // over 128*512
  int o = t >> 9, c = t & 511;
  float v = (o < 64) ? wq[(size_t)o * Cn + c] : wk[(size_t)(o - 64) * Cn + c];
  bf16 h = f2bf(v);
  wqk_hi[t] = h;
  wqk_lo[t] = f2bf(v - bf2f(h));
  if (t < 128) bqk[t] = (t < 64) ? bq[t] : bk[t - 64];
}

__global__ __launch_bounds__(256) void k_cvt_T(const float* __restrict__ in,
                                               bf16* __restrict__ out_hi,
                                               bf16* __restrict__ out_lo){
  __shared__ bf16 th_[32][33];
  __shared__ bf16 tl_[32][33];
  int nt = blockIdx.x, ct = blockIdx.y, b = blockIdx.z;
  int n0 = nt * 32, c0 = ct * 32;
  int t = threadIdx.x;
  #pragma unroll
  for (int kk = 0; kk < 4; ++kk){
    int idx = t + kk * 256;
    int cl = idx >> 5, nl = idx & 31;
    float v = in[((size_t)(b * Cn + c0 + cl)) * Nn + n0 + nl];
    bf16 h = f2bf(v);
    th_[cl][nl] = h;
    tl_[cl][nl] = f2bf(v - bf2f(h));
  }
  __syncthreads();
  #pragma unroll
  for (int kk = 0; kk < 4; ++kk){
    int idx = t + kk * 256;
    int nl = idx >> 5, cl = idx & 31;
    size_t o = ((size_t)(b * Nn + n0 + nl)) * Cn + c0 + cl;
    out_hi[o] = th_[cl][nl];
    out_lo[o] = tl_[cl][nl];
  }
}

// ============================ MFMA GEMMs ============================

// V = Wv @ X. 128x128 tile, BK=64. XCD-chunked 1D grid of 2048.
__global__ __launch_bounds__(256) void k_v_mfma(const bf16* __restrict__ xT,
                                                const bf16* __restrict__ wvb,
                                                const float* __restrict__ bv,
                                                bf16* __restrict__ v){
  __shared__ short As[128 * 64];
  __shared__ short Bs[128 * 64];
  __shared__ float bvs[128];
  int lin = blockIdx.x;
  int swz = (lin & 7) * 256 + (lin >> 3);
  int cb = (swz & 3) * 128;
  int nb = ((swz >> 2) & 127) * 128;
  int b  = swz >> 9;
  int t = threadIdx.x, lane = t & 63, wid = t >> 6;
  int wm = wid >> 1, wn = wid & 1;
  int l15 = lane & 15, l4 = lane >> 4;
  if (t < 128) bvs[t] = bv[cb + t];
  f32x4 acc[4][4];
  #pragma unroll
  for (int i = 0; i < 4; i++)
    #pragma unroll
    for (int j = 0; j < 4; j++) acc[i][j] = (f32x4){0.f, 0.f, 0.f, 0.f};

  const bf16* wp = wvb + (size_t)cb * Cn;
  const bf16* xp = xT + ((size_t)b * Nn + nb) * Cn;
  int r8 = lane >> 3;
  int kc = (lane & 7) * 8;
  for (int kt = 0; kt < 8; ++kt){
    int k0 = kt * 64;
    #pragma unroll
    for (int j = 0; j < 4; ++j){
      int inst = wid * 4 + j;
      int row = inst * 8 + r8;
      gload_lds16(wp + (size_t)row * Cn + k0 + kc, (char*)As + inst * 1024);
      gload_lds16(xp + (size_t)row * Cn + k0 + kc, (char*)Bs + inst * 1024);
    }
    __syncthreads();
    #pragma unroll
    for (int kk = 0; kk < 64; kk += 32){
      s16x8 a[4], bb[4];
      #pragma unroll
      for (int mi = 0; mi < 4; mi++)
        a[mi] = *(const s16x8*)&As[(wm * 64 + mi * 16 + l15) * 64 + kk + l4 * 8];
      #pragma unroll
      for (int ni = 0; ni < 4; ni++)
        bb[ni] = *(const s16x8*)&Bs[(wn * 64 + ni * 16 + l15) * 64 + kk + l4 * 8];
      #pragma unroll
      for (int mi = 0; mi < 4; mi++)
        #pragma unroll
        for (int ni = 0; ni < 4; ni++)
          acc[mi][ni] = __builtin_amdgcn_mfma_f32_16x16x32_bf16(a[mi], bb[ni], acc[mi][ni], 0, 0, 0);
    }
    __syncthreads();
  }
  #pragma unroll
  for (int mi = 0; mi < 4; mi++){
    #pragma unroll
    for (int r = 0; r < 4; r++){
      int cl = wm * 64 + mi * 16 + l4 * 4 + r;
      int c  = cb + cl;
      float bias = bvs[cl];
      #pragma unroll
      for (int ni = 0; ni < 4; ni++){
        int n = nb + wn * 64 + ni * 16 + l15;
        v[((size_t)(b * Cn + c)) * Nn + n] = f2bf(acc[mi][ni][r] + bias);
      }
    }
  }
}

// Q,K = [Wq;Wk] @ X, split-precision bf16 (3 MFMA terms).
// Writes qhw/khw ([b][w][h][c]) DIRECTLY via LDS transpose epilogue (no std q/k).
__global__ __launch_bounds__(256) void k_qk_mfma(const bf16* __restrict__ xT_hi,
                                                 const bf16* __restrict__ xT_lo,
                                                 const bf16* __restrict__ wqk_hi,
                                                 const bf16* __restrict__ wqk_lo,
                                                 const float* __restrict__ bqk,
                                                 bf16* __restrict__ qhw,
                                                 bf16* __restrict__ khw){
  __shared__ char smem[65536];
  short* Ah = (short*)smem;
  short* Al = Ah + 8192;
  short* Bh = Al + 8192;
  short* Bl = Bh + 8192;
  char*  Os = smem;                 // reused after final K-loop barrier (32KB)
  __shared__ float bs[128];
  int h = blockIdx.x, b = blockIdx.y;      // block covers n = h*128 + w, w=0..127
  int nb = h * 128;
  int t = threadIdx.x, lane = t & 63, wid = t >> 6;
  int wm = wid >> 1, wn = wid & 1;
  int l15 = lane & 15, l4 = lane >> 4;
  if (t < 128) bs[t] = bqk[t];
  f32x4 acc[4][4];
  #pragma unroll
  for (int i = 0; i < 4; i++)
    #pragma unroll
    for (int j = 0; j < 4; j++) acc[i][j] = (f32x4){0.f, 0.f, 0.f, 0.f};

  const bf16* xh = xT_hi + ((size_t)b * Nn + nb) * Cn;
  const bf16* xl = xT_lo + ((size_t)b * Nn + nb) * Cn;
  int r8 = lane >> 3;
  int kc = (lane & 7) * 8;
  for (int kt = 0; kt < 8; ++kt){
    int k0 = kt * 64;
    #pragma unroll
    for (int j = 0; j < 4; ++j){
      int inst = wid * 4 + j;
      int row = inst * 8 + r8;
      size_t off = (size_t)row * Cn + k0 + kc;
      gload_lds16(wqk_hi + off, (char*)Ah + inst * 1024);
      gload_lds16(wqk_lo + off, (char*)Al + inst * 1024);
      gload_lds16(xh + off,     (char*)Bh + inst * 1024);
      gload_lds16(xl + off,     (char*)Bl + inst * 1024);
    }
    __syncthreads();
    #pragma unroll
    for (int kk = 0; kk < 64; kk += 32){
      s16x8 ah[4], al[4], bh[4], bl[4];
      #pragma unroll
      for (int mi = 0; mi < 4; mi++){
        int idx = (wm * 64 + mi * 16 + l15) * 64 + kk + l4 * 8;
        ah[mi] = *(const s16x8*)&Ah[idx];
        al[mi] = *(const s16x8*)&Al[idx];
      }
      #pragma unroll
      for (int ni = 0; ni < 4; ni++){
        int idx = (wn * 64 + ni * 16 + l15) * 64 + kk + l4 * 8;
        bh[ni] = *(const s16x8*)&Bh[idx];
        bl[ni] = *(const s16x8*)&Bl[idx];
      }
      #pragma unroll
      for (int mi = 0; mi < 4; mi++)
        #pragma unroll
        for (int ni = 0; ni < 4; ni++){
          acc[mi][ni] = __builtin_amdgcn_mfma_f32_16x16x32_bf16(ah[mi], bh[ni], acc[mi][ni], 0, 0, 0);
          acc[mi][ni] = __builtin_amdgcn_mfma_f32_16x16x32_bf16(ah[mi], bl[ni], acc[mi][ni], 0, 0, 0);
          acc[mi][ni] = __builtin_amdgcn_mfma_f32_16x16x32_bf16(al[mi], bh[ni], acc[mi][ni], 0, 0, 0);
        }
    }
    __syncthreads();
  }
  // epilogue: Os[n][o] bf16 (256B rows, XOR-swizzled), then 128B row stores
  #pragma unroll
  for (int mi = 0; mi < 4; mi++){
    #pragma unroll
    for (int r = 0; r < 4; r++){
      int o = wm * 64 + mi * 16 + l4 * 4 + r;
      float bias = bs[o];
      #pragma unroll
      for (int ni = 0; ni < 4; ni++){
        int n = wn * 64 + ni * 16 + l15;
        bf16 bv = f2bf(acc[mi][ni][r] + bias);
        int byte = (n * 256 + o * 2) ^ ((n & 7) << 4);
        *(unsigned short*)(Os + byte) = *(unsigned short*)&bv;
      }
    }
  }
  __syncthreads();
  #pragma unroll
  for (int i = 0; i < 8; ++i){
    int s = t + i * 256;            // 0..2047: row = s>>3 (w + 128*qk), seg = s&7
    int row = s >> 3, seg = s & 7;
    int w = row & 127, qk = row >> 7;
    int o0 = qk * 64 + seg * 8;
    int byte = (w * 256 + o0 * 2) ^ ((w & 7) << 4);
    s16x8 d = *(const s16x8*)(Os + byte);
    bf16* dst = (qk == 0 ? qhw : khw) + (((size_t)b * Wn + w) * Hn + h) * CQn + seg * 8;
    *(s16x8*)dst = d;
  }
}

// ============================ fused attention ============================

// per (b,w): MFMA e_h from qhw/khw ([b][w][h][c]), diag, stats, p->LDS, PV MFMA.
// ohX layout [b][c][w][h] (unnormalized; alpha in fuse).
__global__ __launch_bounds__(256) void k_att_h(const bf16* __restrict__ qhw,
                                               const bf16* __restrict__ khw,
                                               const bf16* __restrict__ vT,
                                               float* __restrict__ mh,
                                               float* __restrict__ sh,
                                               bf16* __restrict__ ohX){
  __shared__ char smem[65536];
  char* attb = smem;                 // p tile 32KB
  char* vbb  = smem + 32768;         // V tile 32KB (e-phase: first 2KB = stats)
  float* redm = (float*)(smem + 32768);        // [2][128]
  float* reds = redm + 256;                    // [2][128]
  int w = blockIdx.x, b = blockIdx.y;
  int t = threadIdx.x, lane = t & 63, wid = t >> 6;
  int wm = wid >> 1, wn = wid & 1;
  int l15 = lane & 15, l4 = lane >> 4;

  const bf16* qp = qhw + ((size_t)(b * Wn + w)) * (Hn * CQn);
  const bf16* kp = khw + ((size_t)(b * Wn + w)) * (Hn * CQn);
  f32x4 acc[4][4];
  #pragma unroll
  for (int i = 0; i < 4; i++)
    #pragma unroll
    for (int j = 0; j < 4; j++) acc[i][j] = (f32x4){0.f, 0.f, 0.f, 0.f};
  #pragma unroll
  for (int kk = 0; kk < 64; kk += 32){
    s16x8 a[4], bb[4];
    #pragma unroll
    for (int mi = 0; mi < 4; mi++)
      a[mi] = *(const s16x8*)(qp + (size_t)(wm * 64 + mi * 16 + l15) * CQn + kk + l4 * 8);
    #pragma unroll
    for (int ni = 0; ni < 4; ni++)
      bb[ni] = *(const s16x8*)(kp + (size_t)(wn * 64 + ni * 16 + l15) * CQn + kk + l4 * 8);
    #pragma unroll
    for (int mi = 0; mi < 4; mi++)
      #pragma unroll
      for (int ni = 0; ni < 4; ni++)
        acc[mi][ni] = __builtin_amdgcn_mfma_f32_16x16x32_bf16(a[mi], bb[ni], acc[mi][ni], 0, 0, 0);
  }
  // diag mask: h==g
  if (wm == wn){
    #pragma unroll
    for (int mi = 0; mi < 4; mi++)
      #pragma unroll
      for (int r = 0; r < 4; r++)
        if (l15 == l4 * 4 + r) acc[mi][mi][r] = -1e30f;
  }
  float rm[4][4];
  #pragma unroll
  for (int mi = 0; mi < 4; mi++)
    #pragma unroll
    for (int r = 0; r < 4; r++){
      float m = fmaxf(fmaxf(acc[mi][0][r], acc[mi][1][r]),
                      fmaxf(acc[mi][2][r], acc[mi][3][r]));
      m = fmaxf(m, __shfl_xor(m, 1));
      m = fmaxf(m, __shfl_xor(m, 2));
      m = fmaxf(m, __shfl_xor(m, 4));
      m = fmaxf(m, __shfl_xor(m, 8));
      rm[mi][r] = m;
    }
  if (l15 == 0){
    #pragma unroll
    for (int mi = 0; mi < 4; mi++)
      #pragma unroll
      for (int r = 0; r < 4; r++)
        redm[wn * 128 + wm * 64 + mi * 16 + l4 * 4 + r] = rm[mi][r];
  }
  __syncthreads();
  float rs[4][4];
  #pragma unroll
  for (int mi = 0; mi < 4; mi++)
    #pragma unroll
    for (int r = 0; r < 4; r++){
      int h = wm * 64 + mi * 16 + l4 * 4 + r;
      float m = fmaxf(redm[h], redm[128 + h]);
      rm[mi][r] = m;
      float s = 0.f;
      #pragma unroll
      for (int ni = 0; ni < 4; ni++){
        acc[mi][ni][r] = expf(acc[mi][ni][r] - m);
        s += acc[mi][ni][r];
      }
      s += __shfl_xor(s, 1);
      s += __shfl_xor(s, 2);
      s += __shfl_xor(s, 4);
      s += __shfl_xor(s, 8);
      rs[mi][r] = s;
    }
  if (l15 == 0){
    #pragma unroll
    for (int mi = 0; mi < 4; mi++)
      #pragma unroll
      for (int r = 0; r < 4; r++)
        reds[wn * 128 + wm * 64 + mi * 16 + l4 * 4 + r] = rs[mi][r];
  }
  __syncthreads();
  #pragma unroll
  for (int mi = 0; mi < 4; mi++)
    #pragma unroll
    for (int r = 0; r < 4; r++){
      int h = wm * 64 + mi * 16 + l4 * 4 + r;
      if (wn == 0 && l15 == 0){
        mh[(size_t)(b * Wn + w) * Hn + h] = rm[mi][r];
        sh[(size_t)(b * Wn + w) * Hn + h] = reds[h] + reds[128 + h];
      }
      #pragma unroll
      for (int ni = 0; ni < 4; ni++){
        int g = wn * 64 + ni * 16 + l15;
        bf16 bv = f2bf(acc[mi][ni][r]);
        int byte = (h * 256 + g * 2) ^ ((h & 7) << 4);
        *(unsigned short*)(attb + byte) = *(unsigned short*)&bv;
      }
    }
  __syncthreads();
  // PV MFMA over 4 c-tiles
  for (int cb = 0; cb < Cn; cb += 128){
    const bf16* vp = vT + ((size_t)(b * Wn + w) * Cn + cb) * Hn;
    for (int s = t; s < 2048; s += 256){
      int row = s >> 4, seg = s & 15;
      s16x8 d = *(const s16x8*)(vp + (size_t)row * Hn + seg * 8);
      int byte = (row * 256 + seg * 16) ^ ((row & 7) << 4);
      *(s16x8*)(vbb + byte) = d;
    }
    __syncthreads();
    f32x4 acc2[4][4];
    #pragma unroll
    for (int i = 0; i < 4; i++)
      #pragma unroll
      for (int j = 0; j < 4; j++) acc2[i][j] = (f32x4){0.f, 0.f, 0.f, 0.f};
    #pragma unroll
    for (int kk = 0; kk < 128; kk += 32){
      s16x8 a[4], bb[4];
      #pragma unroll
      for (int mi = 0; mi < 4; mi++){
        int row = wm * 64 + mi * 16 + l15;
        int byte = (row * 256 + (kk + l4 * 8) * 2) ^ ((row & 7) << 4);
        a[mi] = *(const s16x8*)(vbb + byte);
      }
      #pragma unroll
      for (int ni = 0; ni < 4; ni++){
        int row = wn * 64 + ni * 16 + l15;
        int byte = (row * 256 + (kk + l4 * 8) * 2) ^ ((row & 7) << 4);
        bb[ni] = *(const s16x8*)(attb + byte);
      }
      #pragma unroll
      for (int mi = 0; mi < 4; mi++)
        #pragma unroll
        for (int ni = 0; ni < 4; ni++)
          acc2[mi][ni] = __builtin_amdgcn_mfma_f32_16x16x32_bf16(a[mi], bb[ni], acc2[mi][ni], 0, 0, 0);
    }
    bf16* op = ohX + ((size_t)(b * Cn + cb)) * Nn + (size_t)w * Hn;
    #pragma unroll
    for (int mi = 0; mi < 4; mi++)
      #pragma unroll
      for (int r = 0; r < 4; r++){
        int cl = wm * 64 + mi * 16 + l4 * 4 + r;
        #pragma unroll
        for (int ni = 0; ni < 4; ni++){
          int h = wn * 64 + ni * 16 + l15;
          op[(size_t)cl * Nn + h] = f2bf(acc2[mi][ni][r]);
        }
      }
    __syncthreads();
  }
}

// per (b,h): MFMA e_w from qhw/khw (strided rows), stats, p->LDS, PV MFMA.
__global__ __launch_bounds__(256) void k_att_w(const bf16* __restrict__ qhw,
                                               const bf16* __restrict__ khw,
                                               const bf16* __restrict__ v,
                                               float* __restrict__ mw,
                                               float* __restrict__ sw,
                                               bf16* __restrict__ ow){
  __shared__ char smem[65536];
  char* attb = smem;
  char* vbb  = smem + 32768;
  float* redm = (float*)(smem + 32768);
  float* reds = redm + 256;
  int h = blockIdx.x, b = blockIdx.y;
  int t = threadIdx.x, lane = t & 63, wid = t >> 6;
  int wm = wid >> 1, wn = wid & 1;
  int l15 = lane & 15, l4 = lane >> 4;

  const bf16* qp = qhw + (size_t)b * Wn * Hn * CQn + (size_t)h * CQn;
  const bf16* kp = khw + (size_t)b * Wn * Hn * CQn + (size_t)h * CQn;
  f32x4 acc[4][4];
  #pragma unroll
  for (int i = 0; i < 4; i++)
    #pragma unroll
    for (int j = 0; j < 4; j++) acc[i][j] = (f32x4){0.f, 0.f, 0.f, 0.f};
  #pragma unroll
  for (int kk = 0; kk < 64; kk += 32){
    s16x8 a[4], bb[4];
    #pragma unroll
    for (int mi = 0; mi < 4; mi++)
      a[mi] = *(const s16x8*)(qp + (size_t)(wm * 64 + mi * 16 + l15) * (Hn * CQn) + kk + l4 * 8);
    #pragma unroll
    for (int ni = 0; ni < 4; ni++)
      bb[ni] = *(const s16x8*)(kp + (size_t)(wn * 64 + ni * 16 + l15) * (Hn * CQn) + kk + l4 * 8);
    #pragma unroll
    for (int mi = 0; mi < 4; mi++)
      #pragma unroll
      for (int ni = 0; ni < 4; ni++)
        acc[mi][ni] = __builtin_amdgcn_mfma_f32_16x16x32_bf16(a[mi], bb[ni], acc[mi][ni], 0, 0, 0);
  }
  float rm[4][4];
  #pragma unroll
  for (int mi = 0; mi < 4; mi++)
    #pragma unroll
    for (int r = 0; r < 4; r++){
      float m = fmaxf(fmaxf(acc[mi][0][r], acc[mi][1][r]),
                      fmaxf(acc[mi][2][r], acc[mi][3][r]));
      m = fmaxf(m, __shfl_xor(m, 1));
      m = fmaxf(m, __shfl_xor(m, 2));
      m = fmaxf(m, __shfl_xor(m, 4));
      m = fmaxf(m, __shfl_xor(m, 8));
      rm[mi][r] = m;
    }
  if (l15 == 0){
    #pragma unroll
    for (int mi = 0; mi < 4; mi++)
      #pragma unroll
      for (int r = 0; r < 4; r++)
        redm[wn * 128 + wm * 64 + mi * 16 + l4 * 4 + r] = rm[mi][r];
  }
  __syncthreads();
  float rs[4][4];
  #pragma unroll
  for (int mi = 0; mi < 4; mi++)
    #pragma unroll
    for (int r = 0; r < 4; r++){
      int wr = wm * 64 + mi * 16 + l4 * 4 + r;
      float m = fmaxf(redm[wr], redm[128 + wr]);
      rm[mi][r] = m;
      float s = 0.f;
      #pragma unroll
      for (int ni = 0; ni < 4; ni++){
        acc[mi][ni][r] = expf(acc[mi][ni][r] - m);
        s += acc[mi][ni][r];
      }
      s += __shfl_xor(s, 1);
      s += __shfl_xor(s, 2);
      s += __shfl_xor(s, 4);
      s += __shfl_xor(s, 8);
      rs[mi][r] = s;
    }
  if (l15 == 0){
    #pragma unroll
    for (int mi = 0; mi < 4; mi++)
      #pragma unroll
      for (int r = 0; r < 4; r++)
        reds[wn * 128 + wm * 64 + mi * 16 + l4 * 4 + r] = rs[mi][r];
  }
  __syncthreads();
  #pragma unroll
  for (int mi = 0; mi < 4; mi++)
    #pragma unroll
    for (int r = 0; r < 4; r++){
      int wr = wm * 64 + mi * 16 + l4 * 4 + r;
      if (wn == 0 && l15 == 0){
        mw[(size_t)(b * Hn + h) * Wn + wr] = rm[mi][r];
        sw[(size_t)(b * Hn + h) * Wn + wr] = reds[wr] + reds[128 + wr];
      }
      #pragma unroll
      for (int ni = 0; ni < 4; ni++){
        int g = wn * 64 + ni * 16 + l15;
        bf16 bv = f2bf(acc[mi][ni][r]);
        int byte = (wr * 256 + g * 2) ^ ((wr & 7) << 4);
        *(unsigned short*)(attb + byte) = *(unsigned short*)&bv;
      }
    }
  __syncthreads();
  for (int cb = 0; cb < Cn; cb += 128){
    const bf16* vp = v + (size_t)(b * Cn + cb) * Nn + (size_t)h * Wn;
    for (int s = t; s < 2048; s += 256){
      int row = s >> 4, seg = s & 15;
      s16x8 d = *(const s16x8*)(vp + (size_t)row * Nn + seg * 8);
      int byte = (row * 256 + seg * 16) ^ ((row & 7) << 4);
      *(s16x8*)(vbb + byte) = d;
    }
    __syncthreads();
    f32x4 acc2[4][4];
    #pragma unroll
    for (int i = 0; i < 4; i++)
      #pragma unroll
      for (int j = 0; j < 4; j++) acc2[i][j] = (f32x4){0.f, 0.f, 0.f, 0.f};
    #pragma unroll
    for (int kk = 0; kk < 128; kk += 32){
      s16x8 a[4], bb[4];
      #pragma unroll
      for (int mi = 0; mi < 4; mi++){
        int row = wm * 64 + mi * 16 + l15;
        int byte = (row * 256 + (kk + l4 * 8) * 2) ^ ((row & 7) << 4);
        a[mi] = *(const s16x8*)(vbb + byte);
      }
      #pragma unroll
      for (int ni = 0; ni < 4; ni++){
        int row = wn * 64 + ni * 16 + l15;
        int byte = (row * 256 + (kk + l4 * 8) * 2) ^ ((row & 7) << 4);
        bb[ni] = *(const s16x8*)(attb + byte);
      }
      #pragma unroll
      for (int mi = 0; mi < 4; mi++)
        #pragma unroll
        for (int ni = 0; ni < 4; ni++)
          acc2[mi][ni] = __builtin_amdgcn_mfma_f32_16x16x32_bf16(a[mi], bb[ni], acc2[mi][ni], 0, 0, 0);
    }
    bf16* op = ow + (size_t)(b * Cn + cb) * Nn + (size_t)h * Wn;
    #pragma unroll
    for (int mi = 0; mi < 4; mi++)
      #pragma unroll
      for (int r = 0; r < 4; r++){
        int cl = wm * 64 + mi * 16 + l4 * 4 + r;
        #pragma unroll
        for (int ni = 0; ni < 4; ni++){
          int wr = wn * 64 + ni * 16 + l15;
          op[(size_t)cl * Nn + wr] = f2bf(acc2[mi][ni][r]);
        }
      }
    __syncthreads();
  }
}

// merge stats -> alphas, both in [b,h,w] layout for fuse
__global__ __launch_bounds__(256) void k_alpha(const float* __restrict__ mh,
                                               const float* __restrict__ sh,
                                               const float* __restrict__ mw,
                                               const float* __restrict__ sw,
                                               float* __restrict__ ahT,
                                               float* __restrict__ aw){
  int t = blockIdx.x * 256 + threadIdx.x;   // (b*Hn+h)*Wn + w
  int b = t >> 14;
  int hw = t & (Nn - 1);
  int h = hw >> 7, w = hw & 127;
  size_t ih = (size_t)(b * Wn + w) * Hn + h;
  size_t iw = t;
  float mhv = mh[ih], mwv = mw[iw];
  float M = fmaxf(mhv, mwv);
  float eh_ = expf(mhv - M), ew_ = expf(mwv - M);
  float inv = 1.f / (sh[ih] * eh_ + sw[iw] * ew_);
  ahT[t] = eh_ * inv;
  aw[t]  = ew_ * inv;
}

// ============================ remaining CA kernels ============================

__global__ __launch_bounds__(256) void k_trans(const bf16* __restrict__ in,
                                               bf16* __restrict__ out,
                                               int CH){
  __shared__ bf16 tile[32][33];
  int tl = blockIdx.x, c = blockIdx.y, b = blockIdx.z;
  int th = tl >> 2, tw = tl & 3;
  int h0 = th * 32, w0 = tw * 32;
  int t = threadIdx.x;
  const bf16* ip = in + ((size_t)(b * CH + c)) * Nn;
  #pragma unroll
  for (int kk = 0; kk < 4; ++kk){
    int idx = t + kk * 256;
    int hl = idx >> 5, wl = idx & 31;
    tile[hl][wl] = ip[(h0 + hl) * Wn + w0 + wl];
  }
  __syncthreads();
  #pragma unroll
  for (int kk = 0; kk < 4; ++kk){
    int idx = t + kk * 256;
    int wl = idx >> 5, hl = idx & 31;
    out[((size_t)(b * Wn + w0 + wl) * CH + c) * Hn + h0 + hl] = tile[hl][wl];
  }
}

// out = gamma*(ah*ohX^T + aw*ow) + resid  [single attention set]
__global__ __launch_bounds__(256) void k_fuse2(const float* __restrict__ in,
                                               const bf16* __restrict__ ohX,
                                               const bf16* __restrict__ ow,
                                               const float* __restrict__ ahT,
                                               const float* __restrict__ aw,
                                               const float* __restrict__ gamma,
                                               float* __restrict__ out){
  __shared__ unsigned short tileT[64][138];
  int c = blockIdx.x, half = blockIdx.y, b = blockIdx.z;
  int t = threadIdx.x;
  float g = gamma[0];
  int h0 = half * 64;
  const bf16* ohp = ohX + ((size_t)(b * Cn + c)) * Nn;   // [w][h] rows
  #pragma unroll
  for (int i = 0; i < 4; ++i){
    int s = t + i * 256;            // 0..1023: w = s>>3, seg = s&7 (h-chunk)
    int w = s >> 3, seg = s & 7;
    s16x8 d = *(const s16x8*)(ohp + (size_t)w * Hn + h0 + seg * 8);
    #pragma unroll
    for (int j = 0; j < 8; ++j)
      tileT[seg * 8 + j][w] = (unsigned short)d[j];
  }
  __syncthreads();
  size_t base = ((size_t)(b * Cn + c)) * Nn;
  #pragma unroll
  for (int i = 0; i < 8; ++i){
    int o = t + i * 256;            // 0..2047
    int hl = o >> 5, w4 = (o & 31) * 4;
    int h = h0 + hl;
    size_t idx = base + (size_t)h * Wn + w4;
    size_t aidx = (size_t)b * Nn + (size_t)h * Wn + w4;
    ushort4 owv = *(const ushort4*)((const unsigned short*)ow + idx);
    float4 ah4 = *(const float4*)(ahT + aidx);
    float4 aw4 = *(const float4*)(aw + aidx);
    float4 inv = in ? *(const float4*)(in + idx) : (float4){0.f,0.f,0.f,0.f};
    float r[4];
    #pragma unroll
    for (int j = 0; j < 4; ++j){
      unsigned short uh = tileT[hl][w4 + j];
      unsigned short uo = ((const unsigned short*)&owv)[j];
      float ohv = bf2f(*(bf16*)&uh);
      float owf = bf2f(*(bf16*)&uo);
      float ahv = ((const float*)&ah4)[j];
      float awv = ((const float*)&aw4)[j];
      r[j] = g * (ahv * ohv + awv * owf) + ((const float*)&inv)[j];
    }
    float4 o4 = { r[0], r[1], r[2], r[3] };
    *(float4*)(out + idx) = o4;
  }
}

// s = gamma*(a1h*oh1^T + a1w*ow1) + gamma*(a2h*oh2^T + a2w*ow2) + x*(mch+msp)
__global__ __launch_bounds__(256) void k_fuse3(const float* __restrict__ x,
                                               const float* __restrict__ mch,
                                               const float* __restrict__ msp,
                                               const bf16* __restrict__ oh1,
                                               const bf16* __restrict__ ow1,
                                               const float* __restrict__ a1h,
                                               const float* __restrict__ a1w,
                                               const bf16* __restrict__ oh2,
                                               const bf16* __restrict__ ow2,
                                               const float* __restrict__ a2h,
                                               const float* __restrict__ a2w,
                                               const float* __restrict__ gamma,
                                               float* __restrict__ out){
  __shared__ unsigned short t1[64][138];
  __shared__ unsigned short t2[64][138];
  int c = blockIdx.x, half = blockIdx.y, b = blockIdx.z;
  int t = threadIdx.x;
  float g = gamma[0];
  float mc = mch[b * Cn + c];
  int h0 = half * 64;
  const bf16* p1 = oh1 + ((size_t)(b * Cn + c)) * Nn;
  const bf16* p2 = oh2 + ((size_t)(b * Cn + c)) * Nn;
  #pragma unroll
  for (int i = 0; i < 4; ++i){
    int s = t + i * 256;
    int w = s >> 3, seg = s & 7;
    s16x8 d1 = *(const s16x8*)(p1 + (size_t)w * Hn + h0 + seg * 8);
    s16x8 d2 = *(const s16x8*)(p2 + (size_t)w * Hn + h0 + seg * 8);
    #pragma unroll
    for (int j = 0; j < 8; ++j){
      t1[seg * 8 + j][w] = (unsigned short)d1[j];
      t2[seg * 8 + j][w] = (unsigned short)d2[j];
    }
  }
  __syncthreads();
  size_t base = ((size_t)(b * Cn + c)) * Nn;
  #pragma unroll
  for (int i = 0; i < 8; ++i){
    int o = t + i * 256;
    int hl = o >> 5, w4 = (o & 31) * 4;
    int h = h0 + hl;
    size_t idx = base + (size_t)h * Wn + w4;
    size_t aidx = (size_t)b * Nn + (size_t)h * Wn + w4;
    ushort4 o1v = *(const ushort4*)((const unsigned short*)ow1 + idx);
    ushort4 o2v = *(const ushort4*)((const unsigned short*)ow2 + idx);
    float4 a1h4 = *(const float4*)(a1h + aidx);
    float4 a1w4 = *(const float4*)(a1w + aidx);
    float4 a2h4 = *(const float4*)(a2h + aidx);
    float4 a2w4 = *(const float4*)(a2w + aidx);
    float4 xv4  = *(const float4*)(x + idx);
    float4 mn4  = *(const float4*)(msp + aidx);
    float r[4];
    #pragma unroll
    for (int j = 0; j < 4; ++j){
      unsigned short u1 = t1[hl][w4 + j];
      unsigned short u2 = t2[hl][w4 + j];
      unsigned short w1 = ((const unsigned short*)&o1v)[j];
      unsigned short w2 = ((const unsigned short*)&o2v)[j];
      float oh1v = bf2f(*(bf16*)&u1), ow1v = bf2f(*(bf16*)&w1);
      float oh2v = bf2f(*(bf16*)&u2), ow2v = bf2f(*(bf16*)&w2);
      float term1 = g * (((const float*)&a1h4)[j] * oh1v + ((const float*)&a1w4)[j] * ow1v);
      float term2 = g * (((const float*)&a2h4)[j] * oh2v + ((const float*)&a2w4)[j] * ow2v);
      float resid = ((const float*)&xv4)[j] * (mc + ((const float*)&mn4)[j]);
      r[j] = term2 + resid + term1;
    }
    float4 o4 = { r[0], r[1], r[2], r[3] };
    *(float4*)(out + idx) = o4;
  }
}

// ============================ host ============================

static void run_att(const bf16* xT_hi, const bf16* xT_lo,
                    const bf16* wqk_hi, const bf16* wqk_lo, const float* bqk,
                    const bf16* wvb, const float* bv,
                    bf16* qhw, bf16* khw, bf16* v, bf16* vT,
                    float* mh, float* sh, float* mw, float* sw,
                    float* ahT, float* aw, bf16* tmp, hipStream_t stream){
  bf16* ohX = tmp;
  bf16* ow  = tmp + (size_t)Bn * Cn * Nn;
  k_qk_mfma<<<dim3(Nn / 128, Bn), 256, 0, stream>>>(xT_hi, xT_lo, wqk_hi, wqk_lo, bqk,
                                                    qhw, khw);
  k_v_mfma<<<2048, 256, 0, stream>>>(xT_hi, wvb, bv, v);
  k_trans<<<dim3(16, Cn, Bn), 256, 0, stream>>>(v, vT, Cn);
  k_att_h<<<dim3(Wn, Bn), 256, 0, stream>>>(qhw, khw, vT, mh, sh, ohX);
  k_att_w<<<dim3(Hn, Bn), 256, 0, stream>>>(qhw, khw, v, mw, sw, ow);
  k_alpha<<<Bn * Nn / 256, 256, 0, stream>>>(mh, sh, mw, sw, ahT, aw);
}

extern "C" void kernel_launch(void* const* d_in, const int* in_sizes, int n_in,
                              void* d_out, int out_size, void* d_ws, size_t ws_size,
                              hipStream_t stream){
  (void)in_sizes; (void)n_in; (void)out_size; (void)ws_size;
  const float* x         = (const float*)d_in[0];
  const float* w_q_right = (const float*)d_in[1];
  const float* w_v_right = (const float*)d_in[2];
  const float* w_up      = (const float*)d_in[3];
  const float* b_up      = (const float*)d_in[4];
  const float* w_q_left  = (const float*)d_in[5];
  const float* w_v_left  = (const float*)d_in[6];
  const float* wq        = (const float*)d_in[7];
  const float* bq        = (const float*)d_in[8];
  const float* wk        = (const float*)d_in[9];
  const float* bk        = (const float*)d_in[10];
  const float* wv        = (const float*)d_in[11];
  const float* bv        = (const float*)d_in[12];
  const float* gamma     = (const float*)d_in[13];

  const size_t SZ_MAP = (size_t)Bn * Cn * Nn;     // 33.5M elements
  char* p = (char*)d_ws;
  float* buf0   = (float*)p; p += SZ_MAP * 4;     // CA2 tmp (oh2/ow2), CA3 tmp
  float* buf1   = (float*)p; p += SZ_MAP * 4;     // cs_hi/lo during CA1-2; then s
  bf16*  vbuf   = (bf16*)p;  p += SZ_MAP * 2;
  bf16*  vT     = (bf16*)p;  p += SZ_MAP * 2;
  bf16*  qhw    = (bf16*)p;  p += (size_t)Bn * CQn * Nn * 2;
  bf16*  khw    = (bf16*)p;  p += (size_t)Bn * CQn * Nn * 2;
  float* ebuf   = (float*)p; p += (size_t)SZ_MAP * 2;         // xT_hi arena (67MB)
  float* logits = (float*)p; p += (size_t)Bn * Nn * 4;
  float* ctxlog = (float*)p; p += (size_t)Bn * Nn * 4;
  float* msp    = (float*)p; p += (size_t)Bn * Nn * 4;
  float* xbar   = (float*)p; p += Bn * Cn * 4;
  float* wgt    = (float*)p; p += Bn * Cn * 4;
  float* u      = (float*)p; p += Bn * Cn * 4;
  float* mch    = (float*)p; p += Bn * Cn * 4;
  float* avg    = (float*)p; p += Bn * CIn * 4;
  float* ctx    = (float*)p; p += Bn * CIn * 4;
  float* stats_sp = (float*)p; p += 64;
  float* stats_ch = (float*)p; p += 64;
  bf16*  wvb    = (bf16*)p;  p += (size_t)Cn * Cn * 2;
  bf16*  wqk_hi = (bf16*)p;  p += (size_t)128 * Cn * 2;
  bf16*  wqk_lo = (bf16*)p;  p += (size_t)128 * Cn * 2;
  float* bqk    = (float*)p; p += 128 * 4;
  float* mh     = (float*)p; p += (size_t)Bn * Nn * 4;
  float* sh     = (float*)p; p += (size_t)Bn * Nn * 4;
  float* mw     = (float*)p; p += (size_t)Bn * Nn * 4;
  float* sw     = (float*)p; p += (size_t)Bn * Nn * 4;
  float* ah1    = (float*)p; p += (size_t)Bn * Nn * 4;
  float* aw1    = (float*)p; p += (size_t)Bn * Nn * 4;
  float* ah2    = (float*)p; p += (size_t)Bn * Nn * 4;
  float* aw2    = (float*)p; p += (size_t)Bn * Nn * 4;

  bf16*  cc_hi  = (bf16*)ebuf;               // dead after CA1's v_mfma
  bf16*  cc_lo  = (bf16*)d_out;              // dead after CA1's qk_mfma
  bf16*  cs_hi  = (bf16*)buf1;               // dead after CA2's v_mfma
  bf16*  cs_lo  = (bf16*)buf1 + SZ_MAP;      // dead after CA2's qk_mfma
  bf16*  xT_hi3 = (bf16*)ebuf;               // CA3 set
  bf16*  xT_lo3 = (bf16*)d_out;              // d_out free after fuse3 consumed oh1/ow1

  // ---- weight prep (once) ----
  k_cvt_w<<<(Cn * Cn + 255) / 256, 256, 0, stream>>>(wv, wvb, Cn * Cn);
  k_prep_wqk<<<(128 * Cn) / 256, 256, 0, stream>>>(wq, wk, bq, bk, wqk_hi, wqk_lo, bqk);

  // ---- stage 0: gating masks ----
  k_dotc<<<Bn * Nn / 256, 256, 0, stream>>>(x, w_q_right, 0, logits);
  k_rowmean<<<Bn * Cn, 256, 0, stream>>>(x, xbar, 1.f / Nn);
  k_rowdot<<<Bn, 256, 0, stream>>>(w_q_left, xbar, avg);
  k_coldot<<<dim3(Cn / 256, Bn), 256, 0, stream>>>(w_v_left, avg, u);
  k_stats<<<Bn, 1024, 0, stream>>>(logits, stats_sp);
  k_weighted<<<Bn * Cn, 256, 0, stream>>>(x, logits, stats_sp, wgt);
  k_rowdot<<<Bn, 256, 0, stream>>>(w_v_right, wgt, ctx);
  k_mch2<<<dim3(Cn / 256, Bn), 256, 0, stream>>>(w_up, b_up, ctx, mch);
  k_dotc<<<Bn * Nn / 256, 256, 0, stream>>>(x, u, Cn, ctxlog);
  k_stats<<<Bn, 1024, 0, stream>>>(ctxlog, stats_ch);
  k_msp<<<Bn * Nn / 256, 256, 0, stream>>>(ctxlog, stats_ch, msp);

  // single x pass: both cc and cs transposed hi/lo sets
  k_applyT3<<<dim3(Nn / 32, Cn / 32, Bn), 256, 0, stream>>>(x, mch, msp,
                                                            cc_hi, cc_lo, cs_hi, cs_lo);

  // ---- CA1 attention only: oh1/ow1 -> d_out, alphas -> ah1/aw1 (no fuse) ----
  run_att(cc_hi, cc_lo, wqk_hi, wqk_lo, bqk, wvb, bv,
          qhw, khw, vbuf, vT, mh, sh, mw, sw, ah1, aw1, (bf16*)d_out, stream);
  // ---- CA2 attention: oh2/ow2 -> buf0, alphas -> ah2/aw2 ----
  run_att(cs_hi, cs_lo, wqk_hi, wqk_lo, bqk, wvb, bv,
          qhw, khw, vbuf, vT, mh, sh, mw, sw, ah2, aw2, (bf16*)buf0, stream);
  // ---- combined fuse: s = g*att1 + g*att2 + x*(mch+msp) -> buf1 ----
  k_fuse3<<<dim3(Cn, 2, Bn), 256, 0, stream>>>(x, mch, msp,
                                               (const bf16*)d_out,
                                               (const bf16*)d_out + SZ_MAP, ah1, aw1,
                                               (const bf16*)buf0,
                                               (const bf16*)buf0 + SZ_MAP, ah2, aw2,
                                               gamma, buf1);
  // ---- CA3: in = s = buf1; tmp = buf0; out = d_out ----
  k_cvt_T<<<dim3(Nn / 32, Cn / 32, Bn), 256, 0, stream>>>(buf1, xT_hi3, xT_lo3);
  run_att(xT_hi3, xT_lo3, wqk_hi, wqk_lo, bqk, wvb, bv,
          qhw, khw, vbuf, vT, mh, sh, mw, sw, ah1, aw1, (bf16*)buf0, stream);
  k_fuse2<<<dim3(Cn, 2, Bn), 256, 0, stream>>>(buf1, (const bf16*)buf0,
                                               (const bf16*)buf0 + SZ_MAP, ah1, aw1,
                                               gamma, (float*)d_out);
}

// Round 19
// 1266.710 us; speedup vs baseline: 1.3405x; 1.0062x over previous
//
#include <hip/hip_runtime.h>
#include <hip/hip_bf16.h>
#include <math.h>

typedef __hip_bfloat16 bf16;
typedef __attribute__((ext_vector_type(8))) short s16x8;
typedef __attribute__((ext_vector_type(4))) float f32x4;

constexpr int Bn  = 4;
constexpr int Cn  = 512;
constexpr int Hn  = 128;
constexpr int Wn  = 128;
constexpr int Nn  = Hn * Wn;   // 16384
constexpr int CQn = 64;
constexpr int CIn = 256;

__device__ __forceinline__ float bf2f(bf16 v){ return __bfloat162float(v); }
__device__ __forceinline__ bf16  f2bf(float v){ return __float2bfloat16(v); }

// async global->LDS, 16B per lane; LDS dest must be wave-uniform base (HW adds lane*16)
__device__ __forceinline__ void gload_lds16(const void* g, void* l){
  __builtin_amdgcn_global_load_lds(
      (const __attribute__((address_space(1))) unsigned int*)g,
      (__attribute__((address_space(3))) unsigned int*)l,
      16, 0, 0);
}

// ============================ stage 0 ============================

// split-K column dot: part[half][b*Nn+n] = sum_{c in half} w[c]*x[b][c][n]
__global__ __launch_bounds__(256) void k_dotc2(const float* __restrict__ x,
                                               const float* __restrict__ w,
                                               int wstride,
                                               float* __restrict__ part){
  int t = blockIdx.x * 256 + threadIdx.x;      // over B*Nn
  int half = blockIdx.y;
  int b = t >> 14;
  const float* wp = w + (size_t)b * wstride + half * 256;
  const float* xp = x + (size_t)b * Cn * Nn + (size_t)(half * 256) * Nn + (t & (Nn - 1));
  float acc = 0.f;
  #pragma unroll 16
  for (int c = 0; c < 256; ++c) acc += wp[c] * xp[(size_t)c * Nn];
  part[(size_t)half * (Bn * Nn) + t] = acc;
}

__global__ __launch_bounds__(256) void k_dotcadd(const float* __restrict__ part,
                                                 float* __restrict__ out){
  int t = blockIdx.x * 256 + threadIdx.x;
  out[t] = part[t] + part[(size_t)Bn * Nn + t];
}

__global__ __launch_bounds__(256) void k_rowmean(const float* __restrict__ x,
                                                 float* __restrict__ out,
                                                 float scale){
  int bc = blockIdx.x;
  const float* xp = x + (size_t)bc * Nn;
  float acc = 0.f;
  for (int n = threadIdx.x; n < Nn; n += 256) acc += xp[n];
  for (int o = 32; o > 0; o >>= 1) acc += __shfl_down(acc, o);
  __shared__ float red[4];
  if ((threadIdx.x & 63) == 0) red[threadIdx.x >> 6] = acc;
  __syncthreads();
  if (threadIdx.x == 0) out[bc] = (red[0] + red[1] + red[2] + red[3]) * scale;
}

__global__ __launch_bounds__(256) void k_rowdot(const float* __restrict__ W,
                                                const float* __restrict__ vec,
                                                float* __restrict__ out){
  __shared__ float vs[Cn];
  int b = blockIdx.x, t = threadIdx.x;
  for (int j = t; j < Cn; j += 256) vs[j] = vec[b * Cn + j];
  __syncthreads();
  const float4* wp = (const float4*)(W + (size_t)t * Cn);
  float a = 0.f;
  #pragma unroll 4
  for (int j = 0; j < Cn / 4; ++j){
    float4 w4 = wp[j];
    a += w4.x * vs[4*j] + w4.y * vs[4*j+1] + w4.z * vs[4*j+2] + w4.w * vs[4*j+3];
  }
  out[b * CIn + t] = a;
}

__global__ __launch_bounds__(256) void k_coldot(const float* __restrict__ W,
                                                const float* __restrict__ vec,
                                                float* __restrict__ out){
  __shared__ float vs[CIn];
  int b = blockIdx.y, t = threadIdx.x;
  int c = blockIdx.x * 256 + t;
  if (t < CIn) vs[t] = vec[b * CIn + t];
  __syncthreads();
  float a = 0.f;
  #pragma unroll 8
  for (int j = 0; j < CIn; ++j) a += W[(size_t)j * Cn + c] * vs[j];
  out[b * Cn + c] = a;
}

__global__ __launch_bounds__(256) void k_mch2(const float* __restrict__ w_up,
                                              const float* __restrict__ b_up,
                                              const float* __restrict__ ctx,
                                              float* __restrict__ mch){
  __shared__ float cs[CIn];
  int b = blockIdx.y, t = threadIdx.x;
  int o = blockIdx.x * 256 + t;
  if (t < CIn) cs[t] = ctx[b * CIn + t];
  __syncthreads();
  const float4* wp = (const float4*)(w_up + (size_t)o * CIn);
  float a = b_up[o];
  #pragma unroll 4
  for (int j = 0; j < CIn / 4; ++j){
    float4 w4 = wp[j];
    a += w4.x * cs[4*j] + w4.y * cs[4*j+1] + w4.z * cs[4*j+2] + w4.w * cs[4*j+3];
  }
  mch[b * Cn + o] = 1.f / (1.f + expf(-a));
}

__global__ __launch_bounds__(1024) void k_stats(const float* __restrict__ vv,
                                                float* __restrict__ stats){
  int b = blockIdx.x;
  const float* pp = vv + (size_t)b * Nn;
  int t = threadIdx.x;
  float m = -3.4e38f;
  for (int n = t; n < Nn; n += 1024) m = fmaxf(m, pp[n]);
  for (int o = 32; o > 0; o >>= 1) m = fmaxf(m, __shfl_down(m, o));
  __shared__ float red[16];
  int wid = t >> 6, lid = t & 63;
  if (lid == 0) red[wid] = m;
  __syncthreads();
  if (t == 0){
    float q = red[0];
    for (int i = 1; i < 16; i++) q = fmaxf(q, red[i]);
    red[0] = q;
  }
  __syncthreads();
  m = red[0];
  __syncthreads();
  float s = 0.f;
  for (int n = t; n < Nn; n += 1024) s += expf(pp[n] - m);
  for (int o = 32; o > 0; o >>= 1) s += __shfl_down(s, o);
  if (lid == 0) red[wid] = s;
  __syncthreads();
  if (t == 0){
    float q = 0.f;
    for (int i = 0; i < 16; i++) q += red[i];
    stats[b * 2]     = m;
    stats[b * 2 + 1] = q;
  }
}

__global__ __launch_bounds__(256) void k_weighted(const float* __restrict__ x,
                                                  const float* __restrict__ logits,
                                                  const float* __restrict__ stats,
                                                  float* __restrict__ out){
  int bc = blockIdx.x;
  int b = bc >> 9;
  const float* xp = x + (size_t)bc * Nn;
  const float* lp = logits + (size_t)b * Nn;
  float m = stats[b * 2], den = stats[b * 2 + 1];
  float acc = 0.f;
  for (int n = threadIdx.x; n < Nn; n += 256) acc += xp[n] * expf(lp[n] - m);
  for (int o = 32; o > 0; o >>= 1) acc += __shfl_down(acc, o);
  __shared__ float red[4];
  if ((threadIdx.x & 63) == 0) red[threadIdx.x >> 6] = acc;
  __syncthreads();
  if (threadIdx.x == 0) out[bc] = (red[0] + red[1] + red[2] + red[3]) / den;
}

__global__ __launch_bounds__(256) void k_msp(const float* __restrict__ lg,
                                             const float* __restrict__ stats,
                                             float* __restrict__ msp){
  int t = blockIdx.x * 256 + threadIdx.x;
  int b = t >> 14;
  float v = expf(lg[t] - stats[b * 2]) / stats[b * 2 + 1];
  msp[t] = 1.f / (1.f + expf(-v));
}

// Single x pass: cc = x*mch -> cc_hi/lo; cs = x*msp -> cs_hi/lo (all transposed [b][n][c])
__global__ __launch_bounds__(256) void k_applyT3(const float* __restrict__ x,
                                                 const float* __restrict__ mch,
                                                 const float* __restrict__ msp,
                                                 bf16* __restrict__ cc_hi,
                                                 bf16* __restrict__ cc_lo,
                                                 bf16* __restrict__ cs_hi,
                                                 bf16* __restrict__ cs_lo){
  __shared__ bf16 tch[32][33], tcl[32][33], tsh[32][33], tsl[32][33];
  int nt = blockIdx.x, ct = blockIdx.y, b = blockIdx.z;
  int n0 = nt * 32, c0 = ct * 32;
  int t = threadIdx.x;
  #pragma unroll
  for (int kk = 0; kk < 4; ++kk){
    int idx = t + kk * 256;
    int cl = idx >> 5, nl = idx & 31;
    float xv = x[((size_t)(b * Cn + c0 + cl)) * Nn + n0 + nl];
    float ccv = xv * mch[b * Cn + c0 + cl];
    float csv = xv * msp[b * Nn + n0 + nl];
    bf16 h1 = f2bf(ccv);
    tch[cl][nl] = h1;
    tcl[cl][nl] = f2bf(ccv - bf2f(h1));
    bf16 h2 = f2bf(csv);
    tsh[cl][nl] = h2;
    tsl[cl][nl] = f2bf(csv - bf2f(h2));
  }
  __syncthreads();
  #pragma unroll
  for (int kk = 0; kk < 4; ++kk){
    int idx = t + kk * 256;
    int nl = idx >> 5, cl = idx & 31;
    size_t o = ((size_t)(b * Nn + n0 + nl)) * Cn + c0 + cl;
    cc_hi[o] = tch[cl][nl];
    cc_lo[o] = tcl[cl][nl];
    cs_hi[o] = tsh[cl][nl];
    cs_lo[o] = tsl[cl][nl];
  }
}

// ============================ conversions ============================

__global__ __launch_bounds__(256) void k_cvt_w(const float* __restrict__ in,
                                               bf16* __restrict__ out, int n){
  int t = blockIdx.x * 256 + threadIdx.x;
  if (t < n) out[t] = f2bf(in[t]);
}

__global__ __launch_bounds__(256) void k_prep_wqk(const float* __restrict__ wq,
                                                  const float* __restrict__ wk,
                                                  const float* __restrict__ bq,
                                                  const float* __restrict__ bk,
                                                  bf16* __restrict__ wqk_hi,
                                                  bf16* __restrict__ wqk_lo,
                                                  float* __restrict__ bqk){
  int t = blockIdx.x * 256 + threadIdx.x;   // over 128*512
  int o = t >> 9, c = t & 511;
  float v = (o < 64) ? wq[(size_t)o * Cn + c] : wk[(size_t)(o - 64) * Cn + c];
  bf16 h = f2bf(v);
  wqk_hi[t] = h;
  wqk_lo[t] = f2bf(v - bf2f(h));
  if (t < 128) bqk[t] = (t < 64) ? bq[t] : bk[t - 64];
}

__global__ __launch_bounds__(256) void k_cvt_T(const float* __restrict__ in,
                                               bf16* __restrict__ out_hi,
                                               bf16* __restrict__ out_lo){
  __shared__ bf16 th_[32][33];
  __shared__ bf16 tl_[32][33];
  int nt = blockIdx.x, ct = blockIdx.y, b = blockIdx.z;
  int n0 = nt * 32, c0 = ct * 32;
  int t = threadIdx.x;
  #pragma unroll
  for (int kk = 0; kk < 4; ++kk){
    int idx = t + kk * 256;
    int cl = idx >> 5, nl = idx & 31;
    float v = in[((size_t)(b * Cn + c0 + cl)) * Nn + n0 + nl];
    bf16 h = f2bf(v);
    th_[cl][nl] = h;
    tl_[cl][nl] = f2bf(v - bf2f(h));
  }
  __syncthreads();
  #pragma unroll
  for (int kk = 0; kk < 4; ++kk){
    int idx = t + kk * 256;
    int nl = idx >> 5, cl = idx & 31;
    size_t o = ((size_t)(b * Nn + n0 + nl)) * Cn + c0 + cl;
    out_hi[o] = th_[cl][nl];
    out_lo[o] = tl_[cl][nl];
  }
}

// ============================ MFMA GEMMs ============================

// V = Wv @ X. 128x128 tile, BK=64. XCD-chunked 1D grid of 2048.
__global__ __launch_bounds__(256) void k_v_mfma(const bf16* __restrict__ xT,
                                                const bf16* __restrict__ wvb,
                                                const float* __restrict__ bv,
                                                bf16* __restrict__ v){
  __shared__ short As[128 * 64];
  __shared__ short Bs[128 * 64];
  __shared__ float bvs[128];
  int lin = blockIdx.x;
  int swz = (lin & 7) * 256 + (lin >> 3);
  int cb = (swz & 3) * 128;
  int nb = ((swz >> 2) & 127) * 128;
  int b  = swz >> 9;
  int t = threadIdx.x, lane = t & 63, wid = t >> 6;
  int wm = wid >> 1, wn = wid & 1;
  int l15 = lane & 15, l4 = lane >> 4;
  if (t < 128) bvs[t] = bv[cb + t];
  f32x4 acc[4][4];
  #pragma unroll
  for (int i = 0; i < 4; i++)
    #pragma unroll
    for (int j = 0; j < 4; j++) acc[i][j] = (f32x4){0.f, 0.f, 0.f, 0.f};

  const bf16* wp = wvb + (size_t)cb * Cn;
  const bf16* xp = xT + ((size_t)b * Nn + nb) * Cn;
  int r8 = lane >> 3;
  int kc = (lane & 7) * 8;
  for (int kt = 0; kt < 8; ++kt){
    int k0 = kt * 64;
    #pragma unroll
    for (int j = 0; j < 4; ++j){
      int inst = wid * 4 + j;
      int row = inst * 8 + r8;
      gload_lds16(wp + (size_t)row * Cn + k0 + kc, (char*)As + inst * 1024);
      gload_lds16(xp + (size_t)row * Cn + k0 + kc, (char*)Bs + inst * 1024);
    }
    __syncthreads();
    #pragma unroll
    for (int kk = 0; kk < 64; kk += 32){
      s16x8 a[4], bb[4];
      #pragma unroll
      for (int mi = 0; mi < 4; mi++)
        a[mi] = *(const s16x8*)&As[(wm * 64 + mi * 16 + l15) * 64 + kk + l4 * 8];
      #pragma unroll
      for (int ni = 0; ni < 4; ni++)
        bb[ni] = *(const s16x8*)&Bs[(wn * 64 + ni * 16 + l15) * 64 + kk + l4 * 8];
      #pragma unroll
      for (int mi = 0; mi < 4; mi++)
        #pragma unroll
        for (int ni = 0; ni < 4; ni++)
          acc[mi][ni] = __builtin_amdgcn_mfma_f32_16x16x32_bf16(a[mi], bb[ni], acc[mi][ni], 0, 0, 0);
    }
    __syncthreads();
  }
  #pragma unroll
  for (int mi = 0; mi < 4; mi++){
    #pragma unroll
    for (int r = 0; r < 4; r++){
      int cl = wm * 64 + mi * 16 + l4 * 4 + r;
      int c  = cb + cl;
      float bias = bvs[cl];
      #pragma unroll
      for (int ni = 0; ni < 4; ni++){
        int n = nb + wn * 64 + ni * 16 + l15;
        v[((size_t)(b * Cn + c)) * Nn + n] = f2bf(acc[mi][ni][r] + bias);
      }
    }
  }
}

// Q,K = [Wq;Wk] @ X, split-precision bf16 (3 MFMA terms).
// Writes qhw/khw ([b][w][h][c]) DIRECTLY via LDS transpose epilogue (no std q/k).
__global__ __launch_bounds__(256) void k_qk_mfma(const bf16* __restrict__ xT_hi,
                                                 const bf16* __restrict__ xT_lo,
                                                 const bf16* __restrict__ wqk_hi,
                                                 const bf16* __restrict__ wqk_lo,
                                                 const float* __restrict__ bqk,
                                                 bf16* __restrict__ qhw,
                                                 bf16* __restrict__ khw){
  __shared__ char smem[65536];
  short* Ah = (short*)smem;
  short* Al = Ah + 8192;
  short* Bh = Al + 8192;
  short* Bl = Bh + 8192;
  char*  Os = smem;                 // reused after final K-loop barrier (32KB)
  __shared__ float bs[128];
  int h = blockIdx.x, b = blockIdx.y;      // block covers n = h*128 + w, w=0..127
  int nb = h * 128;
  int t = threadIdx.x, lane = t & 63, wid = t >> 6;
  int wm = wid >> 1, wn = wid & 1;
  int l15 = lane & 15, l4 = lane >> 4;
  if (t < 128) bs[t] = bqk[t];
  f32x4 acc[4][4];
  #pragma unroll
  for (int i = 0; i < 4; i++)
    #pragma unroll
    for (int j = 0; j < 4; j++) acc[i][j] = (f32x4){0.f, 0.f, 0.f, 0.f};

  const bf16* xh = xT_hi + ((size_t)b * Nn + nb) * Cn;
  const bf16* xl = xT_lo + ((size_t)b * Nn + nb) * Cn;
  int r8 = lane >> 3;
  int kc = (lane & 7) * 8;
  for (int kt = 0; kt < 8; ++kt){
    int k0 = kt * 64;
    #pragma unroll
    for (int j = 0; j < 4; ++j){
      int inst = wid * 4 + j;
      int row = inst * 8 + r8;
      size_t off = (size_t)row * Cn + k0 + kc;
      gload_lds16(wqk_hi + off, (char*)Ah + inst * 1024);
      gload_lds16(wqk_lo + off, (char*)Al + inst * 1024);
      gload_lds16(xh + off,     (char*)Bh + inst * 1024);
      gload_lds16(xl + off,     (char*)Bl + inst * 1024);
    }
    __syncthreads();
    #pragma unroll
    for (int kk = 0; kk < 64; kk += 32){
      s16x8 ah[4], al[4], bh[4], bl[4];
      #pragma unroll
      for (int mi = 0; mi < 4; mi++){
        int idx = (wm * 64 + mi * 16 + l15) * 64 + kk + l4 * 8;
        ah[mi] = *(const s16x8*)&Ah[idx];
        al[mi] = *(const s16x8*)&Al[idx];
      }
      #pragma unroll
      for (int ni = 0; ni < 4; ni++){
        int idx = (wn * 64 + ni * 16 + l15) * 64 + kk + l4 * 8;
        bh[ni] = *(const s16x8*)&Bh[idx];
        bl[ni] = *(const s16x8*)&Bl[idx];
      }
      #pragma unroll
      for (int mi = 0; mi < 4; mi++)
        #pragma unroll
        for (int ni = 0; ni < 4; ni++){
          acc[mi][ni] = __builtin_amdgcn_mfma_f32_16x16x32_bf16(ah[mi], bh[ni], acc[mi][ni], 0, 0, 0);
          acc[mi][ni] = __builtin_amdgcn_mfma_f32_16x16x32_bf16(ah[mi], bl[ni], acc[mi][ni], 0, 0, 0);
          acc[mi][ni] = __builtin_amdgcn_mfma_f32_16x16x32_bf16(al[mi], bh[ni], acc[mi][ni], 0, 0, 0);
        }
    }
    __syncthreads();
  }
  // epilogue: Os[n][o] bf16 (256B rows, XOR-swizzled), then 128B row stores
  #pragma unroll
  for (int mi = 0; mi < 4; mi++){
    #pragma unroll
    for (int r = 0; r < 4; r++){
      int o = wm * 64 + mi * 16 + l4 * 4 + r;
      float bias = bs[o];
      #pragma unroll
      for (int ni = 0; ni < 4; ni++){
        int n = wn * 64 + ni * 16 + l15;
        bf16 bv = f2bf(acc[mi][ni][r] + bias);
        int byte = (n * 256 + o * 2) ^ ((n & 7) << 4);
        *(unsigned short*)(Os + byte) = *(unsigned short*)&bv;
      }
    }
  }
  __syncthreads();
  #pragma unroll
  for (int i = 0; i < 8; ++i){
    int s = t + i * 256;            // 0..2047: row = s>>3 (w + 128*qk), seg = s&7
    int row = s >> 3, seg = s & 7;
    int w = row & 127, qk = row >> 7;
    int o0 = qk * 64 + seg * 8;
    int byte = (w * 256 + o0 * 2) ^ ((w & 7) << 4);
    s16x8 d = *(const s16x8*)(Os + byte);
    bf16* dst = (qk == 0 ? qhw : khw) + (((size_t)b * Wn + w) * Hn + h) * CQn + seg * 8;
    *(s16x8*)dst = d;
  }
}

// ============================ fused attention ============================

// per (b,w): MFMA e_h from qhw/khw ([b][w][h][c]), diag, stats, p->LDS, PV MFMA.
// ohX layout [b][c][w][h] (unnormalized; alpha in fuse).
__global__ __launch_bounds__(256) void k_att_h(const bf16* __restrict__ qhw,
                                               const bf16* __restrict__ khw,
                                               const bf16* __restrict__ vT,
                                               float* __restrict__ mh,
                                               float* __restrict__ sh,
                                               bf16* __restrict__ ohX){
  __shared__ char smem[65536];
  char* attb = smem;                 // p tile 32KB
  char* vbb  = smem + 32768;         // V tile 32KB (e-phase: first 2KB = stats)
  float* redm = (float*)(smem + 32768);        // [2][128]
  float* reds = redm + 256;                    // [2][128]
  int w = blockIdx.x, b = blockIdx.y;
  int t = threadIdx.x, lane = t & 63, wid = t >> 6;
  int wm = wid >> 1, wn = wid & 1;
  int l15 = lane & 15, l4 = lane >> 4;

  const bf16* qp = qhw + ((size_t)(b * Wn + w)) * (Hn * CQn);
  const bf16* kp = khw + ((size_t)(b * Wn + w)) * (Hn * CQn);
  f32x4 acc[4][4];
  #pragma unroll
  for (int i = 0; i < 4; i++)
    #pragma unroll
    for (int j = 0; j < 4; j++) acc[i][j] = (f32x4){0.f, 0.f, 0.f, 0.f};
  #pragma unroll
  for (int kk = 0; kk < 64; kk += 32){
    s16x8 a[4], bb[4];
    #pragma unroll
    for (int mi = 0; mi < 4; mi++)
      a[mi] = *(const s16x8*)(qp + (size_t)(wm * 64 + mi * 16 + l15) * CQn + kk + l4 * 8);
    #pragma unroll
    for (int ni = 0; ni < 4; ni++)
      bb[ni] = *(const s16x8*)(kp + (size_t)(wn * 64 + ni * 16 + l15) * CQn + kk + l4 * 8);
    #pragma unroll
    for (int mi = 0; mi < 4; mi++)
      #pragma unroll
      for (int ni = 0; ni < 4; ni++)
        acc[mi][ni] = __builtin_amdgcn_mfma_f32_16x16x32_bf16(a[mi], bb[ni], acc[mi][ni], 0, 0, 0);
  }
  // diag mask: h==g
  if (wm == wn){
    #pragma unroll
    for (int mi = 0; mi < 4; mi++)
      #pragma unroll
      for (int r = 0; r < 4; r++)
        if (l15 == l4 * 4 + r) acc[mi][mi][r] = -1e30f;
  }
  float rm[4][4];
  #pragma unroll
  for (int mi = 0; mi < 4; mi++)
    #pragma unroll
    for (int r = 0; r < 4; r++){
      float m = fmaxf(fmaxf(acc[mi][0][r], acc[mi][1][r]),
                      fmaxf(acc[mi][2][r], acc[mi][3][r]));
      m = fmaxf(m, __shfl_xor(m, 1));
      m = fmaxf(m, __shfl_xor(m, 2));
      m = fmaxf(m, __shfl_xor(m, 4));
      m = fmaxf(m, __shfl_xor(m, 8));
      rm[mi][r] = m;
    }
  if (l15 == 0){
    #pragma unroll
    for (int mi = 0; mi < 4; mi++)
      #pragma unroll
      for (int r = 0; r < 4; r++)
        redm[wn * 128 + wm * 64 + mi * 16 + l4 * 4 + r] = rm[mi][r];
  }
  __syncthreads();
  float rs[4][4];
  #pragma unroll
  for (int mi = 0; mi < 4; mi++)
    #pragma unroll
    for (int r = 0; r < 4; r++){
      int h = wm * 64 + mi * 16 + l4 * 4 + r;
      float m = fmaxf(redm[h], redm[128 + h]);
      rm[mi][r] = m;
      float s = 0.f;
      #pragma unroll
      for (int ni = 0; ni < 4; ni++){
        acc[mi][ni][r] = expf(acc[mi][ni][r] - m);
        s += acc[mi][ni][r];
      }
      s += __shfl_xor(s, 1);
      s += __shfl_xor(s, 2);
      s += __shfl_xor(s, 4);
      s += __shfl_xor(s, 8);
      rs[mi][r] = s;
    }
  if (l15 == 0){
    #pragma unroll
    for (int mi = 0; mi < 4; mi++)
      #pragma unroll
      for (int r = 0; r < 4; r++)
        reds[wn * 128 + wm * 64 + mi * 16 + l4 * 4 + r] = rs[mi][r];
  }
  __syncthreads();
  #pragma unroll
  for (int mi = 0; mi < 4; mi++)
    #pragma unroll
    for (int r = 0; r < 4; r++){
      int h = wm * 64 + mi * 16 + l4 * 4 + r;
      if (wn == 0 && l15 == 0){
        mh[(size_t)(b * Wn + w) * Hn + h] = rm[mi][r];
        sh[(size_t)(b * Wn + w) * Hn + h] = reds[h] + reds[128 + h];
      }
      #pragma unroll
      for (int ni = 0; ni < 4; ni++){
        int g = wn * 64 + ni * 16 + l15;
        bf16 bv = f2bf(acc[mi][ni][r]);
        int byte = (h * 256 + g * 2) ^ ((h & 7) << 4);
        *(unsigned short*)(attb + byte) = *(unsigned short*)&bv;
      }
    }
  __syncthreads();
  // PV MFMA over 4 c-tiles
  for (int cb = 0; cb < Cn; cb += 128){
    const bf16* vp = vT + ((size_t)(b * Wn + w) * Cn + cb) * Hn;
    for (int s = t; s < 2048; s += 256){
      int row = s >> 4, seg = s & 15;
      s16x8 d = *(const s16x8*)(vp + (size_t)row * Hn + seg * 8);
      int byte = (row * 256 + seg * 16) ^ ((row & 7) << 4);
      *(s16x8*)(vbb + byte) = d;
    }
    __syncthreads();
    f32x4 acc2[4][4];
    #pragma unroll
    for (int i = 0; i < 4; i++)
      #pragma unroll
      for (int j = 0; j < 4; j++) acc2[i][j] = (f32x4){0.f, 0.f, 0.f, 0.f};
    #pragma unroll
    for (int kk = 0; kk < 128; kk += 32){
      s16x8 a[4], bb[4];
      #pragma unroll
      for (int mi = 0; mi < 4; mi++){
        int row = wm * 64 + mi * 16 + l15;
        int byte = (row * 256 + (kk + l4 * 8) * 2) ^ ((row & 7) << 4);
        a[mi] = *(const s16x8*)(vbb + byte);
      }
      #pragma unroll
      for (int ni = 0; ni < 4; ni++){
        int row = wn * 64 + ni * 16 + l15;
        int byte = (row * 256 + (kk + l4 * 8) * 2) ^ ((row & 7) << 4);
        bb[ni] = *(const s16x8*)(attb + byte);
      }
      #pragma unroll
      for (int mi = 0; mi < 4; mi++)
        #pragma unroll
        for (int ni = 0; ni < 4; ni++)
          acc2[mi][ni] = __builtin_amdgcn_mfma_f32_16x16x32_bf16(a[mi], bb[ni], acc2[mi][ni], 0, 0, 0);
    }
    bf16* op = ohX + ((size_t)(b * Cn + cb)) * Nn + (size_t)w * Hn;
    #pragma unroll
    for (int mi = 0; mi < 4; mi++)
      #pragma unroll
      for (int r = 0; r < 4; r++){
        int cl = wm * 64 + mi * 16 + l4 * 4 + r;
        #pragma unroll
        for (int ni = 0; ni < 4; ni++){
          int h = wn * 64 + ni * 16 + l15;
          op[(size_t)cl * Nn + h] = f2bf(acc2[mi][ni][r]);
        }
      }
    __syncthreads();
  }
}

// per (b,h): MFMA e_w from qhw/khw (strided rows), stats, p->LDS, PV MFMA.
__global__ __launch_bounds__(256) void k_att_w(const bf16* __restrict__ qhw,
                                               const bf16* __restrict__ khw,
                                               const bf16* __restrict__ v,
                                               float* __restrict__ mw,
                                               float* __restrict__ sw,
                                               bf16* __restrict__ ow){
  __shared__ char smem[65536];
  char* attb = smem;
  char* vbb  = smem + 32768;
  float* redm = (float*)(smem + 32768);
  float* reds = redm + 256;
  int h = blockIdx.x, b = blockIdx.y;
  int t = threadIdx.x, lane = t & 63, wid = t >> 6;
  int wm = wid >> 1, wn = wid & 1;
  int l15 = lane & 15, l4 = lane >> 4;

  const bf16* qp = qhw + (size_t)b * Wn * Hn * CQn + (size_t)h * CQn;
  const bf16* kp = khw + (size_t)b * Wn * Hn * CQn + (size_t)h * CQn;
  f32x4 acc[4][4];
  #pragma unroll
  for (int i = 0; i < 4; i++)
    #pragma unroll
    for (int j = 0; j < 4; j++) acc[i][j] = (f32x4){0.f, 0.f, 0.f, 0.f};
  #pragma unroll
  for (int kk = 0; kk < 64; kk += 32){
    s16x8 a[4], bb[4];
    #pragma unroll
    for (int mi = 0; mi < 4; mi++)
      a[mi] = *(const s16x8*)(qp + (size_t)(wm * 64 + mi * 16 + l15) * (Hn * CQn) + kk + l4 * 8);
    #pragma unroll
    for (int ni = 0; ni < 4; ni++)
      bb[ni] = *(const s16x8*)(kp + (size_t)(wn * 64 + ni * 16 + l15) * (Hn * CQn) + kk + l4 * 8);
    #pragma unroll
    for (int mi = 0; mi < 4; mi++)
      #pragma unroll
      for (int ni = 0; ni < 4; ni++)
        acc[mi][ni] = __builtin_amdgcn_mfma_f32_16x16x32_bf16(a[mi], bb[ni], acc[mi][ni], 0, 0, 0);
  }
  float rm[4][4];
  #pragma unroll
  for (int mi = 0; mi < 4; mi++)
    #pragma unroll
    for (int r = 0; r < 4; r++){
      float m = fmaxf(fmaxf(acc[mi][0][r], acc[mi][1][r]),
                      fmaxf(acc[mi][2][r], acc[mi][3][r]));
      m = fmaxf(m, __shfl_xor(m, 1));
      m = fmaxf(m, __shfl_xor(m, 2));
      m = fmaxf(m, __shfl_xor(m, 4));
      m = fmaxf(m, __shfl_xor(m, 8));
      rm[mi][r] = m;
    }
  if (l15 == 0){
    #pragma unroll
    for (int mi = 0; mi < 4; mi++)
      #pragma unroll
      for (int r = 0; r < 4; r++)
        redm[wn * 128 + wm * 64 + mi * 16 + l4 * 4 + r] = rm[mi][r];
  }
  __syncthreads();
  float rs[4][4];
  #pragma unroll
  for (int mi = 0; mi < 4; mi++)
    #pragma unroll
    for (int r = 0; r < 4; r++){
      int wr = wm * 64 + mi * 16 + l4 * 4 + r;
      float m = fmaxf(redm[wr], redm[128 + wr]);
      rm[mi][r] = m;
      float s = 0.f;
      #pragma unroll
      for (int ni = 0; ni < 4; ni++){
        acc[mi][ni][r] = expf(acc[mi][ni][r] - m);
        s += acc[mi][ni][r];
      }
      s += __shfl_xor(s, 1);
      s += __shfl_xor(s, 2);
      s += __shfl_xor(s, 4);
      s += __shfl_xor(s, 8);
      rs[mi][r] = s;
    }
  if (l15 == 0){
    #pragma unroll
    for (int mi = 0; mi < 4; mi++)
      #pragma unroll
      for (int r = 0; r < 4; r++)
        reds[wn * 128 + wm * 64 + mi * 16 + l4 * 4 + r] = rs[mi][r];
  }
  __syncthreads();
  #pragma unroll
  for (int mi = 0; mi < 4; mi++)
    #pragma unroll
    for (int r = 0; r < 4; r++){
      int wr = wm * 64 + mi * 16 + l4 * 4 + r;
      if (wn == 0 && l15 == 0){
        mw[(size_t)(b * Hn + h) * Wn + wr] = rm[mi][r];
        sw[(size_t)(b * Hn + h) * Wn + wr] = reds[wr] + reds[128 + wr];
      }
      #pragma unroll
      for (int ni = 0; ni < 4; ni++){
        int g = wn * 64 + ni * 16 + l15;
        bf16 bv = f2bf(acc[mi][ni][r]);
        int byte = (wr * 256 + g * 2) ^ ((wr & 7) << 4);
        *(unsigned short*)(attb + byte) = *(unsigned short*)&bv;
      }
    }
  __syncthreads();
  for (int cb = 0; cb < Cn; cb += 128){
    const bf16* vp = v + (size_t)(b * Cn + cb) * Nn + (size_t)h * Wn;
    for (int s = t; s < 2048; s += 256){
      int row = s >> 4, seg = s & 15;
      s16x8 d = *(const s16x8*)(vp + (size_t)row * Nn + seg * 8);
      int byte = (row * 256 + seg * 16) ^ ((row & 7) << 4);
      *(s16x8*)(vbb + byte) = d;
    }
    __syncthreads();
    f32x4 acc2[4][4];
    #pragma unroll
    for (int i = 0; i < 4; i++)
      #pragma unroll
      for (int j = 0; j < 4; j++) acc2[i][j] = (f32x4){0.f, 0.f, 0.f, 0.f};
    #pragma unroll
    for (int kk = 0; kk < 128; kk += 32){
      s16x8 a[4], bb[4];
      #pragma unroll
      for (int mi = 0; mi < 4; mi++){
        int row = wm * 64 + mi * 16 + l15;
        int byte = (row * 256 + (kk + l4 * 8) * 2) ^ ((row & 7) << 4);
        a[mi] = *(const s16x8*)(vbb + byte);
      }
      #pragma unroll
      for (int ni = 0; ni < 4; ni++){
        int row = wn * 64 + ni * 16 + l15;
        int byte = (row * 256 + (kk + l4 * 8) * 2) ^ ((row & 7) << 4);
        bb[ni] = *(const s16x8*)(attb + byte);
      }
      #pragma unroll
      for (int mi = 0; mi < 4; mi++)
        #pragma unroll
        for (int ni = 0; ni < 4; ni++)
          acc2[mi][ni] = __builtin_amdgcn_mfma_f32_16x16x32_bf16(a[mi], bb[ni], acc2[mi][ni], 0, 0, 0);
    }
    bf16* op = ow + (size_t)(b * Cn + cb) * Nn + (size_t)h * Wn;
    #pragma unroll
    for (int mi = 0; mi < 4; mi++)
      #pragma unroll
      for (int r = 0; r < 4; r++){
        int cl = wm * 64 + mi * 16 + l4 * 4 + r;
        #pragma unroll
        for (int ni = 0; ni < 4; ni++){
          int wr = wn * 64 + ni * 16 + l15;
          op[(size_t)cl * Nn + wr] = f2bf(acc2[mi][ni][r]);
        }
      }
    __syncthreads();
  }
}

// merge stats -> alphas, both in [b,h,w] layout for fuse
__global__ __launch_bounds__(256) void k_alpha(const float* __restrict__ mh,
                                               const float* __restrict__ sh,
                                               const float* __restrict__ mw,
                                               const float* __restrict__ sw,
                                               float* __restrict__ ahT,
                                               float* __restrict__ aw){
  int t = blockIdx.x * 256 + threadIdx.x;   // (b*Hn+h)*Wn + w
  int b = t >> 14;
  int hw = t & (Nn - 1);
  int h = hw >> 7, w = hw & 127;
  size_t ih = (size_t)(b * Wn + w) * Hn + h;
  size_t iw = t;
  float mhv = mh[ih], mwv = mw[iw];
  float M = fmaxf(mhv, mwv);
  float eh_ = expf(mhv - M), ew_ = expf(mwv - M);
  float inv = 1.f / (sh[ih] * eh_ + sw[iw] * ew_);
  ahT[t] = eh_ * inv;
  aw[t]  = ew_ * inv;
}

// ============================ remaining CA kernels ============================

__global__ __launch_bounds__(256) void k_trans(const bf16* __restrict__ in,
                                               bf16* __restrict__ out,
                                               int CH){
  __shared__ bf16 tile[32][33];
  int tl = blockIdx.x, c = blockIdx.y, b = blockIdx.z;
  int th = tl >> 2, tw = tl & 3;
  int h0 = th * 32, w0 = tw * 32;
  int t = threadIdx.x;
  const bf16* ip = in + ((size_t)(b * CH + c)) * Nn;
  #pragma unroll
  for (int kk = 0; kk < 4; ++kk){
    int idx = t + kk * 256;
    int hl = idx >> 5, wl = idx & 31;
    tile[hl][wl] = ip[(h0 + hl) * Wn + w0 + wl];
  }
  __syncthreads();
  #pragma unroll
  for (int kk = 0; kk < 4; ++kk){
    int idx = t + kk * 256;
    int wl = idx >> 5, hl = idx & 31;
    out[((size_t)(b * Wn + w0 + wl) * CH + c) * Hn + h0 + hl] = tile[hl][wl];
  }
}

// out = gamma*(ah*ohX^T + aw*ow) + resid  [single attention set]
__global__ __launch_bounds__(256) void k_fuse2(const float* __restrict__ in,
                                               const bf16* __restrict__ ohX,
                                               const bf16* __restrict__ ow,
                                               const float* __restrict__ ahT,
                                               const float* __restrict__ aw,
                                               const float* __restrict__ gamma,
                                               float* __restrict__ out){
  __shared__ unsigned short tileT[64][138];
  int c = blockIdx.x, half = blockIdx.y, b = blockIdx.z;
  int t = threadIdx.x;
  float g = gamma[0];
  int h0 = half * 64;
  const bf16* ohp = ohX + ((size_t)(b * Cn + c)) * Nn;   // [w][h] rows
  #pragma unroll
  for (int i = 0; i < 4; ++i){
    int s = t + i * 256;            // 0..1023: w = s>>3, seg = s&7 (h-chunk)
    int w = s >> 3, seg = s & 7;
    s16x8 d = *(const s16x8*)(ohp + (size_t)w * Hn + h0 + seg * 8);
    #pragma unroll
    for (int j = 0; j < 8; ++j)
      tileT[seg * 8 + j][w] = (unsigned short)d[j];
  }
  __syncthreads();
  size_t base = ((size_t)(b * Cn + c)) * Nn;
  #pragma unroll
  for (int i = 0; i < 8; ++i){
    int o = t + i * 256;            // 0..2047
    int hl = o >> 5, w4 = (o & 31) * 4;
    int h = h0 + hl;
    size_t idx = base + (size_t)h * Wn + w4;
    size_t aidx = (size_t)b * Nn + (size_t)h * Wn + w4;
    ushort4 owv = *(const ushort4*)((const unsigned short*)ow + idx);
    float4 ah4 = *(const float4*)(ahT + aidx);
    float4 aw4 = *(const float4*)(aw + aidx);
    float4 inv = in ? *(const float4*)(in + idx) : (float4){0.f,0.f,0.f,0.f};
    float r[4];
    #pragma unroll
    for (int j = 0; j < 4; ++j){
      unsigned short uh = tileT[hl][w4 + j];
      unsigned short uo = ((const unsigned short*)&owv)[j];
      float ohv = bf2f(*(bf16*)&uh);
      float owf = bf2f(*(bf16*)&uo);
      float ahv = ((const float*)&ah4)[j];
      float awv = ((const float*)&aw4)[j];
      r[j] = g * (ahv * ohv + awv * owf) + ((const float*)&inv)[j];
    }
    float4 o4 = { r[0], r[1], r[2], r[3] };
    *(float4*)(out + idx) = o4;
  }
}

// s = gamma*(a1h*oh1^T + a1w*ow1) + gamma*(a2h*oh2^T + a2w*ow2) + x*(mch+msp)
__global__ __launch_bounds__(256) void k_fuse3(const float* __restrict__ x,
                                               const float* __restrict__ mch,
                                               const float* __restrict__ msp,
                                               const bf16* __restrict__ oh1,
                                               const bf16* __restrict__ ow1,
                                               const float* __restrict__ a1h,
                                               const float* __restrict__ a1w,
                                               const bf16* __restrict__ oh2,
                                               const bf16* __restrict__ ow2,
                                               const float* __restrict__ a2h,
                                               const float* __restrict__ a2w,
                                               const float* __restrict__ gamma,
                                               float* __restrict__ out){
  __shared__ unsigned short t1[64][138];
  __shared__ unsigned short t2[64][138];
  int c = blockIdx.x, half = blockIdx.y, b = blockIdx.z;
  int t = threadIdx.x;
  float g = gamma[0];
  float mc = mch[b * Cn + c];
  int h0 = half * 64;
  const bf16* p1 = oh1 + ((size_t)(b * Cn + c)) * Nn;
  const bf16* p2 = oh2 + ((size_t)(b * Cn + c)) * Nn;
  #pragma unroll
  for (int i = 0; i < 4; ++i){
    int s = t + i * 256;
    int w = s >> 3, seg = s & 7;
    s16x8 d1 = *(const s16x8*)(p1 + (size_t)w * Hn + h0 + seg * 8);
    s16x8 d2 = *(const s16x8*)(p2 + (size_t)w * Hn + h0 + seg * 8);
    #pragma unroll
    for (int j = 0; j < 8; ++j){
      t1[seg * 8 + j][w] = (unsigned short)d1[j];
      t2[seg * 8 + j][w] = (unsigned short)d2[j];
    }
  }
  __syncthreads();
  size_t base = ((size_t)(b * Cn + c)) * Nn;
  #pragma unroll
  for (int i = 0; i < 8; ++i){
    int o = t + i * 256;
    int hl = o >> 5, w4 = (o & 31) * 4;
    int h = h0 + hl;
    size_t idx = base + (size_t)h * Wn + w4;
    size_t aidx = (size_t)b * Nn + (size_t)h * Wn + w4;
    ushort4 o1v = *(const ushort4*)((const unsigned short*)ow1 + idx);
    ushort4 o2v = *(const ushort4*)((const unsigned short*)ow2 + idx);
    float4 a1h4 = *(const float4*)(a1h + aidx);
    float4 a1w4 = *(const float4*)(a1w + aidx);
    float4 a2h4 = *(const float4*)(a2h + aidx);
    float4 a2w4 = *(const float4*)(a2w + aidx);
    float4 xv4  = *(const float4*)(x + idx);
    float4 mn4  = *(const float4*)(msp + aidx);
    float r[4];
    #pragma unroll
    for (int j = 0; j < 4; ++j){
      unsigned short u1 = t1[hl][w4 + j];
      unsigned short u2 = t2[hl][w4 + j];
      unsigned short w1 = ((const unsigned short*)&o1v)[j];
      unsigned short w2 = ((const unsigned short*)&o2v)[j];
      float oh1v = bf2f(*(bf16*)&u1), ow1v = bf2f(*(bf16*)&w1);
      float oh2v = bf2f(*(bf16*)&u2), ow2v = bf2f(*(bf16*)&w2);
      float term1 = g * (((const float*)&a1h4)[j] * oh1v + ((const float*)&a1w4)[j] * ow1v);
      float term2 = g * (((const float*)&a2h4)[j] * oh2v + ((const float*)&a2w4)[j] * ow2v);
      float resid = ((const float*)&xv4)[j] * (mc + ((const float*)&mn4)[j]);
      r[j] = term2 + resid + term1;
    }
    float4 o4 = { r[0], r[1], r[2], r[3] };
    *(float4*)(out + idx) = o4;
  }
}

// ============================ host ============================

static void run_att(const bf16* xT_hi, const bf16* xT_lo,
                    const bf16* wqk_hi, const bf16* wqk_lo, const float* bqk,
                    const bf16* wvb, const float* bv,
                    bf16* qhw, bf16* khw, bf16* v, bf16* vT,
                    float* mh, float* sh, float* mw, float* sw,
                    float* ahT, float* aw, bf16* tmp, hipStream_t stream){
  bf16* ohX = tmp;
  bf16* ow  = tmp + (size_t)Bn * Cn * Nn;
  k_qk_mfma<<<dim3(Nn / 128, Bn), 256, 0, stream>>>(xT_hi, xT_lo, wqk_hi, wqk_lo, bqk,
                                                    qhw, khw);
  k_v_mfma<<<2048, 256, 0, stream>>>(xT_hi, wvb, bv, v);
  k_trans<<<dim3(16, Cn, Bn), 256, 0, stream>>>(v, vT, Cn);
  k_att_h<<<dim3(Wn, Bn), 256, 0, stream>>>(qhw, khw, vT, mh, sh, ohX);
  k_att_w<<<dim3(Hn, Bn), 256, 0, stream>>>(qhw, khw, v, mw, sw, ow);
  k_alpha<<<Bn * Nn / 256, 256, 0, stream>>>(mh, sh, mw, sw, ahT, aw);
}

extern "C" void kernel_launch(void* const* d_in, const int* in_sizes, int n_in,
                              void* d_out, int out_size, void* d_ws, size_t ws_size,
                              hipStream_t stream){
  (void)in_sizes; (void)n_in; (void)out_size; (void)ws_size;
  const float* x         = (const float*)d_in[0];
  const float* w_q_right = (const float*)d_in[1];
  const float* w_v_right = (const float*)d_in[2];
  const float* w_up      = (const float*)d_in[3];
  const float* b_up      = (const float*)d_in[4];
  const float* w_q_left  = (const float*)d_in[5];
  const float* w_v_left  = (const float*)d_in[6];
  const float* wq        = (const float*)d_in[7];
  const float* bq        = (const float*)d_in[8];
  const float* wk        = (const float*)d_in[9];
  const float* bk        = (const float*)d_in[10];
  const float* wv        = (const float*)d_in[11];
  const float* bv        = (const float*)d_in[12];
  const float* gamma     = (const float*)d_in[13];

  const size_t SZ_MAP = (size_t)Bn * Cn * Nn;     // 33.5M elements
  char* p = (char*)d_ws;
  float* buf0   = (float*)p; p += SZ_MAP * 4;     // CA2 tmp (oh2/ow2), CA3 tmp
  float* buf1   = (float*)p; p += SZ_MAP * 4;     // cs_hi/lo during CA1-2; then s
  bf16*  vbuf   = (bf16*)p;  p += SZ_MAP * 2;
  bf16*  vT     = (bf16*)p;  p += SZ_MAP * 2;
  bf16*  qhw    = (bf16*)p;  p += (size_t)Bn * CQn * Nn * 2;
  bf16*  khw    = (bf16*)p;  p += (size_t)Bn * CQn * Nn * 2;
  float* ebuf   = (float*)p; p += (size_t)SZ_MAP * 2;         // xT_hi arena (67MB)
  float* logits = (float*)p; p += (size_t)Bn * Nn * 4;
  float* ctxlog = (float*)p; p += (size_t)Bn * Nn * 4;
  float* msp    = (float*)p; p += (size_t)Bn * Nn * 4;
  float* xbar   = (float*)p; p += Bn * Cn * 4;
  float* wgt    = (float*)p; p += Bn * Cn * 4;
  float* u      = (float*)p; p += Bn * Cn * 4;
  float* mch    = (float*)p; p += Bn * Cn * 4;
  float* avg    = (float*)p; p += Bn * CIn * 4;
  float* ctx    = (float*)p; p += Bn * CIn * 4;
  float* stats_sp = (float*)p; p += 64;
  float* stats_ch = (float*)p; p += 64;
  bf16*  wvb    = (bf16*)p;  p += (size_t)Cn * Cn * 2;
  bf16*  wqk_hi = (bf16*)p;  p += (size_t)128 * Cn * 2;
  bf16*  wqk_lo = (bf16*)p;  p += (size_t)128 * Cn * 2;
  float* bqk    = (float*)p; p += 128 * 4;
  float* mh     = (float*)p; p += (size_t)Bn * Nn * 4;
  float* sh     = (float*)p; p += (size_t)Bn * Nn * 4;
  float* mw     = (float*)p; p += (size_t)Bn * Nn * 4;
  float* sw     = (float*)p; p += (size_t)Bn * Nn * 4;
  float* ah1    = (float*)p; p += (size_t)Bn * Nn * 4;
  float* aw1    = (float*)p; p += (size_t)Bn * Nn * 4;
  float* ah2    = (float*)p; p += (size_t)Bn * Nn * 4;
  float* aw2    = (float*)p; p += (size_t)Bn * Nn * 4;
  float* dpart  = (float*)p; p += (size_t)2 * Bn * Nn * 4;    // split-K partials (512KB)

  bf16*  cc_hi  = (bf16*)ebuf;               // dead after CA1's v_mfma
  bf16*  cc_lo  = (bf16*)d_out;              // dead after CA1's qk_mfma
  bf16*  cs_hi  = (bf16*)buf1;               // dead after CA2's v_mfma
  bf16*  cs_lo  = (bf16*)buf1 + SZ_MAP;      // dead after CA2's qk_mfma
  bf16*  xT_hi3 = (bf16*)ebuf;               // CA3 set
  bf16*  xT_lo3 = (bf16*)d_out;              // d_out free after fuse3 consumed oh1/ow1

  // ---- weight prep (once) ----
  k_cvt_w<<<(Cn * Cn + 255) / 256, 256, 0, stream>>>(wv, wvb, Cn * Cn);
  k_prep_wqk<<<(128 * Cn) / 256, 256, 0, stream>>>(wq, wk, bq, bk, wqk_hi, wqk_lo, bqk);

  // ---- stage 0: gating masks ----
  k_dotc2<<<dim3(Bn * Nn / 256, 2), 256, 0, stream>>>(x, w_q_right, 0, dpart);
  k_dotcadd<<<Bn * Nn / 256, 256, 0, stream>>>(dpart, logits);
  k_rowmean<<<Bn * Cn, 256, 0, stream>>>(x, xbar, 1.f / Nn);
  k_rowdot<<<Bn, 256, 0, stream>>>(w_q_left, xbar, avg);
  k_coldot<<<dim3(Cn / 256, Bn), 256, 0, stream>>>(w_v_left, avg, u);
  k_stats<<<Bn, 1024, 0, stream>>>(logits, stats_sp);
  k_weighted<<<Bn * Cn, 256, 0, stream>>>(x, logits, stats_sp, wgt);
  k_rowdot<<<Bn, 256, 0, stream>>>(w_v_right, wgt, ctx);
  k_mch2<<<dim3(Cn / 256, Bn), 256, 0, stream>>>(w_up, b_up, ctx, mch);
  k_dotc2<<<dim3(Bn * Nn / 256, 2), 256, 0, stream>>>(x, u, Cn, dpart);
  k_dotcadd<<<Bn * Nn / 256, 256, 0, stream>>>(dpart, ctxlog);
  k_stats<<<Bn, 1024, 0, stream>>>(ctxlog, stats_ch);
  k_msp<<<Bn * Nn / 256, 256, 0, stream>>>(ctxlog, stats_ch, msp);

  // single x pass: both cc and cs transposed hi/lo sets
  k_applyT3<<<dim3(Nn / 32, Cn / 32, Bn), 256, 0, stream>>>(x, mch, msp,
                                                            cc_hi, cc_lo, cs_hi, cs_lo);

  // ---- CA1 attention only: oh1/ow1 -> d_out, alphas -> ah1/aw1 (no fuse) ----
  run_att(cc_hi, cc_lo, wqk_hi, wqk_lo, bqk, wvb, bv,
          qhw, khw, vbuf, vT, mh, sh, mw, sw, ah1, aw1, (bf16*)d_out, stream);
  // ---- CA2 attention: oh2/ow2 -> buf0, alphas -> ah2/aw2 ----
  run_att(cs_hi, cs_lo, wqk_hi, wqk_lo, bqk, wvb, bv,
          qhw, khw, vbuf, vT, mh, sh, mw, sw, ah2, aw2, (bf16*)buf0, stream);
  // ---- combined fuse: s = g*att1 + g*att2 + x*(mch+msp) -> buf1 ----
  k_fuse3<<<dim3(Cn, 2, Bn), 256, 0, stream>>>(x, mch, msp,
                                               (const bf16*)d_out,
                                               (const bf16*)d_out + SZ_MAP, ah1, aw1,
                                               (const bf16*)buf0,
                                               (const bf16*)buf0 + SZ_MAP, ah2, aw2,
                                               gamma, buf1);
  // ---- CA3: in = s = buf1; tmp = buf0; out = d_out ----
  k_cvt_T<<<dim3(Nn / 32, Cn / 32, Bn), 256, 0, stream>>>(buf1, xT_hi3, xT_lo3);
  run_att(xT_hi3, xT_lo3, wqk_hi, wqk_lo, bqk, wvb, bv,
          qhw, khw, vbuf, vT, mh, sh, mw, sw, ah1, aw1, (bf16*)buf0, stream);
  k_fuse2<<<dim3(Cn, 2, Bn), 256, 0, stream>>>(buf1, (const bf16*)buf0,
                                               (const bf16*)buf0 + SZ_MAP, ah1, aw1,
                                               gamma, (float*)d_out);
}

// Round 20
// 1237.183 us; speedup vs baseline: 1.3725x; 1.0239x over previous
//
#include <hip/hip_runtime.h>
#include <hip/hip_bf16.h>
#include <math.h>

typedef __hip_bfloat16 bf16;
typedef __attribute__((ext_vector_type(8))) short s16x8;
typedef __attribute__((ext_vector_type(4))) float f32x4;

constexpr int Bn  = 4;
constexpr int Cn  = 512;
constexpr int Hn  = 128;
constexpr int Wn  = 128;
constexpr int Nn  = Hn * Wn;   // 16384
constexpr int CQn = 64;
constexpr int CIn = 256;

__device__ __forceinline__ float bf2f(bf16 v){ return __bfloat162float(v); }
__device__ __forceinline__ bf16  f2bf(float v){ return __float2bfloat16(v); }

// async global->LDS, 16B per lane; LDS dest must be wave-uniform base (HW adds lane*16)
__device__ __forceinline__ void gload_lds16(const void* g, void* l){
  __builtin_amdgcn_global_load_lds(
      (const __attribute__((address_space(1))) unsigned int*)g,
      (__attribute__((address_space(3))) unsigned int*)l,
      16, 0, 0);
}

// ============================ stage 0 ============================

// split-K column dot: part[half][b*Nn+n] = sum_{c in half} w[c]*x[b][c][n]
__global__ __launch_bounds__(256) void k_dotc2(const float* __restrict__ x,
                                               const float* __restrict__ w,
                                               int wstride,
                                               float* __restrict__ part){
  int t = blockIdx.x * 256 + threadIdx.x;      // over B*Nn
  int half = blockIdx.y;
  int b = t >> 14;
  const float* wp = w + (size_t)b * wstride + half * 256;
  const float* xp = x + (size_t)b * Cn * Nn + (size_t)(half * 256) * Nn + (t & (Nn - 1));
  float acc = 0.f;
  #pragma unroll 16
  for (int c = 0; c < 256; ++c) acc += wp[c] * xp[(size_t)c * Nn];
  part[(size_t)half * (Bn * Nn) + t] = acc;
}

__global__ __launch_bounds__(256) void k_dotcadd(const float* __restrict__ part,
                                                 float* __restrict__ out){
  int t = blockIdx.x * 256 + threadIdx.x;
  out[t] = part[t] + part[(size_t)Bn * Nn + t];
}

__global__ __launch_bounds__(256) void k_rowmean(const float* __restrict__ x,
                                                 float* __restrict__ out,
                                                 float scale){
  int bc = blockIdx.x;
  const float* xp = x + (size_t)bc * Nn;
  float acc = 0.f;
  for (int n = threadIdx.x; n < Nn; n += 256) acc += xp[n];
  for (int o = 32; o > 0; o >>= 1) acc += __shfl_down(acc, o);
  __shared__ float red[4];
  if ((threadIdx.x & 63) == 0) red[threadIdx.x >> 6] = acc;
  __syncthreads();
  if (threadIdx.x == 0) out[bc] = (red[0] + red[1] + red[2] + red[3]) * scale;
}

__global__ __launch_bounds__(256) void k_rowdot(const float* __restrict__ W,
                                                const float* __restrict__ vec,
                                                float* __restrict__ out){
  __shared__ float vs[Cn];
  int b = blockIdx.x, t = threadIdx.x;
  for (int j = t; j < Cn; j += 256) vs[j] = vec[b * Cn + j];
  __syncthreads();
  const float4* wp = (const float4*)(W + (size_t)t * Cn);
  float a = 0.f;
  #pragma unroll 4
  for (int j = 0; j < Cn / 4; ++j){
    float4 w4 = wp[j];
    a += w4.x * vs[4*j] + w4.y * vs[4*j+1] + w4.z * vs[4*j+2] + w4.w * vs[4*j+3];
  }
  out[b * CIn + t] = a;
}

__global__ __launch_bounds__(256) void k_coldot(const float* __restrict__ W,
                                                const float* __restrict__ vec,
                                                float* __restrict__ out){
  __shared__ float vs[CIn];
  int b = blockIdx.y, t = threadIdx.x;
  int c = blockIdx.x * 256 + t;
  if (t < CIn) vs[t] = vec[b * CIn + t];
  __syncthreads();
  float a = 0.f;
  #pragma unroll 8
  for (int j = 0; j < CIn; ++j) a += W[(size_t)j * Cn + c] * vs[j];
  out[b * Cn + c] = a;
}

__global__ __launch_bounds__(256) void k_mch2(const float* __restrict__ w_up,
                                              const float* __restrict__ b_up,
                                              const float* __restrict__ ctx,
                                              float* __restrict__ mch){
  __shared__ float cs[CIn];
  int b = blockIdx.y, t = threadIdx.x;
  int o = blockIdx.x * 256 + t;
  if (t < CIn) cs[t] = ctx[b * CIn + t];
  __syncthreads();
  const float4* wp = (const float4*)(w_up + (size_t)o * CIn);
  float a = b_up[o];
  #pragma unroll 4
  for (int j = 0; j < CIn / 4; ++j){
    float4 w4 = wp[j];
    a += w4.x * cs[4*j] + w4.y * cs[4*j+1] + w4.z * cs[4*j+2] + w4.w * cs[4*j+3];
  }
  mch[b * Cn + o] = 1.f / (1.f + expf(-a));
}

__global__ __launch_bounds__(1024) void k_stats(const float* __restrict__ vv,
                                                float* __restrict__ stats){
  int b = blockIdx.x;
  const float* pp = vv + (size_t)b * Nn;
  int t = threadIdx.x;
  float m = -3.4e38f;
  for (int n = t; n < Nn; n += 1024) m = fmaxf(m, pp[n]);
  for (int o = 32; o > 0; o >>= 1) m = fmaxf(m, __shfl_down(m, o));
  __shared__ float red[16];
  int wid = t >> 6, lid = t & 63;
  if (lid == 0) red[wid] = m;
  __syncthreads();
  if (t == 0){
    float q = red[0];
    for (int i = 1; i < 16; i++) q = fmaxf(q, red[i]);
    red[0] = q;
  }
  __syncthreads();
  m = red[0];
  __syncthreads();
  float s = 0.f;
  for (int n = t; n < Nn; n += 1024) s += expf(pp[n] - m);
  for (int o = 32; o > 0; o >>= 1) s += __shfl_down(s, o);
  if (lid == 0) red[wid] = s;
  __syncthreads();
  if (t == 0){
    float q = 0.f;
    for (int i = 0; i < 16; i++) q += red[i];
    stats[b * 2]     = m;
    stats[b * 2 + 1] = q;
  }
}

__global__ __launch_bounds__(256) void k_weighted(const float* __restrict__ x,
                                                  const float* __restrict__ logits,
                                                  const float* __restrict__ stats,
                                                  float* __restrict__ out){
  int bc = blockIdx.x;
  int b = bc >> 9;
  const float* xp = x + (size_t)bc * Nn;
  const float* lp = logits + (size_t)b * Nn;
  float m = stats[b * 2], den = stats[b * 2 + 1];
  float acc = 0.f;
  for (int n = threadIdx.x; n < Nn; n += 256) acc += xp[n] * expf(lp[n] - m);
  for (int o = 32; o > 0; o >>= 1) acc += __shfl_down(acc, o);
  __shared__ float red[4];
  if ((threadIdx.x & 63) == 0) red[threadIdx.x >> 6] = acc;
  __syncthreads();
  if (threadIdx.x == 0) out[bc] = (red[0] + red[1] + red[2] + red[3]) / den;
}

__global__ __launch_bounds__(256) void k_msp(const float* __restrict__ lg,
                                             const float* __restrict__ stats,
                                             float* __restrict__ msp){
  int t = blockIdx.x * 256 + threadIdx.x;
  int b = t >> 14;
  float v = expf(lg[t] - stats[b * 2]) / stats[b * 2 + 1];
  msp[t] = 1.f / (1.f + expf(-v));
}

// ============================ conversions / weight prep ============================

__global__ __launch_bounds__(256) void k_cvt_w(const float* __restrict__ in,
                                               bf16* __restrict__ out, int n){
  int t = blockIdx.x * 256 + threadIdx.x;
  if (t < n) out[t] = f2bf(in[t]);
}

__global__ __launch_bounds__(256) void k_prep_wqk(const float* __restrict__ wq,
                                                  const float* __restrict__ wk,
                                                  const float* __restrict__ bq,
                                                  const float* __restrict__ bk,
                                                  bf16* __restrict__ wqk_hi,
                                                  bf16* __restrict__ wqk_lo,
                                                  float* __restrict__ bqk){
  int t = blockIdx.x * 256 + threadIdx.x;   // over 128*512
  int o = t >> 9, c = t & 511;
  float v = (o < 64) ? wq[(size_t)o * Cn + c] : wk[(size_t)(o - 64) * Cn + c];
  bf16 h = f2bf(v);
  wqk_hi[t] = h;
  wqk_lo[t] = f2bf(v - bf2f(h));
  if (t < 128) bqk[t] = (t < 64) ? bq[t] : bk[t - 64];
}

// per-b mch-folded QK weights: w[b][o][c] = wqk[o][c] * mch[b][c] (hi/lo)
__global__ __launch_bounds__(256) void k_prep_wqk_mch(const float* __restrict__ wq,
                                                      const float* __restrict__ wk,
                                                      const float* __restrict__ mch,
                                                      bf16* __restrict__ hi,
                                                      bf16* __restrict__ lo){
  int t = blockIdx.x * 256 + threadIdx.x;   // over Bn*128*Cn = 262144
  int b = t >> 16;
  int oc = t & 65535;
  int o = oc >> 9, c = oc & 511;
  float w = (o < 64) ? wq[(size_t)o * Cn + c] : wk[(size_t)(o - 64) * Cn + c];
  float v = w * mch[b * Cn + c];
  bf16 h = f2bf(v);
  hi[t] = h;
  lo[t] = f2bf(v - bf2f(h));
}

// per-b mch-folded V weights: w[b][o][c] = bf16(wv[o][c] * mch[b][c])
__global__ __launch_bounds__(256) void k_prep_wv_mch(const float* __restrict__ wv,
                                                     const float* __restrict__ mch,
                                                     bf16* __restrict__ out){
  int t = blockIdx.x * 256 + threadIdx.x;   // over Bn*Cn*Cn = 1048576
  int b = t >> 18;
  int oc = t & 262143;
  int c = oc & 511;
  out[t] = f2bf(wv[oc] * mch[b * Cn + c]);
}

__global__ __launch_bounds__(256) void k_cvt_T(const float* __restrict__ in,
                                               bf16* __restrict__ out_hi,
                                               bf16* __restrict__ out_lo){
  __shared__ bf16 th_[32][33];
  __shared__ bf16 tl_[32][33];
  int nt = blockIdx.x, ct = blockIdx.y, b = blockIdx.z;
  int n0 = nt * 32, c0 = ct * 32;
  int t = threadIdx.x;
  #pragma unroll
  for (int kk = 0; kk < 4; ++kk){
    int idx = t + kk * 256;
    int cl = idx >> 5, nl = idx & 31;
    float v = in[((size_t)(b * Cn + c0 + cl)) * Nn + n0 + nl];
    bf16 h = f2bf(v);
    th_[cl][nl] = h;
    tl_[cl][nl] = f2bf(v - bf2f(h));
  }
  __syncthreads();
  #pragma unroll
  for (int kk = 0; kk < 4; ++kk){
    int idx = t + kk * 256;
    int nl = idx >> 5, cl = idx & 31;
    size_t o = ((size_t)(b * Nn + n0 + nl)) * Cn + c0 + cl;
    out_hi[o] = th_[cl][nl];
    out_lo[o] = tl_[cl][nl];
  }
}

// ============================ MFMA GEMMs ============================

// V = Wv @ X (+ optional per-n scale). 128x128 tile, BK=64. XCD-chunked 1D grid of 2048.
// wstride: per-b weight stride (0 = shared weights).
__global__ __launch_bounds__(256) void k_v_mfma(const bf16* __restrict__ xT,
                                                const bf16* __restrict__ wvb,
                                                int wstride,
                                                const float* __restrict__ bv,
                                                const float* __restrict__ nscale,
                                                bf16* __restrict__ v){
  __shared__ short As[128 * 64];
  __shared__ short Bs[128 * 64];
  __shared__ float bvs[128];
  int lin = blockIdx.x;
  int swz = (lin & 7) * 256 + (lin >> 3);
  int cb = (swz & 3) * 128;
  int nb = ((swz >> 2) & 127) * 128;
  int b  = swz >> 9;
  int t = threadIdx.x, lane = t & 63, wid = t >> 6;
  int wm = wid >> 1, wn = wid & 1;
  int l15 = lane & 15, l4 = lane >> 4;
  if (t < 128) bvs[t] = bv[cb + t];
  f32x4 acc[4][4];
  #pragma unroll
  for (int i = 0; i < 4; i++)
    #pragma unroll
    for (int j = 0; j < 4; j++) acc[i][j] = (f32x4){0.f, 0.f, 0.f, 0.f};

  const bf16* wp = wvb + (size_t)b * wstride + (size_t)cb * Cn;
  const bf16* xp = xT + ((size_t)b * Nn + nb) * Cn;
  int r8 = lane >> 3;
  int kc = (lane & 7) * 8;
  for (int kt = 0; kt < 8; ++kt){
    int k0 = kt * 64;
    #pragma unroll
    for (int j = 0; j < 4; ++j){
      int inst = wid * 4 + j;
      int row = inst * 8 + r8;
      gload_lds16(wp + (size_t)row * Cn + k0 + kc, (char*)As + inst * 1024);
      gload_lds16(xp + (size_t)row * Cn + k0 + kc, (char*)Bs + inst * 1024);
    }
    __syncthreads();
    #pragma unroll
    for (int kk = 0; kk < 64; kk += 32){
      s16x8 a[4], bb[4];
      #pragma unroll
      for (int mi = 0; mi < 4; mi++)
        a[mi] = *(const s16x8*)&As[(wm * 64 + mi * 16 + l15) * 64 + kk + l4 * 8];
      #pragma unroll
      for (int ni = 0; ni < 4; ni++)
        bb[ni] = *(const s16x8*)&Bs[(wn * 64 + ni * 16 + l15) * 64 + kk + l4 * 8];
      #pragma unroll
      for (int mi = 0; mi < 4; mi++)
        #pragma unroll
        for (int ni = 0; ni < 4; ni++)
          acc[mi][ni] = __builtin_amdgcn_mfma_f32_16x16x32_bf16(a[mi], bb[ni], acc[mi][ni], 0, 0, 0);
    }
    __syncthreads();
  }
  float sc[4];
  #pragma unroll
  for (int ni = 0; ni < 4; ni++)
    sc[ni] = nscale ? nscale[(size_t)b * Nn + nb + wn * 64 + ni * 16 + l15] : 1.f;
  #pragma unroll
  for (int mi = 0; mi < 4; mi++){
    #pragma unroll
    for (int r = 0; r < 4; r++){
      int cl = wm * 64 + mi * 16 + l4 * 4 + r;
      int c  = cb + cl;
      float bias = bvs[cl];
      #pragma unroll
      for (int ni = 0; ni < 4; ni++){
        int n = nb + wn * 64 + ni * 16 + l15;
        v[((size_t)(b * Cn + c)) * Nn + n] = f2bf(acc[mi][ni][r] * sc[ni] + bias);
      }
    }
  }
}

// Q,K = Wqk @ X (+ optional per-n scale), split-precision bf16 (3 MFMA terms).
// Writes qhw/khw ([b][w][h][c]) DIRECTLY via LDS transpose epilogue.
// wstride: per-b weight stride (0 = shared weights).
__global__ __launch_bounds__(256) void k_qk_mfma(const bf16* __restrict__ xT_hi,
                                                 const bf16* __restrict__ xT_lo,
                                                 const bf16* __restrict__ wqk_hi,
                                                 const bf16* __restrict__ wqk_lo,
                                                 int wstride,
                                                 const float* __restrict__ bqk,
                                                 const float* __restrict__ nscale,
                                                 bf16* __restrict__ qhw,
                                                 bf16* __restrict__ khw){
  __shared__ char smem[65536];
  short* Ah = (short*)smem;
  short* Al = Ah + 8192;
  short* Bh = Al + 8192;
  short* Bl = Bh + 8192;
  char*  Os = smem;                 // reused after final K-loop barrier (32KB)
  __shared__ float bs[128];
  int h = blockIdx.x, b = blockIdx.y;      // block covers n = h*128 + w, w=0..127
  int nb = h * 128;
  int t = threadIdx.x, lane = t & 63, wid = t >> 6;
  int wm = wid >> 1, wn = wid & 1;
  int l15 = lane & 15, l4 = lane >> 4;
  if (t < 128) bs[t] = bqk[t];
  f32x4 acc[4][4];
  #pragma unroll
  for (int i = 0; i < 4; i++)
    #pragma unroll
    for (int j = 0; j < 4; j++) acc[i][j] = (f32x4){0.f, 0.f, 0.f, 0.f};

  const bf16* wh = wqk_hi + (size_t)b * wstride;
  const bf16* wl = wqk_lo + (size_t)b * wstride;
  const bf16* xh = xT_hi + ((size_t)b * Nn + nb) * Cn;
  const bf16* xl = xT_lo + ((size_t)b * Nn + nb) * Cn;
  int r8 = lane >> 3;
  int kc = (lane & 7) * 8;
  for (int kt = 0; kt < 8; ++kt){
    int k0 = kt * 64;
    #pragma unroll
    for (int j = 0; j < 4; ++j){
      int inst = wid * 4 + j;
      int row = inst * 8 + r8;
      size_t off = (size_t)row * Cn + k0 + kc;
      gload_lds16(wh + off, (char*)Ah + inst * 1024);
      gload_lds16(wl + off, (char*)Al + inst * 1024);
      gload_lds16(xh + off, (char*)Bh + inst * 1024);
      gload_lds16(xl + off, (char*)Bl + inst * 1024);
    }
    __syncthreads();
    #pragma unroll
    for (int kk = 0; kk < 64; kk += 32){
      s16x8 ah[4], al[4], bh[4], bl[4];
      #pragma unroll
      for (int mi = 0; mi < 4; mi++){
        int idx = (wm * 64 + mi * 16 + l15) * 64 + kk + l4 * 8;
        ah[mi] = *(const s16x8*)&Ah[idx];
        al[mi] = *(const s16x8*)&Al[idx];
      }
      #pragma unroll
      for (int ni = 0; ni < 4; ni++){
        int idx = (wn * 64 + ni * 16 + l15) * 64 + kk + l4 * 8;
        bh[ni] = *(const s16x8*)&Bh[idx];
        bl[ni] = *(const s16x8*)&Bl[idx];
      }
      #pragma unroll
      for (int mi = 0; mi < 4; mi++)
        #pragma unroll
        for (int ni = 0; ni < 4; ni++){
          acc[mi][ni] = __builtin_amdgcn_mfma_f32_16x16x32_bf16(ah[mi], bh[ni], acc[mi][ni], 0, 0, 0);
          acc[mi][ni] = __builtin_amdgcn_mfma_f32_16x16x32_bf16(ah[mi], bl[ni], acc[mi][ni], 0, 0, 0);
          acc[mi][ni] = __builtin_amdgcn_mfma_f32_16x16x32_bf16(al[mi], bh[ni], acc[mi][ni], 0, 0, 0);
        }
    }
    __syncthreads();
  }
  float sc[4];
  #pragma unroll
  for (int ni = 0; ni < 4; ni++)
    sc[ni] = nscale ? nscale[(size_t)b * Nn + nb + wn * 64 + ni * 16 + l15] : 1.f;
  // epilogue: Os[n][o] bf16 (256B rows, XOR-swizzled), then 128B row stores
  #pragma unroll
  for (int mi = 0; mi < 4; mi++){
    #pragma unroll
    for (int r = 0; r < 4; r++){
      int o = wm * 64 + mi * 16 + l4 * 4 + r;
      float bias = bs[o];
      #pragma unroll
      for (int ni = 0; ni < 4; ni++){
        int n = wn * 64 + ni * 16 + l15;
        bf16 bv = f2bf(acc[mi][ni][r] * sc[ni] + bias);
        int byte = (n * 256 + o * 2) ^ ((n & 7) << 4);
        *(unsigned short*)(Os + byte) = *(unsigned short*)&bv;
      }
    }
  }
  __syncthreads();
  #pragma unroll
  for (int i = 0; i < 8; ++i){
    int s = t + i * 256;            // 0..2047: row = s>>3 (w + 128*qk), seg = s&7
    int row = s >> 3, seg = s & 7;
    int w = row & 127, qk = row >> 7;
    int o0 = qk * 64 + seg * 8;
    int byte = (w * 256 + o0 * 2) ^ ((w & 7) << 4);
    s16x8 d = *(const s16x8*)(Os + byte);
    bf16* dst = (qk == 0 ? qhw : khw) + (((size_t)b * Wn + w) * Hn + h) * CQn + seg * 8;
    *(s16x8*)dst = d;
  }
}

// ============================ fused attention ============================

// per (b,w): MFMA e_h from qhw/khw ([b][w][h][c]), diag, stats, p->LDS, PV MFMA.
// ohX layout [b][c][w][h] (unnormalized; alpha in fuse).
__global__ __launch_bounds__(256) void k_att_h(const bf16* __restrict__ qhw,
                                               const bf16* __restrict__ khw,
                                               const bf16* __restrict__ vT,
                                               float* __restrict__ mh,
                                               float* __restrict__ sh,
                                               bf16* __restrict__ ohX){
  __shared__ char smem[65536];
  char* attb = smem;                 // p tile 32KB
  char* vbb  = smem + 32768;         // V tile 32KB (e-phase: first 2KB = stats)
  float* redm = (float*)(smem + 32768);        // [2][128]
  float* reds = redm + 256;                    // [2][128]
  int w = blockIdx.x, b = blockIdx.y;
  int t = threadIdx.x, lane = t & 63, wid = t >> 6;
  int wm = wid >> 1, wn = wid & 1;
  int l15 = lane & 15, l4 = lane >> 4;

  const bf16* qp = qhw + ((size_t)(b * Wn + w)) * (Hn * CQn);
  const bf16* kp = khw + ((size_t)(b * Wn + w)) * (Hn * CQn);
  f32x4 acc[4][4];
  #pragma unroll
  for (int i = 0; i < 4; i++)
    #pragma unroll
    for (int j = 0; j < 4; j++) acc[i][j] = (f32x4){0.f, 0.f, 0.f, 0.f};
  #pragma unroll
  for (int kk = 0; kk < 64; kk += 32){
    s16x8 a[4], bb[4];
    #pragma unroll
    for (int mi = 0; mi < 4; mi++)
      a[mi] = *(const s16x8*)(qp + (size_t)(wm * 64 + mi * 16 + l15) * CQn + kk + l4 * 8);
    #pragma unroll
    for (int ni = 0; ni < 4; ni++)
      bb[ni] = *(const s16x8*)(kp + (size_t)(wn * 64 + ni * 16 + l15) * CQn + kk + l4 * 8);
    #pragma unroll
    for (int mi = 0; mi < 4; mi++)
      #pragma unroll
      for (int ni = 0; ni < 4; ni++)
        acc[mi][ni] = __builtin_amdgcn_mfma_f32_16x16x32_bf16(a[mi], bb[ni], acc[mi][ni], 0, 0, 0);
  }
  // diag mask: h==g
  if (wm == wn){
    #pragma unroll
    for (int mi = 0; mi < 4; mi++)
      #pragma unroll
      for (int r = 0; r < 4; r++)
        if (l15 == l4 * 4 + r) acc[mi][mi][r] = -1e30f;
  }
  float rm[4][4];
  #pragma unroll
  for (int mi = 0; mi < 4; mi++)
    #pragma unroll
    for (int r = 0; r < 4; r++){
      float m = fmaxf(fmaxf(acc[mi][0][r], acc[mi][1][r]),
                      fmaxf(acc[mi][2][r], acc[mi][3][r]));
      m = fmaxf(m, __shfl_xor(m, 1));
      m = fmaxf(m, __shfl_xor(m, 2));
      m = fmaxf(m, __shfl_xor(m, 4));
      m = fmaxf(m, __shfl_xor(m, 8));
      rm[mi][r] = m;
    }
  if (l15 == 0){
    #pragma unroll
    for (int mi = 0; mi < 4; mi++)
      #pragma unroll
      for (int r = 0; r < 4; r++)
        redm[wn * 128 + wm * 64 + mi * 16 + l4 * 4 + r] = rm[mi][r];
  }
  __syncthreads();
  float rs[4][4];
  #pragma unroll
  for (int mi = 0; mi < 4; mi++)
    #pragma unroll
    for (int r = 0; r < 4; r++){
      int h = wm * 64 + mi * 16 + l4 * 4 + r;
      float m = fmaxf(redm[h], redm[128 + h]);
      rm[mi][r] = m;
      float s = 0.f;
      #pragma unroll
      for (int ni = 0; ni < 4; ni++){
        acc[mi][ni][r] = expf(acc[mi][ni][r] - m);
        s += acc[mi][ni][r];
      }
      s += __shfl_xor(s, 1);
      s += __shfl_xor(s, 2);
      s += __shfl_xor(s, 4);
      s += __shfl_xor(s, 8);
      rs[mi][r] = s;
    }
  if (l15 == 0){
    #pragma unroll
    for (int mi = 0; mi < 4; mi++)
      #pragma unroll
      for (int r = 0; r < 4; r++)
        reds[wn * 128 + wm * 64 + mi * 16 + l4 * 4 + r] = rs[mi][r];
  }
  __syncthreads();
  #pragma unroll
  for (int mi = 0; mi < 4; mi++)
    #pragma unroll
    for (int r = 0; r < 4; r++){
      int h = wm * 64 + mi * 16 + l4 * 4 + r;
      if (wn == 0 && l15 == 0){
        mh[(size_t)(b * Wn + w) * Hn + h] = rm[mi][r];
        sh[(size_t)(b * Wn + w) * Hn + h] = reds[h] + reds[128 + h];
      }
      #pragma unroll
      for (int ni = 0; ni < 4; ni++){
        int g = wn * 64 + ni * 16 + l15;
        bf16 bv = f2bf(acc[mi][ni][r]);
        int byte = (h * 256 + g * 2) ^ ((h & 7) << 4);
        *(unsigned short*)(attb + byte) = *(unsigned short*)&bv;
      }
    }
  __syncthreads();
  // PV MFMA over 4 c-tiles
  for (int cb = 0; cb < Cn; cb += 128){
    const bf16* vp = vT + ((size_t)(b * Wn + w) * Cn + cb) * Hn;
    for (int s = t; s < 2048; s += 256){
      int row = s >> 4, seg = s & 15;
      s16x8 d = *(const s16x8*)(vp + (size_t)row * Hn + seg * 8);
      int byte = (row * 256 + seg * 16) ^ ((row & 7) << 4);
      *(s16x8*)(vbb + byte) = d;
    }
    __syncthreads();
    f32x4 acc2[4][4];
    #pragma unroll
    for (int i = 0; i < 4; i++)
      #pragma unroll
      for (int j = 0; j < 4; j++) acc2[i][j] = (f32x4){0.f, 0.f, 0.f, 0.f};
    #pragma unroll
    for (int kk = 0; kk < 128; kk += 32){
      s16x8 a[4], bb[4];
      #pragma unroll
      for (int mi = 0; mi < 4; mi++){
        int row = wm * 64 + mi * 16 + l15;
        int byte = (row * 256 + (kk + l4 * 8) * 2) ^ ((row & 7) << 4);
        a[mi] = *(const s16x8*)(vbb + byte);
      }
      #pragma unroll
      for (int ni = 0; ni < 4; ni++){
        int row = wn * 64 + ni * 16 + l15;
        int byte = (row * 256 + (kk + l4 * 8) * 2) ^ ((row & 7) << 4);
        bb[ni] = *(const s16x8*)(attb + byte);
      }
      #pragma unroll
      for (int mi = 0; mi < 4; mi++)
        #pragma unroll
        for (int ni = 0; ni < 4; ni++)
          acc2[mi][ni] = __builtin_amdgcn_mfma_f32_16x16x32_bf16(a[mi], bb[ni], acc2[mi][ni], 0, 0, 0);
    }
    bf16* op = ohX + ((size_t)(b * Cn + cb)) * Nn + (size_t)w * Hn;
    #pragma unroll
    for (int mi = 0; mi < 4; mi++)
      #pragma unroll
      for (int r = 0; r < 4; r++){
        int cl = wm * 64 + mi * 16 + l4 * 4 + r;
        #pragma unroll
        for (int ni = 0; ni < 4; ni++){
          int h = wn * 64 + ni * 16 + l15;
          op[(size_t)cl * Nn + h] = f2bf(acc2[mi][ni][r]);
        }
      }
    __syncthreads();
  }
}

// per (b,h): MFMA e_w from qhw/khw (strided rows), stats, p->LDS, PV MFMA.
__global__ __launch_bounds__(256) void k_att_w(const bf16* __restrict__ qhw,
                                               const bf16* __restrict__ khw,
                                               const bf16* __restrict__ v,
                                               float* __restrict__ mw,
                                               float* __restrict__ sw,
                                               bf16* __restrict__ ow){
  __shared__ char smem[65536];
  char* attb = smem;
  char* vbb  = smem + 32768;
  float* redm = (float*)(smem + 32768);
  float* reds = redm + 256;
  int h = blockIdx.x, b = blockIdx.y;
  int t = threadIdx.x, lane = t & 63, wid = t >> 6;
  int wm = wid >> 1, wn = wid & 1;
  int l15 = lane & 15, l4 = lane >> 4;

  const bf16* qp = qhw + (size_t)b * Wn * Hn * CQn + (size_t)h * CQn;
  const bf16* kp = khw + (size_t)b * Wn * Hn * CQn + (size_t)h * CQn;
  f32x4 acc[4][4];
  #pragma unroll
  for (int i = 0; i < 4; i++)
    #pragma unroll
    for (int j = 0; j < 4; j++) acc[i][j] = (f32x4){0.f, 0.f, 0.f, 0.f};
  #pragma unroll
  for (int kk = 0; kk < 64; kk += 32){
    s16x8 a[4], bb[4];
    #pragma unroll
    for (int mi = 0; mi < 4; mi++)
      a[mi] = *(const s16x8*)(qp + (size_t)(wm * 64 + mi * 16 + l15) * (Hn * CQn) + kk + l4 * 8);
    #pragma unroll
    for (int ni = 0; ni < 4; ni++)
      bb[ni] = *(const s16x8*)(kp + (size_t)(wn * 64 + ni * 16 + l15) * (Hn * CQn) + kk + l4 * 8);
    #pragma unroll
    for (int mi = 0; mi < 4; mi++)
      #pragma unroll
      for (int ni = 0; ni < 4; ni++)
        acc[mi][ni] = __builtin_amdgcn_mfma_f32_16x16x32_bf16(a[mi], bb[ni], acc[mi][ni], 0, 0, 0);
  }
  float rm[4][4];
  #pragma unroll
  for (int mi = 0; mi < 4; mi++)
    #pragma unroll
    for (int r = 0; r < 4; r++){
      float m = fmaxf(fmaxf(acc[mi][0][r], acc[mi][1][r]),
                      fmaxf(acc[mi][2][r], acc[mi][3][r]));
      m = fmaxf(m, __shfl_xor(m, 1));
      m = fmaxf(m, __shfl_xor(m, 2));
      m = fmaxf(m, __shfl_xor(m, 4));
      m = fmaxf(m, __shfl_xor(m, 8));
      rm[mi][r] = m;
    }
  if (l15 == 0){
    #pragma unroll
    for (int mi = 0; mi < 4; mi++)
      #pragma unroll
      for (int r = 0; r < 4; r++)
        redm[wn * 128 + wm * 64 + mi * 16 + l4 * 4 + r] = rm[mi][r];
  }
  __syncthreads();
  float rs[4][4];
  #pragma unroll
  for (int mi = 0; mi < 4; mi++)
    #pragma unroll
    for (int r = 0; r < 4; r++){
      int wr = wm * 64 + mi * 16 + l4 * 4 + r;
      float m = fmaxf(redm[wr], redm[128 + wr]);
      rm[mi][r] = m;
      float s = 0.f;
      #pragma unroll
      for (int ni = 0; ni < 4; ni++){
        acc[mi][ni][r] = expf(acc[mi][ni][r] - m);
        s += acc[mi][ni][r];
      }
      s += __shfl_xor(s, 1);
      s += __shfl_xor(s, 2);
      s += __shfl_xor(s, 4);
      s += __shfl_xor(s, 8);
      rs[mi][r] = s;
    }
  if (l15 == 0){
    #pragma unroll
    for (int mi = 0; mi < 4; mi++)
      #pragma unroll
      for (int r = 0; r < 4; r++)
        reds[wn * 128 + wm * 64 + mi * 16 + l4 * 4 + r] = rs[mi][r];
  }
  __syncthreads();
  #pragma unroll
  for (int mi = 0; mi < 4; mi++)
    #pragma unroll
    for (int r = 0; r < 4; r++){
      int wr = wm * 64 + mi * 16 + l4 * 4 + r;
      if (wn == 0 && l15 == 0){
        mw[(size_t)(b * Hn + h) * Wn + wr] = rm[mi][r];
        sw[(size_t)(b * Hn + h) * Wn + wr] = reds[wr] + reds[128 + wr];
      }
      #pragma unroll
      for (int ni = 0; ni < 4; ni++){
        int g = wn * 64 + ni * 16 + l15;
        bf16 bv = f2bf(acc[mi][ni][r]);
        int byte = (wr * 256 + g * 2) ^ ((wr & 7) << 4);
        *(unsigned short*)(attb + byte) = *(unsigned short*)&bv;
      }
    }
  __syncthreads();
  for (int cb = 0; cb < Cn; cb += 128){
    const bf16* vp = v + (size_t)(b * Cn + cb) * Nn + (size_t)h * Wn;
    for (int s = t; s < 2048; s += 256){
      int row = s >> 4, seg = s & 15;
      s16x8 d = *(const s16x8*)(vp + (size_t)row * Nn + seg * 8);
      int byte = (row * 256 + seg * 16) ^ ((row & 7) << 4);
      *(s16x8*)(vbb + byte) = d;
    }
    __syncthreads();
    f32x4 acc2[4][4];
    #pragma unroll
    for (int i = 0; i < 4; i++)
      #pragma unroll
      for (int j = 0; j < 4; j++) acc2[i][j] = (f32x4){0.f, 0.f, 0.f, 0.f};
    #pragma unroll
    for (int kk = 0; kk < 128; kk += 32){
      s16x8 a[4], bb[4];
      #pragma unroll
      for (int mi = 0; mi < 4; mi++){
        int row = wm * 64 + mi * 16 + l15;
        int byte = (row * 256 + (kk + l4 * 8) * 2) ^ ((row & 7) << 4);
        a[mi] = *(const s16x8*)(vbb + byte);
      }
      #pragma unroll
      for (int ni = 0; ni < 4; ni++){
        int row = wn * 64 + ni * 16 + l15;
        int byte = (row * 256 + (kk + l4 * 8) * 2) ^ ((row & 7) << 4);
        bb[ni] = *(const s16x8*)(attb + byte);
      }
      #pragma unroll
      for (int mi = 0; mi < 4; mi++)
        #pragma unroll
        for (int ni = 0; ni < 4; ni++)
          acc2[mi][ni] = __builtin_amdgcn_mfma_f32_16x16x32_bf16(a[mi], bb[ni], acc2[mi][ni], 0, 0, 0);
    }
    bf16* op = ow + (size_t)(b * Cn + cb) * Nn + (size_t)h * Wn;
    #pragma unroll
    for (int mi = 0; mi < 4; mi++)
      #pragma unroll
      for (int r = 0; r < 4; r++){
        int cl = wm * 64 + mi * 16 + l4 * 4 + r;
        #pragma unroll
        for (int ni = 0; ni < 4; ni++){
          int wr = wn * 64 + ni * 16 + l15;
          op[(size_t)cl * Nn + wr] = f2bf(acc2[mi][ni][r]);
        }
      }
    __syncthreads();
  }
}

// merge stats -> alphas, both in [b,h,w] layout for fuse
__global__ __launch_bounds__(256) void k_alpha(const float* __restrict__ mh,
                                               const float* __restrict__ sh,
                                               const float* __restrict__ mw,
                                               const float* __restrict__ sw,
                                               float* __restrict__ ahT,
                                               float* __restrict__ aw){
  int t = blockIdx.x * 256 + threadIdx.x;   // (b*Hn+h)*Wn + w
  int b = t >> 14;
  int hw = t & (Nn - 1);
  int h = hw >> 7, w = hw & 127;
  size_t ih = (size_t)(b * Wn + w) * Hn + h;
  size_t iw = t;
  float mhv = mh[ih], mwv = mw[iw];
  float M = fmaxf(mhv, mwv);
  float eh_ = expf(mhv - M), ew_ = expf(mwv - M);
  float inv = 1.f / (sh[ih] * eh_ + sw[iw] * ew_);
  ahT[t] = eh_ * inv;
  aw[t]  = ew_ * inv;
}

// ============================ remaining CA kernels ============================

__global__ __launch_bounds__(256) void k_trans(const bf16* __restrict__ in,
                                               bf16* __restrict__ out,
                                               int CH){
  __shared__ bf16 tile[32][33];
  int tl = blockIdx.x, c = blockIdx.y, b = blockIdx.z;
  int th = tl >> 2, tw = tl & 3;
  int h0 = th * 32, w0 = tw * 32;
  int t = threadIdx.x;
  const bf16* ip = in + ((size_t)(b * CH + c)) * Nn;
  #pragma unroll
  for (int kk = 0; kk < 4; ++kk){
    int idx = t + kk * 256;
    int hl = idx >> 5, wl = idx & 31;
    tile[hl][wl] = ip[(h0 + hl) * Wn + w0 + wl];
  }
  __syncthreads();
  #pragma unroll
  for (int kk = 0; kk < 4; ++kk){
    int idx = t + kk * 256;
    int wl = idx >> 5, hl = idx & 31;
    out[((size_t)(b * Wn + w0 + wl) * CH + c) * Hn + h0 + hl] = tile[hl][wl];
  }
}

// out = gamma*(ah*ohX^T + aw*ow) + resid  [single attention set]
__global__ __launch_bounds__(256) void k_fuse2(const float* __restrict__ in,
                                               const bf16* __restrict__ ohX,
                                               const bf16* __restrict__ ow,
                                               const float* __restrict__ ahT,
                                               const float* __restrict__ aw,
                                               const float* __restrict__ gamma,
                                               float* __restrict__ out){
  __shared__ unsigned short tileT[64][138];
  int c = blockIdx.x, half = blockIdx.y, b = blockIdx.z;
  int t = threadIdx.x;
  float g = gamma[0];
  int h0 = half * 64;
  const bf16* ohp = ohX + ((size_t)(b * Cn + c)) * Nn;   // [w][h] rows
  #pragma unroll
  for (int i = 0; i < 4; ++i){
    int s = t + i * 256;            // 0..1023: w = s>>3, seg = s&7 (h-chunk)
    int w = s >> 3, seg = s & 7;
    s16x8 d = *(const s16x8*)(ohp + (size_t)w * Hn + h0 + seg * 8);
    #pragma unroll
    for (int j = 0; j < 8; ++j)
      tileT[seg * 8 + j][w] = (unsigned short)d[j];
  }
  __syncthreads();
  size_t base = ((size_t)(b * Cn + c)) * Nn;
  #pragma unroll
  for (int i = 0; i < 8; ++i){
    int o = t + i * 256;            // 0..2047
    int hl = o >> 5, w4 = (o & 31) * 4;
    int h = h0 + hl;
    size_t idx = base + (size_t)h * Wn + w4;
    size_t aidx = (size_t)b * Nn + (size_t)h * Wn + w4;
    ushort4 owv = *(const ushort4*)((const unsigned short*)ow + idx);
    float4 ah4 = *(const float4*)(ahT + aidx);
    float4 aw4 = *(const float4*)(aw + aidx);
    float4 inv = in ? *(const float4*)(in + idx) : (float4){0.f,0.f,0.f,0.f};
    float r[4];
    #pragma unroll
    for (int j = 0; j < 4; ++j){
      unsigned short uh = tileT[hl][w4 + j];
      unsigned short uo = ((const unsigned short*)&owv)[j];
      float ohv = bf2f(*(bf16*)&uh);
      float owf = bf2f(*(bf16*)&uo);
      float ahv = ((const float*)&ah4)[j];
      float awv = ((const float*)&aw4)[j];
      r[j] = g * (ahv * ohv + awv * owf) + ((const float*)&inv)[j];
    }
    float4 o4 = { r[0], r[1], r[2], r[3] };
    *(float4*)(out + idx) = o4;
  }
}

// s = gamma*(a1h*oh1^T + a1w*ow1) + gamma*(a2h*oh2^T + a2w*ow2) + x*(mch+msp)
// h-QUARTER tiles: 2x [32][138] = 17.7KB LDS -> ~9 blocks/CU residency.
__global__ __launch_bounds__(256) void k_fuse3(const float* __restrict__ x,
                                               const float* __restrict__ mch,
                                               const float* __restrict__ msp,
                                               const bf16* __restrict__ oh1,
                                               const bf16* __restrict__ ow1,
                                               const float* __restrict__ a1h,
                                               const float* __restrict__ a1w,
                                               const bf16* __restrict__ oh2,
                                               const bf16* __restrict__ ow2,
                                               const float* __restrict__ a2h,
                                               const float* __restrict__ a2w,
                                               const float* __restrict__ gamma,
                                               float* __restrict__ out){
  __shared__ unsigned short t1[32][138];
  __shared__ unsigned short t2[32][138];
  int c = blockIdx.x, quarter = blockIdx.y, b = blockIdx.z;
  int t = threadIdx.x;
  float g = gamma[0];
  float mc = mch[b * Cn + c];
  int h0 = quarter * 32;
  const bf16* p1 = oh1 + ((size_t)(b * Cn + c)) * Nn;
  const bf16* p2 = oh2 + ((size_t)(b * Cn + c)) * Nn;
  #pragma unroll
  for (int i = 0; i < 2; ++i){
    int s = t + i * 256;            // 0..511: w = s>>2, seg = s&3 (h-chunk of 8)
    int w = s >> 2, seg = s & 3;
    s16x8 d1 = *(const s16x8*)(p1 + (size_t)w * Hn + h0 + seg * 8);
    s16x8 d2 = *(const s16x8*)(p2 + (size_t)w * Hn + h0 + seg * 8);
    #pragma unroll
    for (int j = 0; j < 8; ++j){
      t1[seg * 8 + j][w] = (unsigned short)d1[j];
      t2[seg * 8 + j][w] = (unsigned short)d2[j];
    }
  }
  __syncthreads();
  size_t base = ((size_t)(b * Cn + c)) * Nn;
  #pragma unroll
  for (int i = 0; i < 4; ++i){
    int o = t + i * 256;            // 0..1023
    int hl = o >> 5, w4 = (o & 31) * 4;
    int h = h0 + hl;
    size_t idx = base + (size_t)h * Wn + w4;
    size_t aidx = (size_t)b * Nn + (size_t)h * Wn + w4;
    ushort4 o1v = *(const ushort4*)((const unsigned short*)ow1 + idx);
    ushort4 o2v = *(const ushort4*)((const unsigned short*)ow2 + idx);
    float4 a1h4 = *(const float4*)(a1h + aidx);
    float4 a1w4 = *(const float4*)(a1w + aidx);
    float4 a2h4 = *(const float4*)(a2h + aidx);
    float4 a2w4 = *(const float4*)(a2w + aidx);
    float4 xv4  = *(const float4*)(x + idx);
    float4 mn4  = *(const float4*)(msp + aidx);
    float r[4];
    #pragma unroll
    for (int j = 0; j < 4; ++j){
      unsigned short u1 = t1[hl][w4 + j];
      unsigned short u2 = t2[hl][w4 + j];
      unsigned short w1 = ((const unsigned short*)&o1v)[j];
      unsigned short w2 = ((const unsigned short*)&o2v)[j];
      float oh1v = bf2f(*(bf16*)&u1), ow1v = bf2f(*(bf16*)&w1);
      float oh2v = bf2f(*(bf16*)&u2), ow2v = bf2f(*(bf16*)&w2);
      float term1 = g * (((const float*)&a1h4)[j] * oh1v + ((const float*)&a1w4)[j] * ow1v);
      float term2 = g * (((const float*)&a2h4)[j] * oh2v + ((const float*)&a2w4)[j] * ow2v);
      float resid = ((const float*)&xv4)[j] * (mc + ((const float*)&mn4)[j]);
      r[j] = term2 + resid + term1;
    }
    float4 o4 = { r[0], r[1], r[2], r[3] };
    *(float4*)(out + idx) = o4;
  }
}

// ============================ host ============================

static void run_att(const bf16* xT_hi, const bf16* xT_lo,
                    const bf16* wqk_hi, const bf16* wqk_lo, int wqk_bstride,
                    const float* bqk,
                    const bf16* wvb, int wv_bstride, const float* bv,
                    const float* nscale,
                    bf16* qhw, bf16* khw, bf16* v, bf16* vT,
                    float* mh, float* sh, float* mw, float* sw,
                    float* ahT, float* aw, bf16* tmp, hipStream_t stream){
  bf16* ohX = tmp;
  bf16* ow  = tmp + (size_t)Bn * Cn * Nn;
  k_qk_mfma<<<dim3(Nn / 128, Bn), 256, 0, stream>>>(xT_hi, xT_lo, wqk_hi, wqk_lo,
                                                    wqk_bstride, bqk, nscale,
                                                    qhw, khw);
  k_v_mfma<<<2048, 256, 0, stream>>>(xT_hi, wvb, wv_bstride, bv, nscale, v);
  k_trans<<<dim3(16, Cn, Bn), 256, 0, stream>>>(v, vT, Cn);
  k_att_h<<<dim3(Wn, Bn), 256, 0, stream>>>(qhw, khw, vT, mh, sh, ohX);
  k_att_w<<<dim3(Hn, Bn), 256, 0, stream>>>(qhw, khw, v, mw, sw, ow);
  k_alpha<<<Bn * Nn / 256, 256, 0, stream>>>(mh, sh, mw, sw, ahT, aw);
}

extern "C" void kernel_launch(void* const* d_in, const int* in_sizes, int n_in,
                              void* d_out, int out_size, void* d_ws, size_t ws_size,
                              hipStream_t stream){
  (void)in_sizes; (void)n_in; (void)out_size; (void)ws_size;
  const float* x         = (const float*)d_in[0];
  const float* w_q_right = (const float*)d_in[1];
  const float* w_v_right = (const float*)d_in[2];
  const float* w_up      = (const float*)d_in[3];
  const float* b_up      = (const float*)d_in[4];
  const float* w_q_left  = (const float*)d_in[5];
  const float* w_v_left  = (const float*)d_in[6];
  const float* wq        = (const float*)d_in[7];
  const float* bq        = (const float*)d_in[8];
  const float* wk        = (const float*)d_in[9];
  const float* bk        = (const float*)d_in[10];
  const float* wv        = (const float*)d_in[11];
  const float* bv        = (const float*)d_in[12];
  const float* gamma     = (const float*)d_in[13];

  const size_t SZ_MAP = (size_t)Bn * Cn * Nn;     // 33.5M elements
  char* p = (char*)d_ws;
  float* buf0   = (float*)p; p += SZ_MAP * 4;     // CA2 tmp (oh2/ow2), CA3 tmp
  float* buf1   = (float*)p; p += SZ_MAP * 4;     // xT_lo(x) first half; then s
  bf16*  vbuf   = (bf16*)p;  p += SZ_MAP * 2;
  bf16*  vT     = (bf16*)p;  p += SZ_MAP * 2;
  bf16*  qhw    = (bf16*)p;  p += (size_t)Bn * CQn * Nn * 2;
  bf16*  khw    = (bf16*)p;  p += (size_t)Bn * CQn * Nn * 2;
  float* ebuf   = (float*)p; p += (size_t)SZ_MAP * 2;         // xT_hi arena (67MB)
  float* logits = (float*)p; p += (size_t)Bn * Nn * 4;
  float* ctxlog = (float*)p; p += (size_t)Bn * Nn * 4;
  float* msp    = (float*)p; p += (size_t)Bn * Nn * 4;
  float* xbar   = (float*)p; p += Bn * Cn * 4;
  float* wgt    = (float*)p; p += Bn * Cn * 4;
  float* u      = (float*)p; p += Bn * Cn * 4;
  float* mch    = (float*)p; p += Bn * Cn * 4;
  float* avg    = (float*)p; p += Bn * CIn * 4;
  float* ctx    = (float*)p; p += Bn * CIn * 4;
  float* stats_sp = (float*)p; p += 64;
  float* stats_ch = (float*)p; p += 64;
  bf16*  wvb    = (bf16*)p;  p += (size_t)Cn * Cn * 2;
  bf16*  wqk_hi = (bf16*)p;  p += (size_t)128 * Cn * 2;
  bf16*  wqk_lo = (bf16*)p;  p += (size_t)128 * Cn * 2;
  float* bqk    = (float*)p; p += 128 * 4;
  float* mh     = (float*)p; p += (size_t)Bn * Nn * 4;
  float* sh     = (float*)p; p += (size_t)Bn * Nn * 4;
  float* mw     = (float*)p; p += (size_t)Bn * Nn * 4;
  float* sw     = (float*)p; p += (size_t)Bn * Nn * 4;
  float* ah1    = (float*)p; p += (size_t)Bn * Nn * 4;
  float* aw1    = (float*)p; p += (size_t)Bn * Nn * 4;
  float* ah2    = (float*)p; p += (size_t)Bn * Nn * 4;
  float* aw2    = (float*)p; p += (size_t)Bn * Nn * 4;
  float* dpart  = (float*)p; p += (size_t)2 * Bn * Nn * 4;    // split-K partials (512KB)
  bf16*  wqk_mch_hi = (bf16*)p; p += (size_t)Bn * 128 * Cn * 2;   // per-b mch-folded QK w
  bf16*  wqk_mch_lo = (bf16*)p; p += (size_t)Bn * 128 * Cn * 2;
  bf16*  wv_mch     = (bf16*)p; p += (size_t)Bn * Cn * Cn * 2;    // per-b mch-folded V w

  bf16*  xT_hi  = (bf16*)ebuf;               // x transposed hi (dead after CA2 v_mfma)
  bf16*  xT_lo  = (bf16*)buf1;               // x transposed lo (dead after CA2 qk_mfma)
  bf16*  xT_hi3 = (bf16*)ebuf;               // CA3 set (after xT_hi dead)
  bf16*  xT_lo3 = (bf16*)d_out;              // d_out free after fuse3 consumed oh1/ow1

  // ---- weight prep (once) ----
  k_cvt_w<<<(Cn * Cn + 255) / 256, 256, 0, stream>>>(wv, wvb, Cn * Cn);
  k_prep_wqk<<<(128 * Cn) / 256, 256, 0, stream>>>(wq, wk, bq, bk, wqk_hi, wqk_lo, bqk);
  // single x transpose (replaces applyT3): hi -> ebuf, lo -> buf1 first half
  k_cvt_T<<<dim3(Nn / 32, Cn / 32, Bn), 256, 0, stream>>>(x, xT_hi, xT_lo);

  // ---- stage 0: gating masks ----
  k_dotc2<<<dim3(Bn * Nn / 256, 2), 256, 0, stream>>>(x, w_q_right, 0, dpart);
  k_dotcadd<<<Bn * Nn / 256, 256, 0, stream>>>(dpart, logits);
  k_rowmean<<<Bn * Cn, 256, 0, stream>>>(x, xbar, 1.f / Nn);
  k_rowdot<<<Bn, 256, 0, stream>>>(w_q_left, xbar, avg);
  k_coldot<<<dim3(Cn / 256, Bn), 256, 0, stream>>>(w_v_left, avg, u);
  k_stats<<<Bn, 1024, 0, stream>>>(logits, stats_sp);
  k_weighted<<<Bn * Cn, 256, 0, stream>>>(x, logits, stats_sp, wgt);
  k_rowdot<<<Bn, 256, 0, stream>>>(w_v_right, wgt, ctx);
  k_mch2<<<dim3(Cn / 256, Bn), 256, 0, stream>>>(w_up, b_up, ctx, mch);
  // per-b mch-folded weights (CA1 path)
  k_prep_wqk_mch<<<(Bn * 128 * Cn) / 256, 256, 0, stream>>>(wq, wk, mch,
                                                            wqk_mch_hi, wqk_mch_lo);
  k_prep_wv_mch<<<(Bn * Cn * Cn) / 256, 256, 0, stream>>>(wv, mch, wv_mch);
  k_dotc2<<<dim3(Bn * Nn / 256, 2), 256, 0, stream>>>(x, u, Cn, dpart);
  k_dotcadd<<<Bn * Nn / 256, 256, 0, stream>>>(dpart, ctxlog);
  k_stats<<<Bn, 1024, 0, stream>>>(ctxlog, stats_ch);
  k_msp<<<Bn * Nn / 256, 256, 0, stream>>>(ctxlog, stats_ch, msp);

  // ---- CA1 (cc = x*mch): mch folded into per-b weights; tmp = d_out ----
  run_att(xT_hi, xT_lo, wqk_mch_hi, wqk_mch_lo, 128 * Cn, bqk,
          wv_mch, Cn * Cn, bv, nullptr,
          qhw, khw, vbuf, vT, mh, sh, mw, sw, ah1, aw1, (bf16*)d_out, stream);
  // ---- CA2 (cs = x*msp): msp applied as per-n epilogue scale; tmp = buf0 ----
  run_att(xT_hi, xT_lo, wqk_hi, wqk_lo, 0, bqk, wvb, 0, bv, msp,
          qhw, khw, vbuf, vT, mh, sh, mw, sw, ah2, aw2, (bf16*)buf0, stream);
  // ---- combined fuse: s = g*att1 + g*att2 + x*(mch+msp) -> buf1 ----
  k_fuse3<<<dim3(Cn, 4, Bn), 256, 0, stream>>>(x, mch, msp,
                                               (const bf16*)d_out,
                                               (const bf16*)d_out + SZ_MAP, ah1, aw1,
                                               (const bf16*)buf0,
                                               (const bf16*)buf0 + SZ_MAP, ah2, aw2,
                                               gamma, buf1);
  // ---- CA3: in = s = buf1; tmp = buf0; out = d_out ----
  k_cvt_T<<<dim3(Nn / 32, Cn / 32, Bn), 256, 0, stream>>>(buf1, xT_hi3, xT_lo3);
  run_att(xT_hi3, xT_lo3, wqk_hi, wqk_lo, 0, bqk, wvb, 0, bv, nullptr,
          qhw, khw, vbuf, vT, mh, sh, mw, sw, ah1, aw1, (bf16*)buf0, stream);
  k_fuse2<<<dim3(Cn, 2, Bn), 256, 0, stream>>>(buf1, (const bf16*)buf0,
                                               (const bf16*)buf0 + SZ_MAP, ah1, aw1,
                                               gamma, (float*)d_out);
}

// Round 21
// 1214.155 us; speedup vs baseline: 1.3985x; 1.0190x over previous
//
#include <hip/hip_runtime.h>
#include <hip/hip_bf16.h>
#include <math.h>

typedef __hip_bfloat16 bf16;
typedef __attribute__((ext_vector_type(8))) short s16x8;
typedef __attribute__((ext_vector_type(4))) float f32x4;

constexpr int Bn  = 4;
constexpr int Cn  = 512;
constexpr int Hn  = 128;
constexpr int Wn  = 128;
constexpr int Nn  = Hn * Wn;   // 16384
constexpr int CQn = 64;
constexpr int CIn = 256;

__device__ __forceinline__ float bf2f(bf16 v){ return __bfloat162float(v); }
__device__ __forceinline__ bf16  f2bf(float v){ return __float2bfloat16(v); }

// async global->LDS, 16B per lane; LDS dest must be wave-uniform base (HW adds lane*16)
__device__ __forceinline__ void gload_lds16(const void* g, void* l){
  __builtin_amdgcn_global_load_lds(
      (const __attribute__((address_space(1))) unsigned int*)g,
      (__attribute__((address_space(3))) unsigned int*)l,
      16, 0, 0);
}

// ============================ stage 0 ============================

// split-K column dot: part[half][b*Nn+n] = sum_{c in half} w[c]*x[b][c][n]
__global__ __launch_bounds__(256) void k_dotc2(const float* __restrict__ x,
                                               const float* __restrict__ w,
                                               int wstride,
                                               float* __restrict__ part){
  int t = blockIdx.x * 256 + threadIdx.x;      // over B*Nn
  int half = blockIdx.y;
  int b = t >> 14;
  const float* wp = w + (size_t)b * wstride + half * 256;
  const float* xp = x + (size_t)b * Cn * Nn + (size_t)(half * 256) * Nn + (t & (Nn - 1));
  float acc = 0.f;
  #pragma unroll 16
  for (int c = 0; c < 256; ++c) acc += wp[c] * xp[(size_t)c * Nn];
  part[(size_t)half * (Bn * Nn) + t] = acc;
}

__global__ __launch_bounds__(256) void k_dotcadd(const float* __restrict__ part,
                                                 float* __restrict__ out){
  int t = blockIdx.x * 256 + threadIdx.x;
  out[t] = part[t] + part[(size_t)Bn * Nn + t];
}

__global__ __launch_bounds__(256) void k_rowmean(const float* __restrict__ x,
                                                 float* __restrict__ out,
                                                 float scale){
  int bc = blockIdx.x;
  const float* xp = x + (size_t)bc * Nn;
  float acc = 0.f;
  for (int n = threadIdx.x; n < Nn; n += 256) acc += xp[n];
  for (int o = 32; o > 0; o >>= 1) acc += __shfl_down(acc, o);
  __shared__ float red[4];
  if ((threadIdx.x & 63) == 0) red[threadIdx.x >> 6] = acc;
  __syncthreads();
  if (threadIdx.x == 0) out[bc] = (red[0] + red[1] + red[2] + red[3]) * scale;
}

__global__ __launch_bounds__(256) void k_rowdot(const float* __restrict__ W,
                                                const float* __restrict__ vec,
                                                float* __restrict__ out){
  __shared__ float vs[Cn];
  int b = blockIdx.x, t = threadIdx.x;
  for (int j = t; j < Cn; j += 256) vs[j] = vec[b * Cn + j];
  __syncthreads();
  const float4* wp = (const float4*)(W + (size_t)t * Cn);
  float a = 0.f;
  #pragma unroll 4
  for (int j = 0; j < Cn / 4; ++j){
    float4 w4 = wp[j];
    a += w4.x * vs[4*j] + w4.y * vs[4*j+1] + w4.z * vs[4*j+2] + w4.w * vs[4*j+3];
  }
  out[b * CIn + t] = a;
}

__global__ __launch_bounds__(256) void k_coldot(const float* __restrict__ W,
                                                const float* __restrict__ vec,
                                                float* __restrict__ out){
  __shared__ float vs[CIn];
  int b = blockIdx.y, t = threadIdx.x;
  int c = blockIdx.x * 256 + t;
  if (t < CIn) vs[t] = vec[b * CIn + t];
  __syncthreads();
  float a = 0.f;
  #pragma unroll 8
  for (int j = 0; j < CIn; ++j) a += W[(size_t)j * Cn + c] * vs[j];
  out[b * Cn + c] = a;
}

__global__ __launch_bounds__(256) void k_mch2(const float* __restrict__ w_up,
                                              const float* __restrict__ b_up,
                                              const float* __restrict__ ctx,
                                              float* __restrict__ mch){
  __shared__ float cs[CIn];
  int b = blockIdx.y, t = threadIdx.x;
  int o = blockIdx.x * 256 + t;
  if (t < CIn) cs[t] = ctx[b * CIn + t];
  __syncthreads();
  const float4* wp = (const float4*)(w_up + (size_t)o * CIn);
  float a = b_up[o];
  #pragma unroll 4
  for (int j = 0; j < CIn / 4; ++j){
    float4 w4 = wp[j];
    a += w4.x * cs[4*j] + w4.y * cs[4*j+1] + w4.z * cs[4*j+2] + w4.w * cs[4*j+3];
  }
  mch[b * Cn + o] = 1.f / (1.f + expf(-a));
}

__global__ __launch_bounds__(1024) void k_stats(const float* __restrict__ vv,
                                                float* __restrict__ stats){
  int b = blockIdx.x;
  const float* pp = vv + (size_t)b * Nn;
  int t = threadIdx.x;
  float m = -3.4e38f;
  for (int n = t; n < Nn; n += 1024) m = fmaxf(m, pp[n]);
  for (int o = 32; o > 0; o >>= 1) m = fmaxf(m, __shfl_down(m, o));
  __shared__ float red[16];
  int wid = t >> 6, lid = t & 63;
  if (lid == 0) red[wid] = m;
  __syncthreads();
  if (t == 0){
    float q = red[0];
    for (int i = 1; i < 16; i++) q = fmaxf(q, red[i]);
    red[0] = q;
  }
  __syncthreads();
  m = red[0];
  __syncthreads();
  float s = 0.f;
  for (int n = t; n < Nn; n += 1024) s += expf(pp[n] - m);
  for (int o = 32; o > 0; o >>= 1) s += __shfl_down(s, o);
  if (lid == 0) red[wid] = s;
  __syncthreads();
  if (t == 0){
    float q = 0.f;
    for (int i = 0; i < 16; i++) q += red[i];
    stats[b * 2]     = m;
    stats[b * 2 + 1] = q;
  }
}

__global__ __launch_bounds__(256) void k_weighted(const float* __restrict__ x,
                                                  const float* __restrict__ logits,
                                                  const float* __restrict__ stats,
                                                  float* __restrict__ out){
  int bc = blockIdx.x;
  int b = bc >> 9;
  const float* xp = x + (size_t)bc * Nn;
  const float* lp = logits + (size_t)b * Nn;
  float m = stats[b * 2], den = stats[b * 2 + 1];
  float acc = 0.f;
  for (int n = threadIdx.x; n < Nn; n += 256) acc += xp[n] * expf(lp[n] - m);
  for (int o = 32; o > 0; o >>= 1) acc += __shfl_down(acc, o);
  __shared__ float red[4];
  if ((threadIdx.x & 63) == 0) red[threadIdx.x >> 6] = acc;
  __syncthreads();
  if (threadIdx.x == 0) out[bc] = (red[0] + red[1] + red[2] + red[3]) / den;
}

__global__ __launch_bounds__(256) void k_msp(const float* __restrict__ lg,
                                             const float* __restrict__ stats,
                                             float* __restrict__ msp){
  int t = blockIdx.x * 256 + threadIdx.x;
  int b = t >> 14;
  float v = expf(lg[t] - stats[b * 2]) / stats[b * 2 + 1];
  msp[t] = 1.f / (1.f + expf(-v));
}

// ============================ conversions / weight prep ============================

__global__ __launch_bounds__(256) void k_cvt_w(const float* __restrict__ in,
                                               bf16* __restrict__ out, int n){
  int t = blockIdx.x * 256 + threadIdx.x;
  if (t < n) out[t] = f2bf(in[t]);
}

__global__ __launch_bounds__(256) void k_prep_wqk(const float* __restrict__ wq,
                                                  const float* __restrict__ wk,
                                                  const float* __restrict__ bq,
                                                  const float* __restrict__ bk,
                                                  bf16* __restrict__ wqk_hi,
                                                  bf16* __restrict__ wqk_lo,
                                                  float* __restrict__ bqk){
  int t = blockIdx.x * 256 + threadIdx.x;   // over 128*512
  int o = t >> 9, c = t & 511;
  float v = (o < 64) ? wq[(size_t)o * Cn + c] : wk[(size_t)(o - 64) * Cn + c];
  bf16 h = f2bf(v);
  wqk_hi[t] = h;
  wqk_lo[t] = f2bf(v - bf2f(h));
  if (t < 128) bqk[t] = (t < 64) ? bq[t] : bk[t - 64];
}

// per-b mch-folded QK weights: w[b][o][c] = wqk[o][c] * mch[b][c] (hi/lo)
__global__ __launch_bounds__(256) void k_prep_wqk_mch(const float* __restrict__ wq,
                                                      const float* __restrict__ wk,
                                                      const float* __restrict__ mch,
                                                      bf16* __restrict__ hi,
                                                      bf16* __restrict__ lo){
  int t = blockIdx.x * 256 + threadIdx.x;   // over Bn*128*Cn = 262144
  int b = t >> 16;
  int oc = t & 65535;
  int o = oc >> 9, c = oc & 511;
  float w = (o < 64) ? wq[(size_t)o * Cn + c] : wk[(size_t)(o - 64) * Cn + c];
  float v = w * mch[b * Cn + c];
  bf16 h = f2bf(v);
  hi[t] = h;
  lo[t] = f2bf(v - bf2f(h));
}

// per-b mch-folded V weights: w[b][o][c] = bf16(wv[o][c] * mch[b][c])
__global__ __launch_bounds__(256) void k_prep_wv_mch(const float* __restrict__ wv,
                                                     const float* __restrict__ mch,
                                                     bf16* __restrict__ out){
  int t = blockIdx.x * 256 + threadIdx.x;   // over Bn*Cn*Cn = 1048576
  int b = t >> 18;
  int oc = t & 262143;
  int c = oc & 511;
  out[t] = f2bf(wv[oc] * mch[b * Cn + c]);
}

__global__ __launch_bounds__(256) void k_cvt_T(const float* __restrict__ in,
                                               bf16* __restrict__ out_hi,
                                               bf16* __restrict__ out_lo){
  __shared__ bf16 th_[32][33];
  __shared__ bf16 tl_[32][33];
  int nt = blockIdx.x, ct = blockIdx.y, b = blockIdx.z;
  int n0 = nt * 32, c0 = ct * 32;
  int t = threadIdx.x;
  #pragma unroll
  for (int kk = 0; kk < 4; ++kk){
    int idx = t + kk * 256;
    int cl = idx >> 5, nl = idx & 31;
    float v = in[((size_t)(b * Cn + c0 + cl)) * Nn + n0 + nl];
    bf16 h = f2bf(v);
    th_[cl][nl] = h;
    tl_[cl][nl] = f2bf(v - bf2f(h));
  }
  __syncthreads();
  #pragma unroll
  for (int kk = 0; kk < 4; ++kk){
    int idx = t + kk * 256;
    int nl = idx >> 5, cl = idx & 31;
    size_t o = ((size_t)(b * Nn + n0 + nl)) * Cn + c0 + cl;
    out_hi[o] = th_[cl][nl];
    out_lo[o] = tl_[cl][nl];
  }
}

// ============================ MFMA GEMMs ============================

// V = Wv @ X (+ optional per-n scale). 128x128 tile, BK=64. XCD-chunked 1D grid of 2048.
// wstride: per-b weight stride (0 = shared weights).
__global__ __launch_bounds__(256) void k_v_mfma(const bf16* __restrict__ xT,
                                                const bf16* __restrict__ wvb,
                                                int wstride,
                                                const float* __restrict__ bv,
                                                const float* __restrict__ nscale,
                                                bf16* __restrict__ v){
  __shared__ short As[128 * 64];
  __shared__ short Bs[128 * 64];
  __shared__ float bvs[128];
  int lin = blockIdx.x;
  int swz = (lin & 7) * 256 + (lin >> 3);
  int cb = (swz & 3) * 128;
  int nb = ((swz >> 2) & 127) * 128;
  int b  = swz >> 9;
  int t = threadIdx.x, lane = t & 63, wid = t >> 6;
  int wm = wid >> 1, wn = wid & 1;
  int l15 = lane & 15, l4 = lane >> 4;
  if (t < 128) bvs[t] = bv[cb + t];
  f32x4 acc[4][4];
  #pragma unroll
  for (int i = 0; i < 4; i++)
    #pragma unroll
    for (int j = 0; j < 4; j++) acc[i][j] = (f32x4){0.f, 0.f, 0.f, 0.f};

  const bf16* wp = wvb + (size_t)b * wstride + (size_t)cb * Cn;
  const bf16* xp = xT + ((size_t)b * Nn + nb) * Cn;
  int r8 = lane >> 3;
  int kc = (lane & 7) * 8;
  for (int kt = 0; kt < 8; ++kt){
    int k0 = kt * 64;
    #pragma unroll
    for (int j = 0; j < 4; ++j){
      int inst = wid * 4 + j;
      int row = inst * 8 + r8;
      gload_lds16(wp + (size_t)row * Cn + k0 + kc, (char*)As + inst * 1024);
      gload_lds16(xp + (size_t)row * Cn + k0 + kc, (char*)Bs + inst * 1024);
    }
    __syncthreads();
    #pragma unroll
    for (int kk = 0; kk < 64; kk += 32){
      s16x8 a[4], bb[4];
      #pragma unroll
      for (int mi = 0; mi < 4; mi++)
        a[mi] = *(const s16x8*)&As[(wm * 64 + mi * 16 + l15) * 64 + kk + l4 * 8];
      #pragma unroll
      for (int ni = 0; ni < 4; ni++)
        bb[ni] = *(const s16x8*)&Bs[(wn * 64 + ni * 16 + l15) * 64 + kk + l4 * 8];
      #pragma unroll
      for (int mi = 0; mi < 4; mi++)
        #pragma unroll
        for (int ni = 0; ni < 4; ni++)
          acc[mi][ni] = __builtin_amdgcn_mfma_f32_16x16x32_bf16(a[mi], bb[ni], acc[mi][ni], 0, 0, 0);
    }
    __syncthreads();
  }
  float sc[4];
  #pragma unroll
  for (int ni = 0; ni < 4; ni++)
    sc[ni] = nscale ? nscale[(size_t)b * Nn + nb + wn * 64 + ni * 16 + l15] : 1.f;
  #pragma unroll
  for (int mi = 0; mi < 4; mi++){
    #pragma unroll
    for (int r = 0; r < 4; r++){
      int cl = wm * 64 + mi * 16 + l4 * 4 + r;
      int c  = cb + cl;
      float bias = bvs[cl];
      #pragma unroll
      for (int ni = 0; ni < 4; ni++){
        int n = nb + wn * 64 + ni * 16 + l15;
        v[((size_t)(b * Cn + c)) * Nn + n] = f2bf(acc[mi][ni][r] * sc[ni] + bias);
      }
    }
  }
}

// Q,K = Wqk @ X (+ optional per-n scale), split-precision bf16 (3 MFMA terms).
// Writes qhw/khw ([b][w][h][c]) DIRECTLY via LDS transpose epilogue.
// wstride: per-b weight stride (0 = shared weights).
__global__ __launch_bounds__(256) void k_qk_mfma(const bf16* __restrict__ xT_hi,
                                                 const bf16* __restrict__ xT_lo,
                                                 const bf16* __restrict__ wqk_hi,
                                                 const bf16* __restrict__ wqk_lo,
                                                 int wstride,
                                                 const float* __restrict__ bqk,
                                                 const float* __restrict__ nscale,
                                                 bf16* __restrict__ qhw,
                                                 bf16* __restrict__ khw){
  __shared__ char smem[65536];
  short* Ah = (short*)smem;
  short* Al = Ah + 8192;
  short* Bh = Al + 8192;
  short* Bl = Bh + 8192;
  char*  Os = smem;                 // reused after final K-loop barrier (32KB)
  __shared__ float bs[128];
  int h = blockIdx.x, b = blockIdx.y;      // block covers n = h*128 + w, w=0..127
  int nb = h * 128;
  int t = threadIdx.x, lane = t & 63, wid = t >> 6;
  int wm = wid >> 1, wn = wid & 1;
  int l15 = lane & 15, l4 = lane >> 4;
  if (t < 128) bs[t] = bqk[t];
  f32x4 acc[4][4];
  #pragma unroll
  for (int i = 0; i < 4; i++)
    #pragma unroll
    for (int j = 0; j < 4; j++) acc[i][j] = (f32x4){0.f, 0.f, 0.f, 0.f};

  const bf16* wh = wqk_hi + (size_t)b * wstride;
  const bf16* wl = wqk_lo + (size_t)b * wstride;
  const bf16* xh = xT_hi + ((size_t)b * Nn + nb) * Cn;
  const bf16* xl = xT_lo + ((size_t)b * Nn + nb) * Cn;
  int r8 = lane >> 3;
  int kc = (lane & 7) * 8;
  for (int kt = 0; kt < 8; ++kt){
    int k0 = kt * 64;
    #pragma unroll
    for (int j = 0; j < 4; ++j){
      int inst = wid * 4 + j;
      int row = inst * 8 + r8;
      size_t off = (size_t)row * Cn + k0 + kc;
      gload_lds16(wh + off, (char*)Ah + inst * 1024);
      gload_lds16(wl + off, (char*)Al + inst * 1024);
      gload_lds16(xh + off, (char*)Bh + inst * 1024);
      gload_lds16(xl + off, (char*)Bl + inst * 1024);
    }
    __syncthreads();
    #pragma unroll
    for (int kk = 0; kk < 64; kk += 32){
      s16x8 ah[4], al[4], bh[4], bl[4];
      #pragma unroll
      for (int mi = 0; mi < 4; mi++){
        int idx = (wm * 64 + mi * 16 + l15) * 64 + kk + l4 * 8;
        ah[mi] = *(const s16x8*)&Ah[idx];
        al[mi] = *(const s16x8*)&Al[idx];
      }
      #pragma unroll
      for (int ni = 0; ni < 4; ni++){
        int idx = (wn * 64 + ni * 16 + l15) * 64 + kk + l4 * 8;
        bh[ni] = *(const s16x8*)&Bh[idx];
        bl[ni] = *(const s16x8*)&Bl[idx];
      }
      #pragma unroll
      for (int mi = 0; mi < 4; mi++)
        #pragma unroll
        for (int ni = 0; ni < 4; ni++){
          acc[mi][ni] = __builtin_amdgcn_mfma_f32_16x16x32_bf16(ah[mi], bh[ni], acc[mi][ni], 0, 0, 0);
          acc[mi][ni] = __builtin_amdgcn_mfma_f32_16x16x32_bf16(ah[mi], bl[ni], acc[mi][ni], 0, 0, 0);
          acc[mi][ni] = __builtin_amdgcn_mfma_f32_16x16x32_bf16(al[mi], bh[ni], acc[mi][ni], 0, 0, 0);
        }
    }
    __syncthreads();
  }
  float sc[4];
  #pragma unroll
  for (int ni = 0; ni < 4; ni++)
    sc[ni] = nscale ? nscale[(size_t)b * Nn + nb + wn * 64 + ni * 16 + l15] : 1.f;
  // epilogue: Os[n][o] bf16 (256B rows, XOR-swizzled), then 128B row stores
  #pragma unroll
  for (int mi = 0; mi < 4; mi++){
    #pragma unroll
    for (int r = 0; r < 4; r++){
      int o = wm * 64 + mi * 16 + l4 * 4 + r;
      float bias = bs[o];
      #pragma unroll
      for (int ni = 0; ni < 4; ni++){
        int n = wn * 64 + ni * 16 + l15;
        bf16 bv = f2bf(acc[mi][ni][r] * sc[ni] + bias);
        int byte = (n * 256 + o * 2) ^ ((n & 7) << 4);
        *(unsigned short*)(Os + byte) = *(unsigned short*)&bv;
      }
    }
  }
  __syncthreads();
  #pragma unroll
  for (int i = 0; i < 8; ++i){
    int s = t + i * 256;            // 0..2047: row = s>>3 (w + 128*qk), seg = s&7
    int row = s >> 3, seg = s & 7;
    int w = row & 127, qk = row >> 7;
    int o0 = qk * 64 + seg * 8;
    int byte = (w * 256 + o0 * 2) ^ ((w & 7) << 4);
    s16x8 d = *(const s16x8*)(Os + byte);
    bf16* dst = (qk == 0 ? qhw : khw) + (((size_t)b * Wn + w) * Hn + h) * CQn + seg * 8;
    *(s16x8*)dst = d;
  }
}

// ============================ fused attention ============================

// per (b,w): MFMA e_h from qhw/khw ([b][w][h][c]), diag, stats, p->LDS, PV MFMA.
// ohX layout [b][c][w][h] (unnormalized; alpha in fuse).
__global__ __launch_bounds__(256) void k_att_h(const bf16* __restrict__ qhw,
                                               const bf16* __restrict__ khw,
                                               const bf16* __restrict__ vT,
                                               float* __restrict__ mh,
                                               float* __restrict__ sh,
                                               bf16* __restrict__ ohX){
  __shared__ char smem[65536];
  char* attb = smem;                 // p tile 32KB
  char* vbb  = smem + 32768;         // V tile 32KB (e-phase: first 2KB = stats)
  float* redm = (float*)(smem + 32768);        // [2][128]
  float* reds = redm + 256;                    // [2][128]
  int w = blockIdx.x, b = blockIdx.y;
  int t = threadIdx.x, lane = t & 63, wid = t >> 6;
  int wm = wid >> 1, wn = wid & 1;
  int l15 = lane & 15, l4 = lane >> 4;

  const bf16* qp = qhw + ((size_t)(b * Wn + w)) * (Hn * CQn);
  const bf16* kp = khw + ((size_t)(b * Wn + w)) * (Hn * CQn);
  f32x4 acc[4][4];
  #pragma unroll
  for (int i = 0; i < 4; i++)
    #pragma unroll
    for (int j = 0; j < 4; j++) acc[i][j] = (f32x4){0.f, 0.f, 0.f, 0.f};
  #pragma unroll
  for (int kk = 0; kk < 64; kk += 32){
    s16x8 a[4], bb[4];
    #pragma unroll
    for (int mi = 0; mi < 4; mi++)
      a[mi] = *(const s16x8*)(qp + (size_t)(wm * 64 + mi * 16 + l15) * CQn + kk + l4 * 8);
    #pragma unroll
    for (int ni = 0; ni < 4; ni++)
      bb[ni] = *(const s16x8*)(kp + (size_t)(wn * 64 + ni * 16 + l15) * CQn + kk + l4 * 8);
    #pragma unroll
    for (int mi = 0; mi < 4; mi++)
      #pragma unroll
      for (int ni = 0; ni < 4; ni++)
        acc[mi][ni] = __builtin_amdgcn_mfma_f32_16x16x32_bf16(a[mi], bb[ni], acc[mi][ni], 0, 0, 0);
  }
  // diag mask: h==g
  if (wm == wn){
    #pragma unroll
    for (int mi = 0; mi < 4; mi++)
      #pragma unroll
      for (int r = 0; r < 4; r++)
        if (l15 == l4 * 4 + r) acc[mi][mi][r] = -1e30f;
  }
  float rm[4][4];
  #pragma unroll
  for (int mi = 0; mi < 4; mi++)
    #pragma unroll
    for (int r = 0; r < 4; r++){
      float m = fmaxf(fmaxf(acc[mi][0][r], acc[mi][1][r]),
                      fmaxf(acc[mi][2][r], acc[mi][3][r]));
      m = fmaxf(m, __shfl_xor(m, 1));
      m = fmaxf(m, __shfl_xor(m, 2));
      m = fmaxf(m, __shfl_xor(m, 4));
      m = fmaxf(m, __shfl_xor(m, 8));
      rm[mi][r] = m;
    }
  if (l15 == 0){
    #pragma unroll
    for (int mi = 0; mi < 4; mi++)
      #pragma unroll
      for (int r = 0; r < 4; r++)
        redm[wn * 128 + wm * 64 + mi * 16 + l4 * 4 + r] = rm[mi][r];
  }
  __syncthreads();
  float rs[4][4];
  #pragma unroll
  for (int mi = 0; mi < 4; mi++)
    #pragma unroll
    for (int r = 0; r < 4; r++){
      int h = wm * 64 + mi * 16 + l4 * 4 + r;
      float m = fmaxf(redm[h], redm[128 + h]);
      rm[mi][r] = m;
      float s = 0.f;
      #pragma unroll
      for (int ni = 0; ni < 4; ni++){
        acc[mi][ni][r] = expf(acc[mi][ni][r] - m);
        s += acc[mi][ni][r];
      }
      s += __shfl_xor(s, 1);
      s += __shfl_xor(s, 2);
      s += __shfl_xor(s, 4);
      s += __shfl_xor(s, 8);
      rs[mi][r] = s;
    }
  if (l15 == 0){
    #pragma unroll
    for (int mi = 0; mi < 4; mi++)
      #pragma unroll
      for (int r = 0; r < 4; r++)
        reds[wn * 128 + wm * 64 + mi * 16 + l4 * 4 + r] = rs[mi][r];
  }
  __syncthreads();
  #pragma unroll
  for (int mi = 0; mi < 4; mi++)
    #pragma unroll
    for (int r = 0; r < 4; r++){
      int h = wm * 64 + mi * 16 + l4 * 4 + r;
      if (wn == 0 && l15 == 0){
        mh[(size_t)(b * Wn + w) * Hn + h] = rm[mi][r];
        sh[(size_t)(b * Wn + w) * Hn + h] = reds[h] + reds[128 + h];
      }
      #pragma unroll
      for (int ni = 0; ni < 4; ni++){
        int g = wn * 64 + ni * 16 + l15;
        bf16 bv = f2bf(acc[mi][ni][r]);
        int byte = (h * 256 + g * 2) ^ ((h & 7) << 4);
        *(unsigned short*)(attb + byte) = *(unsigned short*)&bv;
      }
    }
  __syncthreads();
  // PV MFMA over 4 c-tiles
  for (int cb = 0; cb < Cn; cb += 128){
    const bf16* vp = vT + ((size_t)(b * Wn + w) * Cn + cb) * Hn;
    for (int s = t; s < 2048; s += 256){
      int row = s >> 4, seg = s & 15;
      s16x8 d = *(const s16x8*)(vp + (size_t)row * Hn + seg * 8);
      int byte = (row * 256 + seg * 16) ^ ((row & 7) << 4);
      *(s16x8*)(vbb + byte) = d;
    }
    __syncthreads();
    f32x4 acc2[4][4];
    #pragma unroll
    for (int i = 0; i < 4; i++)
      #pragma unroll
      for (int j = 0; j < 4; j++) acc2[i][j] = (f32x4){0.f, 0.f, 0.f, 0.f};
    #pragma unroll
    for (int kk = 0; kk < 128; kk += 32){
      s16x8 a[4], bb[4];
      #pragma unroll
      for (int mi = 0; mi < 4; mi++){
        int row = wm * 64 + mi * 16 + l15;
        int byte = (row * 256 + (kk + l4 * 8) * 2) ^ ((row & 7) << 4);
        a[mi] = *(const s16x8*)(vbb + byte);
      }
      #pragma unroll
      for (int ni = 0; ni < 4; ni++){
        int row = wn * 64 + ni * 16 + l15;
        int byte = (row * 256 + (kk + l4 * 8) * 2) ^ ((row & 7) << 4);
        bb[ni] = *(const s16x8*)(attb + byte);
      }
      #pragma unroll
      for (int mi = 0; mi < 4; mi++)
        #pragma unroll
        for (int ni = 0; ni < 4; ni++)
          acc2[mi][ni] = __builtin_amdgcn_mfma_f32_16x16x32_bf16(a[mi], bb[ni], acc2[mi][ni], 0, 0, 0);
    }
    bf16* op = ohX + ((size_t)(b * Cn + cb)) * Nn + (size_t)w * Hn;
    #pragma unroll
    for (int mi = 0; mi < 4; mi++)
      #pragma unroll
      for (int r = 0; r < 4; r++){
        int cl = wm * 64 + mi * 16 + l4 * 4 + r;
        #pragma unroll
        for (int ni = 0; ni < 4; ni++){
          int h = wn * 64 + ni * 16 + l15;
          op[(size_t)cl * Nn + h] = f2bf(acc2[mi][ni][r]);
        }
      }
    __syncthreads();
  }
}

// per (b,h): MFMA e_w from qhw/khw (strided rows), stats, p->LDS, PV MFMA.
__global__ __launch_bounds__(256) void k_att_w(const bf16* __restrict__ qhw,
                                               const bf16* __restrict__ khw,
                                               const bf16* __restrict__ v,
                                               float* __restrict__ mw,
                                               float* __restrict__ sw,
                                               bf16* __restrict__ ow){
  __shared__ char smem[65536];
  char* attb = smem;
  char* vbb  = smem + 32768;
  float* redm = (float*)(smem + 32768);
  float* reds = redm + 256;
  int h = blockIdx.x, b = blockIdx.y;
  int t = threadIdx.x, lane = t & 63, wid = t >> 6;
  int wm = wid >> 1, wn = wid & 1;
  int l15 = lane & 15, l4 = lane >> 4;

  const bf16* qp = qhw + (size_t)b * Wn * Hn * CQn + (size_t)h * CQn;
  const bf16* kp = khw + (size_t)b * Wn * Hn * CQn + (size_t)h * CQn;
  f32x4 acc[4][4];
  #pragma unroll
  for (int i = 0; i < 4; i++)
    #pragma unroll
    for (int j = 0; j < 4; j++) acc[i][j] = (f32x4){0.f, 0.f, 0.f, 0.f};
  #pragma unroll
  for (int kk = 0; kk < 64; kk += 32){
    s16x8 a[4], bb[4];
    #pragma unroll
    for (int mi = 0; mi < 4; mi++)
      a[mi] = *(const s16x8*)(qp + (size_t)(wm * 64 + mi * 16 + l15) * (Hn * CQn) + kk + l4 * 8);
    #pragma unroll
    for (int ni = 0; ni < 4; ni++)
      bb[ni] = *(const s16x8*)(kp + (size_t)(wn * 64 + ni * 16 + l15) * (Hn * CQn) + kk + l4 * 8);
    #pragma unroll
    for (int mi = 0; mi < 4; mi++)
      #pragma unroll
      for (int ni = 0; ni < 4; ni++)
        acc[mi][ni] = __builtin_amdgcn_mfma_f32_16x16x32_bf16(a[mi], bb[ni], acc[mi][ni], 0, 0, 0);
  }
  float rm[4][4];
  #pragma unroll
  for (int mi = 0; mi < 4; mi++)
    #pragma unroll
    for (int r = 0; r < 4; r++){
      float m = fmaxf(fmaxf(acc[mi][0][r], acc[mi][1][r]),
                      fmaxf(acc[mi][2][r], acc[mi][3][r]));
      m = fmaxf(m, __shfl_xor(m, 1));
      m = fmaxf(m, __shfl_xor(m, 2));
      m = fmaxf(m, __shfl_xor(m, 4));
      m = fmaxf(m, __shfl_xor(m, 8));
      rm[mi][r] = m;
    }
  if (l15 == 0){
    #pragma unroll
    for (int mi = 0; mi < 4; mi++)
      #pragma unroll
      for (int r = 0; r < 4; r++)
        redm[wn * 128 + wm * 64 + mi * 16 + l4 * 4 + r] = rm[mi][r];
  }
  __syncthreads();
  float rs[4][4];
  #pragma unroll
  for (int mi = 0; mi < 4; mi++)
    #pragma unroll
    for (int r = 0; r < 4; r++){
      int wr = wm * 64 + mi * 16 + l4 * 4 + r;
      float m = fmaxf(redm[wr], redm[128 + wr]);
      rm[mi][r] = m;
      float s = 0.f;
      #pragma unroll
      for (int ni = 0; ni < 4; ni++){
        acc[mi][ni][r] = expf(acc[mi][ni][r] - m);
        s += acc[mi][ni][r];
      }
      s += __shfl_xor(s, 1);
      s += __shfl_xor(s, 2);
      s += __shfl_xor(s, 4);
      s += __shfl_xor(s, 8);
      rs[mi][r] = s;
    }
  if (l15 == 0){
    #pragma unroll
    for (int mi = 0; mi < 4; mi++)
      #pragma unroll
      for (int r = 0; r < 4; r++)
        reds[wn * 128 + wm * 64 + mi * 16 + l4 * 4 + r] = rs[mi][r];
  }
  __syncthreads();
  #pragma unroll
  for (int mi = 0; mi < 4; mi++)
    #pragma unroll
    for (int r = 0; r < 4; r++){
      int wr = wm * 64 + mi * 16 + l4 * 4 + r;
      if (wn == 0 && l15 == 0){
        mw[(size_t)(b * Hn + h) * Wn + wr] = rm[mi][r];
        sw[(size_t)(b * Hn + h) * Wn + wr] = reds[wr] + reds[128 + wr];
      }
      #pragma unroll
      for (int ni = 0; ni < 4; ni++){
        int g = wn * 64 + ni * 16 + l15;
        bf16 bv = f2bf(acc[mi][ni][r]);
        int byte = (wr * 256 + g * 2) ^ ((wr & 7) << 4);
        *(unsigned short*)(attb + byte) = *(unsigned short*)&bv;
      }
    }
  __syncthreads();
  for (int cb = 0; cb < Cn; cb += 128){
    const bf16* vp = v + (size_t)(b * Cn + cb) * Nn + (size_t)h * Wn;
    for (int s = t; s < 2048; s += 256){
      int row = s >> 4, seg = s & 15;
      s16x8 d = *(const s16x8*)(vp + (size_t)row * Nn + seg * 8);
      int byte = (row * 256 + seg * 16) ^ ((row & 7) << 4);
      *(s16x8*)(vbb + byte) = d;
    }
    __syncthreads();
    f32x4 acc2[4][4];
    #pragma unroll
    for (int i = 0; i < 4; i++)
      #pragma unroll
      for (int j = 0; j < 4; j++) acc2[i][j] = (f32x4){0.f, 0.f, 0.f, 0.f};
    #pragma unroll
    for (int kk = 0; kk < 128; kk += 32){
      s16x8 a[4], bb[4];
      #pragma unroll
      for (int mi = 0; mi < 4; mi++){
        int row = wm * 64 + mi * 16 + l15;
        int byte = (row * 256 + (kk + l4 * 8) * 2) ^ ((row & 7) << 4);
        a[mi] = *(const s16x8*)(vbb + byte);
      }
      #pragma unroll
      for (int ni = 0; ni < 4; ni++){
        int row = wn * 64 + ni * 16 + l15;
        int byte = (row * 256 + (kk + l4 * 8) * 2) ^ ((row & 7) << 4);
        bb[ni] = *(const s16x8*)(attb + byte);
      }
      #pragma unroll
      for (int mi = 0; mi < 4; mi++)
        #pragma unroll
        for (int ni = 0; ni < 4; ni++)
          acc2[mi][ni] = __builtin_amdgcn_mfma_f32_16x16x32_bf16(a[mi], bb[ni], acc2[mi][ni], 0, 0, 0);
    }
    bf16* op = ow + (size_t)(b * Cn + cb) * Nn + (size_t)h * Wn;
    #pragma unroll
    for (int mi = 0; mi < 4; mi++)
      #pragma unroll
      for (int r = 0; r < 4; r++){
        int cl = wm * 64 + mi * 16 + l4 * 4 + r;
        #pragma unroll
        for (int ni = 0; ni < 4; ni++){
          int wr = wn * 64 + ni * 16 + l15;
          op[(size_t)cl * Nn + wr] = f2bf(acc2[mi][ni][r]);
        }
      }
    __syncthreads();
  }
}

// merge stats -> alphas, both in [b,h,w] layout for fuse
__global__ __launch_bounds__(256) void k_alpha(const float* __restrict__ mh,
                                               const float* __restrict__ sh,
                                               const float* __restrict__ mw,
                                               const float* __restrict__ sw,
                                               float* __restrict__ ahT,
                                               float* __restrict__ aw){
  int t = blockIdx.x * 256 + threadIdx.x;   // (b*Hn+h)*Wn + w
  int b = t >> 14;
  int hw = t & (Nn - 1);
  int h = hw >> 7, w = hw & 127;
  size_t ih = (size_t)(b * Wn + w) * Hn + h;
  size_t iw = t;
  float mhv = mh[ih], mwv = mw[iw];
  float M = fmaxf(mhv, mwv);
  float eh_ = expf(mhv - M), ew_ = expf(mwv - M);
  float inv = 1.f / (sh[ih] * eh_ + sw[iw] * ew_);
  ahT[t] = eh_ * inv;
  aw[t]  = ew_ * inv;
}

// ============================ remaining CA kernels ============================

// v [b][c][h][w] -> vT [b][w][c][h]; 64x64 tiles, vectorized 16B both sides.
__global__ __launch_bounds__(256) void k_trans(const bf16* __restrict__ in,
                                               bf16* __restrict__ out,
                                               int CH){
  __shared__ unsigned short tile[64][72];   // [w][h], pad 8 -> row 144B (16B-mult)
  int tl = blockIdx.x, c = blockIdx.y, b = blockIdx.z;
  int th = tl >> 1, tw = tl & 1;
  int h0 = th * 64, w0 = tw * 64;
  int t = threadIdx.x;
  const bf16* ip = in + ((size_t)(b * CH + c)) * Nn;
  {
    int hl = t >> 2, wq = (t & 3) * 16;
    const bf16* src = ip + (size_t)(h0 + hl) * Wn + w0 + wq;
    s16x8 d0 = *(const s16x8*)(src);
    s16x8 d1 = *(const s16x8*)(src + 8);
    #pragma unroll
    for (int j = 0; j < 8; ++j){
      tile[wq + j][hl]     = (unsigned short)d0[j];
      tile[wq + 8 + j][hl] = (unsigned short)d1[j];
    }
  }
  __syncthreads();
  {
    int wl = t >> 2, hq = (t & 3) * 16;
    s16x8 d0 = *(const s16x8*)&tile[wl][hq];
    s16x8 d1 = *(const s16x8*)&tile[wl][hq + 8];
    bf16* dst = out + ((size_t)(b * Wn + w0 + wl) * CH + c) * Hn + h0 + hq;
    *(s16x8*)(dst)     = d0;
    *(s16x8*)(dst + 8) = d1;
  }
}

// out = gamma*(ah*ohX^T + aw*ow) + resid  [single attention set]
__global__ __launch_bounds__(256) void k_fuse2(const float* __restrict__ in,
                                               const bf16* __restrict__ ohX,
                                               const bf16* __restrict__ ow,
                                               const float* __restrict__ ahT,
                                               const float* __restrict__ aw,
                                               const float* __restrict__ gamma,
                                               float* __restrict__ out){
  __shared__ unsigned short tileT[64][138];
  int c = blockIdx.x, half = blockIdx.y, b = blockIdx.z;
  int t = threadIdx.x;
  float g = gamma[0];
  int h0 = half * 64;
  const bf16* ohp = ohX + ((size_t)(b * Cn + c)) * Nn;   // [w][h] rows
  #pragma unroll
  for (int i = 0; i < 4; ++i){
    int s = t + i * 256;            // 0..1023: w = s>>3, seg = s&7 (h-chunk)
    int w = s >> 3, seg = s & 7;
    s16x8 d = *(const s16x8*)(ohp + (size_t)w * Hn + h0 + seg * 8);
    #pragma unroll
    for (int j = 0; j < 8; ++j)
      tileT[seg * 8 + j][w] = (unsigned short)d[j];
  }
  __syncthreads();
  size_t base = ((size_t)(b * Cn + c)) * Nn;
  #pragma unroll
  for (int i = 0; i < 8; ++i){
    int o = t + i * 256;            // 0..2047
    int hl = o >> 5, w4 = (o & 31) * 4;
    int h = h0 + hl;
    size_t idx = base + (size_t)h * Wn + w4;
    size_t aidx = (size_t)b * Nn + (size_t)h * Wn + w4;
    ushort4 owv = *(const ushort4*)((const unsigned short*)ow + idx);
    float4 ah4 = *(const float4*)(ahT + aidx);
    float4 aw4 = *(const float4*)(aw + aidx);
    float4 inv = in ? *(const float4*)(in + idx) : (float4){0.f,0.f,0.f,0.f};
    float r[4];
    #pragma unroll
    for (int j = 0; j < 4; ++j){
      unsigned short uh = tileT[hl][w4 + j];
      unsigned short uo = ((const unsigned short*)&owv)[j];
      float ohv = bf2f(*(bf16*)&uh);
      float owf = bf2f(*(bf16*)&uo);
      float ahv = ((const float*)&ah4)[j];
      float awv = ((const float*)&aw4)[j];
      r[j] = g * (ahv * ohv + awv * owf) + ((const float*)&inv)[j];
    }
    float4 o4 = { r[0], r[1], r[2], r[3] };
    *(float4*)(out + idx) = o4;
  }
}

// s = gamma*(a1h*oh1^T + a1w*ow1) + gamma*(a2h*oh2^T + a2w*ow2) + x*(mch+msp)
// Two-phase single-tile (17.7KB LDS, 512 threads): phase1 oh2 (term2+resid),
// phase2 oh1 (+= term1). 128B row reads preserved; high occupancy.
__global__ __launch_bounds__(512) void k_fuse3(const float* __restrict__ x,
                                               const float* __restrict__ mch,
                                               const float* __restrict__ msp,
                                               const bf16* __restrict__ oh1,
                                               const bf16* __restrict__ ow1,
                                               const float* __restrict__ a1h,
                                               const float* __restrict__ a1w,
                                               const bf16* __restrict__ oh2,
                                               const bf16* __restrict__ ow2,
                                               const float* __restrict__ a2h,
                                               const float* __restrict__ a2w,
                                               const float* __restrict__ gamma,
                                               float* __restrict__ out){
  __shared__ unsigned short tl_[64][138];
  int c = blockIdx.x, half = blockIdx.y, b = blockIdx.z;
  int t = threadIdx.x;
  float g = gamma[0];
  float mc = mch[b * Cn + c];
  int h0 = half * 64;
  const bf16* p1 = oh1 + ((size_t)(b * Cn + c)) * Nn;
  const bf16* p2 = oh2 + ((size_t)(b * Cn + c)) * Nn;
  size_t base = ((size_t)(b * Cn + c)) * Nn;
  // phase 1: oh2 tile
  #pragma unroll
  for (int i = 0; i < 2; ++i){
    int s = t + i * 512;            // 0..1023: w = s>>3, seg = s&7
    int w = s >> 3, seg = s & 7;
    s16x8 d = *(const s16x8*)(p2 + (size_t)w * Hn + h0 + seg * 8);
    #pragma unroll
    for (int j = 0; j < 8; ++j)
      tl_[seg * 8 + j][w] = (unsigned short)d[j];
  }
  __syncthreads();
  float r[4][4];
  #pragma unroll
  for (int i = 0; i < 4; ++i){
    int o = t + i * 512;            // 0..2047
    int hl = o >> 5, w4 = (o & 31) * 4;
    int h = h0 + hl;
    size_t idx = base + (size_t)h * Wn + w4;
    size_t aidx = (size_t)b * Nn + (size_t)h * Wn + w4;
    ushort4 o2v = *(const ushort4*)((const unsigned short*)ow2 + idx);
    float4 a2h4 = *(const float4*)(a2h + aidx);
    float4 a2w4 = *(const float4*)(a2w + aidx);
    float4 xv4  = *(const float4*)(x + idx);
    float4 mn4  = *(const float4*)(msp + aidx);
    #pragma unroll
    for (int j = 0; j < 4; ++j){
      unsigned short u2 = tl_[hl][w4 + j];
      unsigned short w2 = ((const unsigned short*)&o2v)[j];
      float oh2v = bf2f(*(bf16*)&u2), ow2v = bf2f(*(bf16*)&w2);
      float term2 = g * (((const float*)&a2h4)[j] * oh2v + ((const float*)&a2w4)[j] * ow2v);
      float resid = ((const float*)&xv4)[j] * (mc + ((const float*)&mn4)[j]);
      r[i][j] = term2 + resid;
    }
  }
  __syncthreads();
  // phase 2: oh1 tile (same LDS)
  #pragma unroll
  for (int i = 0; i < 2; ++i){
    int s = t + i * 512;
    int w = s >> 3, seg = s & 7;
    s16x8 d = *(const s16x8*)(p1 + (size_t)w * Hn + h0 + seg * 8);
    #pragma unroll
    for (int j = 0; j < 8; ++j)
      tl_[seg * 8 + j][w] = (unsigned short)d[j];
  }
  __syncthreads();
  #pragma unroll
  for (int i = 0; i < 4; ++i){
    int o = t + i * 512;
    int hl = o >> 5, w4 = (o & 31) * 4;
    int h = h0 + hl;
    size_t idx = base + (size_t)h * Wn + w4;
    size_t aidx = (size_t)b * Nn + (size_t)h * Wn + w4;
    ushort4 o1v = *(const ushort4*)((const unsigned short*)ow1 + idx);
    float4 a1h4 = *(const float4*)(a1h + aidx);
    float4 a1w4 = *(const float4*)(a1w + aidx);
    float rr[4];
    #pragma unroll
    for (int j = 0; j < 4; ++j){
      unsigned short u1 = tl_[hl][w4 + j];
      unsigned short w1 = ((const unsigned short*)&o1v)[j];
      float oh1v = bf2f(*(bf16*)&u1), ow1v = bf2f(*(bf16*)&w1);
      float term1 = g * (((const float*)&a1h4)[j] * oh1v + ((const float*)&a1w4)[j] * ow1v);
      rr[j] = r[i][j] + term1;
    }
    float4 o4 = { rr[0], rr[1], rr[2], rr[3] };
    *(float4*)(out + idx) = o4;
  }
}

// ============================ host ============================

static void run_att(const bf16* xT_hi, const bf16* xT_lo,
                    const bf16* wqk_hi, const bf16* wqk_lo, int wqk_bstride,
                    const float* bqk,
                    const bf16* wvb, int wv_bstride, const float* bv,
                    const float* nscale,
                    bf16* qhw, bf16* khw, bf16* v, bf16* vT,
                    float* mh, float* sh, float* mw, float* sw,
                    float* ahT, float* aw, bf16* tmp, hipStream_t stream){
  bf16* ohX = tmp;
  bf16* ow  = tmp + (size_t)Bn * Cn * Nn;
  k_qk_mfma<<<dim3(Nn / 128, Bn), 256, 0, stream>>>(xT_hi, xT_lo, wqk_hi, wqk_lo,
                                                    wqk_bstride, bqk, nscale,
                                                    qhw, khw);
  k_v_mfma<<<2048, 256, 0, stream>>>(xT_hi, wvb, wv_bstride, bv, nscale, v);
  k_trans<<<dim3(4, Cn, Bn), 256, 0, stream>>>(v, vT, Cn);
  k_att_h<<<dim3(Wn, Bn), 256, 0, stream>>>(qhw, khw, vT, mh, sh, ohX);
  k_att_w<<<dim3(Hn, Bn), 256, 0, stream>>>(qhw, khw, v, mw, sw, ow);
  k_alpha<<<Bn * Nn / 256, 256, 0, stream>>>(mh, sh, mw, sw, ahT, aw);
}

extern "C" void kernel_launch(void* const* d_in, const int* in_sizes, int n_in,
                              void* d_out, int out_size, void* d_ws, size_t ws_size,
                              hipStream_t stream){
  (void)in_sizes; (void)n_in; (void)out_size; (void)ws_size;
  const float* x         = (const float*)d_in[0];
  const float* w_q_right = (const float*)d_in[1];
  const float* w_v_right = (const float*)d_in[2];
  const float* w_up      = (const float*)d_in[3];
  const float* b_up      = (const float*)d_in[4];
  const float* w_q_left  = (const float*)d_in[5];
  const float* w_v_left  = (const float*)d_in[6];
  const float* wq        = (const float*)d_in[7];
  const float* bq        = (const float*)d_in[8];
  const float* wk        = (const float*)d_in[9];
  const float* bk        = (const float*)d_in[10];
  const float* wv        = (const float*)d_in[11];
  const float* bv        = (const float*)d_in[12];
  const float* gamma     = (const float*)d_in[13];

  const size_t SZ_MAP = (size_t)Bn * Cn * Nn;     // 33.5M elements
  char* p = (char*)d_ws;
  float* buf0   = (float*)p; p += SZ_MAP * 4;     // CA2 tmp (oh2/ow2), CA3 tmp
  float* buf1   = (float*)p; p += SZ_MAP * 4;     // xT_lo(x) first half; then s
  bf16*  vbuf   = (bf16*)p;  p += SZ_MAP * 2;
  bf16*  vT     = (bf16*)p;  p += SZ_MAP * 2;
  bf16*  qhw    = (bf16*)p;  p += (size_t)Bn * CQn * Nn * 2;
  bf16*  khw    = (bf16*)p;  p += (size_t)Bn * CQn * Nn * 2;
  float* ebuf   = (float*)p; p += (size_t)SZ_MAP * 2;         // xT_hi arena (67MB)
  float* logits = (float*)p; p += (size_t)Bn * Nn * 4;
  float* ctxlog = (float*)p; p += (size_t)Bn * Nn * 4;
  float* msp    = (float*)p; p += (size_t)Bn * Nn * 4;
  float* xbar   = (float*)p; p += Bn * Cn * 4;
  float* wgt    = (float*)p; p += Bn * Cn * 4;
  float* u      = (float*)p; p += Bn * Cn * 4;
  float* mch    = (float*)p; p += Bn * Cn * 4;
  float* avg    = (float*)p; p += Bn * CIn * 4;
  float* ctx    = (float*)p; p += Bn * CIn * 4;
  float* stats_sp = (float*)p; p += 64;
  float* stats_ch = (float*)p; p += 64;
  bf16*  wvb    = (bf16*)p;  p += (size_t)Cn * Cn * 2;
  bf16*  wqk_hi = (bf16*)p;  p += (size_t)128 * Cn * 2;
  bf16*  wqk_lo = (bf16*)p;  p += (size_t)128 * Cn * 2;
  float* bqk    = (float*)p; p += 128 * 4;
  float* mh     = (float*)p; p += (size_t)Bn * Nn * 4;
  float* sh     = (float*)p; p += (size_t)Bn * Nn * 4;
  float* mw     = (float*)p; p += (size_t)Bn * Nn * 4;
  float* sw     = (float*)p; p += (size_t)Bn * Nn * 4;
  float* ah1    = (float*)p; p += (size_t)Bn * Nn * 4;
  float* aw1    = (float*)p; p += (size_t)Bn * Nn * 4;
  float* ah2    = (float*)p; p += (size_t)Bn * Nn * 4;
  float* aw2    = (float*)p; p += (size_t)Bn * Nn * 4;
  float* dpart  = (float*)p; p += (size_t)2 * Bn * Nn * 4;    // split-K partials (512KB)
  bf16*  wqk_mch_hi = (bf16*)p; p += (size_t)Bn * 128 * Cn * 2;   // per-b mch-folded QK w
  bf16*  wqk_mch_lo = (bf16*)p; p += (size_t)Bn * 128 * Cn * 2;
  bf16*  wv_mch     = (bf16*)p; p += (size_t)Bn * Cn * Cn * 2;    // per-b mch-folded V w

  bf16*  xT_hi  = (bf16*)ebuf;               // x transposed hi (dead after CA2 v_mfma)
  bf16*  xT_lo  = (bf16*)buf1;               // x transposed lo (dead after CA2 qk_mfma)
  bf16*  xT_hi3 = (bf16*)ebuf;               // CA3 set (after xT_hi dead)
  bf16*  xT_lo3 = (bf16*)d_out;              // d_out free after fuse3 consumed oh1/ow1

  // ---- weight prep (once) ----
  k_cvt_w<<<(Cn * Cn + 255) / 256, 256, 0, stream>>>(wv, wvb, Cn * Cn);
  k_prep_wqk<<<(128 * Cn) / 256, 256, 0, stream>>>(wq, wk, bq, bk, wqk_hi, wqk_lo, bqk);
  // single x transpose: hi -> ebuf, lo -> buf1 first half
  k_cvt_T<<<dim3(Nn / 32, Cn / 32, Bn), 256, 0, stream>>>(x, xT_hi, xT_lo);

  // ---- stage 0: gating masks ----
  k_dotc2<<<dim3(Bn * Nn / 256, 2), 256, 0, stream>>>(x, w_q_right, 0, dpart);
  k_dotcadd<<<Bn * Nn / 256, 256, 0, stream>>>(dpart, logits);
  k_rowmean<<<Bn * Cn, 256, 0, stream>>>(x, xbar, 1.f / Nn);
  k_rowdot<<<Bn, 256, 0, stream>>>(w_q_left, xbar, avg);
  k_coldot<<<dim3(Cn / 256, Bn), 256, 0, stream>>>(w_v_left, avg, u);
  k_stats<<<Bn, 1024, 0, stream>>>(logits, stats_sp);
  k_weighted<<<Bn * Cn, 256, 0, stream>>>(x, logits, stats_sp, wgt);
  k_rowdot<<<Bn, 256, 0, stream>>>(w_v_right, wgt, ctx);
  k_mch2<<<dim3(Cn / 256, Bn), 256, 0, stream>>>(w_up, b_up, ctx, mch);
  // per-b mch-folded weights (CA1 path)
  k_prep_wqk_mch<<<(Bn * 128 * Cn) / 256, 256, 0, stream>>>(wq, wk, mch,
                                                            wqk_mch_hi, wqk_mch_lo);
  k_prep_wv_mch<<<(Bn * Cn * Cn) / 256, 256, 0, stream>>>(wv, mch, wv_mch);
  k_dotc2<<<dim3(Bn * Nn / 256, 2), 256, 0, stream>>>(x, u, Cn, dpart);
  k_dotcadd<<<Bn * Nn / 256, 256, 0, stream>>>(dpart, ctxlog);
  k_stats<<<Bn, 1024, 0, stream>>>(ctxlog, stats_ch);
  k_msp<<<Bn * Nn / 256, 256, 0, stream>>>(ctxlog, stats_ch, msp);

  // ---- CA1 (cc = x*mch): mch folded into per-b weights; tmp = d_out ----
  run_att(xT_hi, xT_lo, wqk_mch_hi, wqk_mch_lo, 128 * Cn, bqk,
          wv_mch, Cn * Cn, bv, nullptr,
          qhw, khw, vbuf, vT, mh, sh, mw, sw, ah1, aw1, (bf16*)d_out, stream);
  // ---- CA2 (cs = x*msp): msp applied as per-n epilogue scale; tmp = buf0 ----
  run_att(xT_hi, xT_lo, wqk_hi, wqk_lo, 0, bqk, wvb, 0, bv, msp,
          qhw, khw, vbuf, vT, mh, sh, mw, sw, ah2, aw2, (bf16*)buf0, stream);
  // ---- combined fuse: s = g*att1 + g*att2 + x*(mch+msp) -> buf1 ----
  k_fuse3<<<dim3(Cn, 2, Bn), 512, 0, stream>>>(x, mch, msp,
                                               (const bf16*)d_out,
                                               (const bf16*)d_out + SZ_MAP, ah1, aw1,
                                               (const bf16*)buf0,
                                               (const bf16*)buf0 + SZ_MAP, ah2, aw2,
                                               gamma, buf1);
  // ---- CA3: in = s = buf1; tmp = buf0; out = d_out ----
  k_cvt_T<<<dim3(Nn / 32, Cn / 32, Bn), 256, 0, stream>>>(buf1, xT_hi3, xT_lo3);
  run_att(xT_hi3, xT_lo3, wqk_hi, wqk_lo, 0, bqk, wvb, 0, bv, nullptr,
          qhw, khw, vbuf, vT, mh, sh, mw, sw, ah1, aw1, (bf16*)buf0, stream);
  k_fuse2<<<dim3(Cn, 2, Bn), 256, 0, stream>>>(buf1, (const bf16*)buf0,
                                               (const bf16*)buf0 + SZ_MAP, ah1, aw1,
                                               gamma, (float*)d_out);
}